// Round 1
// baseline (4079.729 us; speedup 1.0000x reference)
//
#include <hip/hip_runtime.h>
#include <math.h>

#define Nn 100000
#define Ee 1600000
#define EP 1700000   /* Ee + Nn self loops */
#define H1 8
#define NC 40
#define SLOPE 0.2f

// ---------- helpers ----------

__device__ __forceinline__ void atomicMaxFloat(float* addr, float val) {
    if (val > 0.0f) {
        atomicMax((int*)addr, __float_as_int(val));
    } else {
        atomicMin((unsigned int*)addr, __float_as_uint(val));
    }
}

__device__ __forceinline__ void edge_sd(int e, const int* __restrict__ ei, int& s, int& d) {
    if (e < Ee) { s = ei[e]; d = ei[Ee + e]; }
    else        { s = e - Ee; d = s; }
}

__global__ void fill_kernel(float* __restrict__ p, int n, float v) {
    int i = blockIdx.x * 256 + threadIdx.x;
    if (i < n) p[i] = v;
}

// ---------- layer 1: h1 = x@W1, hres = x@res1_W + res1_b, a_src/a_dst ----------
// 16 nodes per block, 128 threads (one output column each for both matrices).

__global__ __launch_bounds__(128) void gemm1_kernel(
        const float* __restrict__ x,
        const float* __restrict__ W1, const float* __restrict__ Wr,
        const float* __restrict__ rb,
        const float* __restrict__ att_s, const float* __restrict__ att_d,
        float* __restrict__ h1, float* __restrict__ hbuf,
        float* __restrict__ asrc, float* __restrict__ adst) {
    __shared__ float xs[16][128];
    int t = threadIdx.x;
    int n0 = blockIdx.x * 16;
    #pragma unroll
    for (int i = 0; i < 16; i++) xs[i][t] = x[(size_t)(n0 + i) * 128 + t];
    __syncthreads();

    float acch[16], accr[16];
    #pragma unroll
    for (int i = 0; i < 16; i++) { acch[i] = 0.f; accr[i] = 0.f; }

    for (int k = 0; k < 128; k += 4) {
        float w1a[4], wra[4];
        #pragma unroll
        for (int j = 0; j < 4; j++) {
            w1a[j] = W1[(k + j) * 128 + t];
            wra[j] = Wr[(k + j) * 128 + t];
        }
        #pragma unroll
        for (int i = 0; i < 16; i++) {
            float4 xv = *(const float4*)&xs[i][k];
            acch[i] += xv.x * w1a[0] + xv.y * w1a[1] + xv.z * w1a[2] + xv.w * w1a[3];
            accr[i] += xv.x * wra[0] + xv.y * wra[1] + xv.z * wra[2] + xv.w * wra[3];
        }
    }

    float bias = rb[t];
    float asw = att_s[t];
    float adw = att_d[t];
    #pragma unroll
    for (int i = 0; i < 16; i++) {
        int n = n0 + i;
        h1[(size_t)n * 128 + t] = acch[i];
        hbuf[(size_t)n * 128 + t] = accr[i] + bias;
        float vs = acch[i] * asw;
        float vd = acch[i] * adw;
        #pragma unroll
        for (int m = 8; m >= 1; m >>= 1) {
            vs += __shfl_xor(vs, m, 16);
            vd += __shfl_xor(vd, m, 16);
        }
        if ((t & 15) == 0) {
            asrc[n * 8 + (t >> 4)] = vs;
            adst[n * 8 + (t >> 4)] = vd;
        }
    }
}

// ---------- layer 1 edge passes ----------

__global__ void edge_max1_kernel(const int* __restrict__ ei,
                                 const float* __restrict__ as, const float* __restrict__ ad,
                                 float* __restrict__ mx) {
    int tid = blockIdx.x * 256 + threadIdx.x;
    if (tid >= EP * 8) return;
    int e = tid >> 3, h = tid & 7;
    int s, d; edge_sd(e, ei, s, d);
    float v = as[s * 8 + h] + ad[d * 8 + h];
    v = v > 0.f ? v : SLOPE * v;
    atomicMaxFloat(&mx[d * 8 + h], v);
}

__global__ void edge_sum1_kernel(const int* __restrict__ ei,
                                 const float* __restrict__ as, const float* __restrict__ ad,
                                 const float* __restrict__ mx, float* __restrict__ sm) {
    int tid = blockIdx.x * 256 + threadIdx.x;
    if (tid >= EP * 8) return;
    int e = tid >> 3, h = tid & 7;
    int s, d; edge_sd(e, ei, s, d);
    float v = as[s * 8 + h] + ad[d * 8 + h];
    v = v > 0.f ? v : SLOPE * v;
    atomicAdd(&sm[d * 8 + h], __expf(v - mx[d * 8 + h]));
}

__global__ void edge_agg1_kernel(const int* __restrict__ ei,
                                 const float* __restrict__ as, const float* __restrict__ ad,
                                 const float* __restrict__ mx, const float* __restrict__ sm,
                                 const float* __restrict__ h1, float* __restrict__ acc) {
    int tid = blockIdx.x * 256 + threadIdx.x;
    if (tid >= EP * 32) return;
    int e = tid >> 5;
    int q = tid & 31;        // 32 float4 chunks of the 128-wide row
    int h = q >> 2;          // head = chunk/4
    int s, d; edge_sd(e, ei, s, d);
    float v = as[s * 8 + h] + ad[d * 8 + h];
    v = v > 0.f ? v : SLOPE * v;
    float alpha = __expf(v - mx[d * 8 + h]) / sm[d * 8 + h];
    const float4 hv = *(const float4*)(h1 + (size_t)s * 128 + q * 4);
    float* ap = acc + (size_t)d * 128 + q * 4;
    atomicAdd(ap + 0, alpha * hv.x);
    atomicAdd(ap + 1, alpha * hv.y);
    atomicAdd(ap + 2, alpha * hv.z);
    atomicAdd(ap + 3, alpha * hv.w);
}

__global__ void finalize1_kernel(const float* __restrict__ acc, const float* __restrict__ bias,
                                 float* __restrict__ hbuf) {
    int i = blockIdx.x * 256 + threadIdx.x;
    if (i >= Nn * 128) return;
    float g = acc[i] + bias[i & 127];
    float e = g > 0.f ? g : expm1f(g);
    hbuf[i] += e;   // hbuf holds x@res1_W + res1_b
}

// ---------- layer 2: h2 = h@W2, res -> d_out, a_src2/a_dst2 ----------
// one wave per node (lanes 0..39 active), 4 nodes per 256-thread block.

__global__ __launch_bounds__(256) void gemm2_kernel(
        const float* __restrict__ h,
        const float* __restrict__ W2, const float* __restrict__ Wr,
        const float* __restrict__ rb,
        const float* __restrict__ att_s, const float* __restrict__ att_d,
        float* __restrict__ h2, float* __restrict__ resout,
        float* __restrict__ as2, float* __restrict__ ad2) {
    __shared__ float hs[4][128];
    int lane = threadIdx.x & 63, wv = threadIdx.x >> 6;
    int n = blockIdx.x * 4 + wv;
    hs[wv][lane]      = h[(size_t)n * 128 + lane];
    hs[wv][lane + 64] = h[(size_t)n * 128 + 64 + lane];
    __syncthreads();
    float acc = 0.f, accr = 0.f;
    int c = lane;
    if (c < NC) {
        for (int k = 0; k < 128; k++) {
            float hv = hs[wv][k];
            acc  += hv * W2[k * NC + c];
            accr += hv * Wr[k * NC + c];
        }
    }
    float vs = c < NC ? acc * att_s[c] : 0.f;
    float vd = c < NC ? acc * att_d[c] : 0.f;
    #pragma unroll
    for (int m = 32; m >= 1; m >>= 1) {
        vs += __shfl_xor(vs, m, 64);
        vd += __shfl_xor(vd, m, 64);
    }
    if (c < NC) {
        h2[n * NC + c] = acc;
        resout[n * NC + c] = accr + rb[c];
    }
    if (lane == 0) { as2[n] = vs; ad2[n] = vd; }
}

// ---------- layer 2 edge passes ----------

__global__ void edge_max2_kernel(const int* __restrict__ ei,
                                 const float* __restrict__ as, const float* __restrict__ ad,
                                 float* __restrict__ mx) {
    int e = blockIdx.x * 256 + threadIdx.x;
    if (e >= EP) return;
    int s, d; edge_sd(e, ei, s, d);
    float v = as[s] + ad[d];
    v = v > 0.f ? v : SLOPE * v;
    atomicMaxFloat(&mx[d], v);
}

__global__ void edge_sum2_kernel(const int* __restrict__ ei,
                                 const float* __restrict__ as, const float* __restrict__ ad,
                                 const float* __restrict__ mx, float* __restrict__ sm) {
    int e = blockIdx.x * 256 + threadIdx.x;
    if (e >= EP) return;
    int s, d; edge_sd(e, ei, s, d);
    float v = as[s] + ad[d];
    v = v > 0.f ? v : SLOPE * v;
    atomicAdd(&sm[d], __expf(v - mx[d]));
}

__global__ __launch_bounds__(256) void edge_agg2_kernel(
        const int* __restrict__ ei,
        const float* __restrict__ as, const float* __restrict__ ad,
        const float* __restrict__ mx, const float* __restrict__ sm,
        const float* __restrict__ h2, float* __restrict__ acc) {
    int lane = threadIdx.x & 63, wv = threadIdx.x >> 6;
    int e = blockIdx.x * 4 + wv;
    if (e >= EP) return;
    int s, d; edge_sd(e, ei, s, d);
    float v = as[s] + ad[d];
    v = v > 0.f ? v : SLOPE * v;
    float alpha = __expf(v - mx[d]) / sm[d];
    if (lane < NC) atomicAdd(&acc[d * NC + lane], alpha * h2[s * NC + lane]);
}

__global__ __launch_bounds__(256) void finalize2_kernel(
        const float* __restrict__ acc, const float* __restrict__ b2,
        float* __restrict__ outp) {
    int lane = threadIdx.x & 63, wv = threadIdx.x >> 6;
    int n = blockIdx.x * 4 + wv;
    bool act = lane < NC;
    float v = act ? acc[n * NC + lane] + b2[lane] + outp[n * NC + lane] : -3.4e38f;
    float m = v;
    #pragma unroll
    for (int s = 32; s >= 1; s >>= 1) m = fmaxf(m, __shfl_xor(m, s, 64));
    float ex = act ? __expf(v - m) : 0.f;
    float ssum = ex;
    #pragma unroll
    for (int s = 32; s >= 1; s >>= 1) ssum += __shfl_xor(ssum, s, 64);
    if (act) outp[n * NC + lane] = v - m - logf(ssum);
}

// ---------- host ----------

extern "C" void kernel_launch(void* const* d_in, const int* in_sizes, int n_in,
                              void* d_out, int out_size, void* d_ws, size_t ws_size,
                              hipStream_t stream) {
    const float* x      = (const float*)d_in[0];
    const int*   ei     = (const int*)d_in[1];
    const float* W1     = (const float*)d_in[2];
    const float* att_s1 = (const float*)d_in[3];
    const float* att_d1 = (const float*)d_in[4];
    const float* bias1  = (const float*)d_in[5];
    const float* W2     = (const float*)d_in[6];
    const float* att_s2 = (const float*)d_in[7];
    const float* att_d2 = (const float*)d_in[8];
    const float* bias2  = (const float*)d_in[9];
    const float* r1W    = (const float*)d_in[10];
    const float* r1b    = (const float*)d_in[11];
    const float* r2W    = (const float*)d_in[12];
    const float* r2b    = (const float*)d_in[13];
    float* out = (float*)d_out;

    float* ws   = (float*)d_ws;
    float* h1   = ws;                           // N*128
    float* hbuf = h1 + (size_t)Nn * 128;        // N*128  (res1, then h)
    float* regC = hbuf + (size_t)Nn * 128;      // N*128 region, reused
    float* acc1 = regC;
    float* asrc1 = regC + (size_t)Nn * 128;     // N*8
    float* adst1 = asrc1 + Nn * 8;              // N*8
    float* mx1   = adst1 + Nn * 8;              // N*8
    float* sm1   = mx1 + Nn * 8;                // N*8
    // layer-2 aliases into regC (valid after finalize1)
    float* h2v   = regC;                        // N*40
    float* acc2  = regC + (size_t)Nn * 40;      // N*40
    float* asrc2 = regC + (size_t)Nn * 80;      // N
    float* adst2 = asrc2 + Nn;                  // N
    float* mx2   = adst2 + Nn;                  // N
    float* sm2   = mx2 + Nn;                    // N

    const float NEGINF = -__builtin_huge_valf();

    // ---- layer 1 ----
    fill_kernel<<<(Nn * 128 + 255) / 256, 256, 0, stream>>>(acc1, Nn * 128, 0.f);
    fill_kernel<<<(Nn * 8 + 255) / 256, 256, 0, stream>>>(mx1, Nn * 8, NEGINF);
    fill_kernel<<<(Nn * 8 + 255) / 256, 256, 0, stream>>>(sm1, Nn * 8, 0.f);

    gemm1_kernel<<<Nn / 16, 128, 0, stream>>>(x, W1, r1W, r1b, att_s1, att_d1,
                                              h1, hbuf, asrc1, adst1);

    edge_max1_kernel<<<(EP * 8 + 255) / 256, 256, 0, stream>>>(ei, asrc1, adst1, mx1);
    edge_sum1_kernel<<<(EP * 8 + 255) / 256, 256, 0, stream>>>(ei, asrc1, adst1, mx1, sm1);
    edge_agg1_kernel<<<(EP * 32 + 255) / 256, 256, 0, stream>>>(ei, asrc1, adst1, mx1, sm1, h1, acc1);

    finalize1_kernel<<<(Nn * 128 + 255) / 256, 256, 0, stream>>>(acc1, bias1, hbuf);

    // ---- layer 2 ----
    fill_kernel<<<(Nn * 40 + 255) / 256, 256, 0, stream>>>(acc2, Nn * 40, 0.f);
    fill_kernel<<<(Nn + 255) / 256, 256, 0, stream>>>(mx2, Nn, NEGINF);
    fill_kernel<<<(Nn + 255) / 256, 256, 0, stream>>>(sm2, Nn, 0.f);

    gemm2_kernel<<<Nn / 4, 256, 0, stream>>>(hbuf, W2, r2W, r2b, att_s2, att_d2,
                                             h2v, out, asrc2, adst2);

    edge_max2_kernel<<<(EP + 255) / 256, 256, 0, stream>>>(ei, asrc2, adst2, mx2);
    edge_sum2_kernel<<<(EP + 255) / 256, 256, 0, stream>>>(ei, asrc2, adst2, mx2, sm2);
    edge_agg2_kernel<<<EP / 4, 256, 0, stream>>>(ei, asrc2, adst2, mx2, sm2, h2v, acc2);

    finalize2_kernel<<<Nn / 4, 256, 0, stream>>>(acc2, bias2, out);
}

// Round 2
// 1267.597 us; speedup vs baseline: 3.2185x; 3.2185x over previous
//
#include <hip/hip_runtime.h>
#include <math.h>

#define Nn 100000
#define Ee 1600000
#define EP 1700000   /* Ee + Nn self loops */
#define NC 40
#define SLOPE 0.2f

// ---------------- CSR build ----------------

__global__ void zero_int_kernel(int* __restrict__ p, int n) {
    int i = blockIdx.x * 256 + threadIdx.x;
    if (i < n) p[i] = 0;
}

__global__ void hist_kernel(const int* __restrict__ ei, int* __restrict__ cnt) {
    int e = blockIdx.x * 256 + threadIdx.x;
    if (e >= EP) return;
    int d = (e < Ee) ? ei[Ee + e] : (e - Ee);
    atomicAdd(&cnt[d], 1);
}

#define SCAN_T 1024
__global__ __launch_bounds__(SCAN_T) void scan_kernel(int* __restrict__ cnt /* in: counts, out: cursor */,
                                                      int* __restrict__ rs) {
    __shared__ int part[SCAN_T];
    int t = threadIdx.x;
    const int chunk = (Nn + SCAN_T - 1) / SCAN_T;   // 98
    int lo = t * chunk;
    int hi = lo + chunk; if (hi > Nn) hi = Nn;
    int s = 0;
    for (int i = lo; i < hi; i++) s += cnt[i];
    part[t] = s;
    __syncthreads();
    for (int off = 1; off < SCAN_T; off <<= 1) {
        int v = (t >= off) ? part[t - off] : 0;
        __syncthreads();
        part[t] += v;
        __syncthreads();
    }
    int run = (t == 0) ? 0 : part[t - 1];
    for (int i = lo; i < hi; i++) {
        int c = cnt[i];
        rs[i] = run;
        cnt[i] = run;    // becomes the scatter cursor
        run += c;
    }
    if (t == SCAN_T - 1) rs[Nn] = part[SCAN_T - 1];
}

__global__ void scatter_kernel(const int* __restrict__ ei, int* __restrict__ cursor,
                               int* __restrict__ csr_src) {
    int e = blockIdx.x * 256 + threadIdx.x;
    if (e >= EP) return;
    int s, d;
    if (e < Ee) { s = ei[e]; d = ei[Ee + e]; }
    else        { s = e - Ee; d = s; }
    int pos = atomicAdd(&cursor[d], 1);
    csr_src[pos] = s;
}

// ---------------- layer 1 GEMM: h1 = x@W1, hbuf = x@res1_W + res1_b, a_src/a_dst ----------------

__global__ __launch_bounds__(128) void gemm1_kernel(
        const float* __restrict__ x,
        const float* __restrict__ W1, const float* __restrict__ Wr,
        const float* __restrict__ rb,
        const float* __restrict__ att_s, const float* __restrict__ att_d,
        float* __restrict__ h1, float* __restrict__ hbuf,
        float* __restrict__ asrc, float* __restrict__ adst) {
    __shared__ float xs[16][128];
    int t = threadIdx.x;
    int n0 = blockIdx.x * 16;
    #pragma unroll
    for (int i = 0; i < 16; i++) xs[i][t] = x[(size_t)(n0 + i) * 128 + t];
    __syncthreads();

    float acch[16], accr[16];
    #pragma unroll
    for (int i = 0; i < 16; i++) { acch[i] = 0.f; accr[i] = 0.f; }

    for (int k = 0; k < 128; k += 4) {
        float w1a[4], wra[4];
        #pragma unroll
        for (int j = 0; j < 4; j++) {
            w1a[j] = W1[(k + j) * 128 + t];
            wra[j] = Wr[(k + j) * 128 + t];
        }
        #pragma unroll
        for (int i = 0; i < 16; i++) {
            float4 xv = *(const float4*)&xs[i][k];
            acch[i] += xv.x * w1a[0] + xv.y * w1a[1] + xv.z * w1a[2] + xv.w * w1a[3];
            accr[i] += xv.x * wra[0] + xv.y * wra[1] + xv.z * wra[2] + xv.w * wra[3];
        }
    }

    float bias = rb[t];
    float asw = att_s[t];
    float adw = att_d[t];
    #pragma unroll
    for (int i = 0; i < 16; i++) {
        int n = n0 + i;
        h1[(size_t)n * 128 + t] = acch[i];
        hbuf[(size_t)n * 128 + t] = accr[i] + bias;
        float vs = acch[i] * asw;
        float vd = acch[i] * adw;
        #pragma unroll
        for (int m = 8; m >= 1; m >>= 1) {
            vs += __shfl_xor(vs, m, 16);
            vd += __shfl_xor(vd, m, 16);
        }
        if ((t & 15) == 0) {
            asrc[n * 8 + (t >> 4)] = vs;
            adst[n * 8 + (t >> 4)] = vd;
        }
    }
}

// ---------------- layer 1 gather-aggregate: one wave per dst ----------------
// lanes: h = lane&7 (head for logit work), cols lane and lane+64 for aggregation.

__global__ __launch_bounds__(256) void agg1_kernel(
        const int* __restrict__ rs, const int* __restrict__ csr,
        const float* __restrict__ as, const float* __restrict__ ad,
        const float* __restrict__ h1, const float* __restrict__ bias,
        float* __restrict__ hbuf) {
    int lane = threadIdx.x & 63, wv = threadIdx.x >> 6;
    int n = blockIdx.x * 4 + wv;
    if (n >= Nn) return;
    int row = rs[n], end = rs[n + 1];
    int h = lane & 7;
    int j8 = lane >> 3;
    float adh = ad[n * 8 + h];

    // phase 1: per-head max (8 edges in parallel across lane groups)
    float m = -3.4e38f;
    for (int j = row + j8; j < end; j += 8) {
        int s = csr[j];
        float v = as[s * 8 + h] + adh;
        v = v > 0.f ? v : SLOPE * v;
        m = fmaxf(m, v);
    }
    m = fmaxf(m, __shfl_xor(m, 8, 64));
    m = fmaxf(m, __shfl_xor(m, 16, 64));
    m = fmaxf(m, __shfl_xor(m, 32, 64));

    // phase 2: per-head sum of exp
    float se = 0.f;
    for (int j = row + j8; j < end; j += 8) {
        int s = csr[j];
        float v = as[s * 8 + h] + adh;
        v = v > 0.f ? v : SLOPE * v;
        se += __expf(v - m);
    }
    se += __shfl_xor(se, 8, 64);
    se += __shfl_xor(se, 16, 64);
    se += __shfl_xor(se, 32, 64);
    float inv = 1.f / se;

    // phase 3: weighted gather-accumulate (serial over edges, wave-wide rows)
    float acc0 = 0.f, acc1 = 0.f;
    int ha = lane >> 4;        // head of col `lane`
    int hb = 4 + (lane >> 4);  // head of col `lane+64`
    for (int j = row; j < end; j++) {
        int s = csr[j];
        float v = as[s * 8 + h] + adh;
        v = v > 0.f ? v : SLOPE * v;
        float alpha = __expf(v - m) * inv;   // valid for head h = lane&7
        float aa = __shfl(alpha, ha, 64);
        float ab = __shfl(alpha, hb, 64);
        const float* hp = h1 + (size_t)s * 128;
        acc0 += aa * hp[lane];
        acc1 += ab * hp[lane + 64];
    }

    // epilogue: bias + ELU + residual add (hbuf holds x@res1_W + res1_b)
    float g0 = acc0 + bias[lane];
    float g1 = acc1 + bias[lane + 64];
    g0 = g0 > 0.f ? g0 : expm1f(g0);
    g1 = g1 > 0.f ? g1 : expm1f(g1);
    hbuf[(size_t)n * 128 + lane]      += g0;
    hbuf[(size_t)n * 128 + 64 + lane] += g1;
}

// ---------------- layer 2 GEMM ----------------

__global__ __launch_bounds__(256) void gemm2_kernel(
        const float* __restrict__ h,
        const float* __restrict__ W2, const float* __restrict__ Wr,
        const float* __restrict__ rb,
        const float* __restrict__ att_s, const float* __restrict__ att_d,
        float* __restrict__ h2, float* __restrict__ resout,
        float* __restrict__ as2, float* __restrict__ ad2) {
    __shared__ float hs[4][128];
    int lane = threadIdx.x & 63, wv = threadIdx.x >> 6;
    int n = blockIdx.x * 4 + wv;
    hs[wv][lane]      = h[(size_t)n * 128 + lane];
    hs[wv][lane + 64] = h[(size_t)n * 128 + 64 + lane];
    __syncthreads();
    float acc = 0.f, accr = 0.f;
    int c = lane;
    if (c < NC) {
        for (int k = 0; k < 128; k++) {
            float hv = hs[wv][k];
            acc  += hv * W2[k * NC + c];
            accr += hv * Wr[k * NC + c];
        }
    }
    float vs = c < NC ? acc * att_s[c] : 0.f;
    float vd = c < NC ? acc * att_d[c] : 0.f;
    #pragma unroll
    for (int m = 32; m >= 1; m >>= 1) {
        vs += __shfl_xor(vs, m, 64);
        vd += __shfl_xor(vd, m, 64);
    }
    if (c < NC) {
        h2[n * NC + c] = acc;
        resout[n * NC + c] = accr + rb[c];
    }
    if (lane == 0) { as2[n] = vs; ad2[n] = vd; }
}

// ---------------- layer 2 gather-aggregate + log_softmax: one wave per dst ----------------

__global__ __launch_bounds__(256) void agg2_kernel(
        const int* __restrict__ rs, const int* __restrict__ csr,
        const float* __restrict__ as, const float* __restrict__ ad,
        const float* __restrict__ h2, const float* __restrict__ b2,
        float* __restrict__ outp) {
    int lane = threadIdx.x & 63, wv = threadIdx.x >> 6;
    int n = blockIdx.x * 4 + wv;
    if (n >= Nn) return;
    int row = rs[n], end = rs[n + 1];
    float adn = ad[n];

    float m = -3.4e38f;
    for (int j = row + lane; j < end; j += 64) {
        float v = as[csr[j]] + adn;
        v = v > 0.f ? v : SLOPE * v;
        m = fmaxf(m, v);
    }
    #pragma unroll
    for (int st = 32; st >= 1; st >>= 1) m = fmaxf(m, __shfl_xor(m, st, 64));

    float se = 0.f;
    for (int j = row + lane; j < end; j += 64) {
        float v = as[csr[j]] + adn;
        v = v > 0.f ? v : SLOPE * v;
        se += __expf(v - m);
    }
    #pragma unroll
    for (int st = 32; st >= 1; st >>= 1) se += __shfl_xor(se, st, 64);
    float inv = 1.f / se;

    float acc = 0.f;
    for (int j = row; j < end; j++) {
        int s = csr[j];
        float v = as[s] + adn;
        v = v > 0.f ? v : SLOPE * v;
        float alpha = __expf(v - m) * inv;
        if (lane < NC) acc += alpha * h2[s * NC + lane];
    }

    // epilogue: + bias2 + residual (outp holds h@res2_W + res2_b), then log_softmax
    bool act = lane < NC;
    float v = act ? acc + b2[lane] + outp[n * NC + lane] : -3.4e38f;
    float mm = v;
    #pragma unroll
    for (int st = 32; st >= 1; st >>= 1) mm = fmaxf(mm, __shfl_xor(mm, st, 64));
    float ex = act ? __expf(v - mm) : 0.f;
    float ss = ex;
    #pragma unroll
    for (int st = 32; st >= 1; st >>= 1) ss += __shfl_xor(ss, st, 64);
    if (act) outp[n * NC + lane] = v - mm - logf(ss);
}

// ---------------- host ----------------

extern "C" void kernel_launch(void* const* d_in, const int* in_sizes, int n_in,
                              void* d_out, int out_size, void* d_ws, size_t ws_size,
                              hipStream_t stream) {
    const float* x      = (const float*)d_in[0];
    const int*   ei     = (const int*)d_in[1];
    const float* W1     = (const float*)d_in[2];
    const float* att_s1 = (const float*)d_in[3];
    const float* att_d1 = (const float*)d_in[4];
    const float* bias1  = (const float*)d_in[5];
    const float* W2     = (const float*)d_in[6];
    const float* att_s2 = (const float*)d_in[7];
    const float* att_d2 = (const float*)d_in[8];
    const float* bias2  = (const float*)d_in[9];
    const float* r1W    = (const float*)d_in[10];
    const float* r1b    = (const float*)d_in[11];
    const float* r2W    = (const float*)d_in[12];
    const float* r2b    = (const float*)d_in[13];
    float* out = (float*)d_out;

    float* ws   = (float*)d_ws;
    float* h1   = ws;                            // N*128
    float* hbuf = h1 + (size_t)Nn * 128;         // N*128 (res1, then h)
    float* h2v  = hbuf + (size_t)Nn * 128;       // N*40
    float* as1  = h2v + (size_t)Nn * 40;         // N*8
    float* ad1  = as1 + (size_t)Nn * 8;          // N*8
    float* as2  = ad1 + (size_t)Nn * 8;          // N
    float* ad2  = as2 + Nn;                      // N
    int* rs     = (int*)(ad2 + Nn);              // N+1
    int* cursor = rs + Nn + 1;                   // N
    int* csr    = cursor + Nn;                   // EP

    // ---- CSR build (by destination) ----
    zero_int_kernel<<<(Nn + 255) / 256, 256, 0, stream>>>(cursor, Nn);
    hist_kernel<<<(EP + 255) / 256, 256, 0, stream>>>(ei, cursor);
    scan_kernel<<<1, SCAN_T, 0, stream>>>(cursor, rs);
    scatter_kernel<<<(EP + 255) / 256, 256, 0, stream>>>(ei, cursor, csr);

    // ---- layer 1 ----
    gemm1_kernel<<<Nn / 16, 128, 0, stream>>>(x, W1, r1W, r1b, att_s1, att_d1,
                                              h1, hbuf, as1, ad1);
    agg1_kernel<<<(Nn + 3) / 4, 256, 0, stream>>>(rs, csr, as1, ad1, h1, bias1, hbuf);

    // ---- layer 2 ----
    gemm2_kernel<<<Nn / 4, 256, 0, stream>>>(hbuf, W2, r2W, r2b, att_s2, att_d2,
                                             h2v, out, as2, ad2);
    agg2_kernel<<<(Nn + 3) / 4, 256, 0, stream>>>(rs, csr, as2, ad2, h2v, bias2, out);
}

// Round 3
// 1041.426 us; speedup vs baseline: 3.9174x; 1.2172x over previous
//
#include <hip/hip_runtime.h>
#include <math.h>

#define Nn 100000
#define Ee 1600000
#define EP 1700000   /* Ee + Nn self loops */
#define NC 40
#define SLOPE 0.2f
#define NB_SCAN 391  /* ceil(Nn/256) */

// ---------- bf16 helpers ----------

__device__ __forceinline__ unsigned short f2bf(float f) {
    unsigned u = __float_as_uint(f);
    unsigned r = u + 0x7FFFu + ((u >> 16) & 1u);
    return (unsigned short)(r >> 16);
}
__device__ __forceinline__ float bf2f(unsigned short u) {
    return __uint_as_float(((unsigned)u) << 16);
}

// ---------------- CSR build ----------------

__global__ void zero_int_kernel(int* __restrict__ p, int n) {
    int i = blockIdx.x * 256 + threadIdx.x;
    if (i < n) p[i] = 0;
}

__global__ void hist_kernel(const int* __restrict__ ei, int* __restrict__ cnt) {
    int e = blockIdx.x * 256 + threadIdx.x;
    if (e >= EP) return;
    int d = (e < Ee) ? ei[Ee + e] : (e - Ee);
    atomicAdd(&cnt[d], 1);
}

// level-1: per-256-block exclusive scan of cnt -> rs (pre-offset), block sums -> bsum
__global__ __launch_bounds__(256) void scanA_kernel(const int* __restrict__ cnt,
                                                    int* __restrict__ rs,
                                                    int* __restrict__ bsum) {
    __shared__ int sh[256];
    int t = threadIdx.x;
    int i = blockIdx.x * 256 + t;
    int c = (i < Nn) ? cnt[i] : 0;
    sh[t] = c;
    __syncthreads();
    #pragma unroll
    for (int off = 1; off < 256; off <<= 1) {
        int v = (t >= off) ? sh[t - off] : 0;
        __syncthreads();
        sh[t] += v;
        __syncthreads();
    }
    if (i < Nn) rs[i] = sh[t] - c;          // exclusive
    if (t == 255) bsum[blockIdx.x] = sh[255];
}

// level-2: scan the NB_SCAN block sums (single block)
__global__ __launch_bounds__(512) void scanB_kernel(const int* __restrict__ bsum,
                                                    int* __restrict__ bpre,
                                                    int* __restrict__ rs) {
    __shared__ int sh[512];
    int t = threadIdx.x;
    int v = (t < NB_SCAN) ? bsum[t] : 0;
    sh[t] = v;
    __syncthreads();
    #pragma unroll
    for (int off = 1; off < 512; off <<= 1) {
        int u = (t >= off) ? sh[t - off] : 0;
        __syncthreads();
        sh[t] += u;
        __syncthreads();
    }
    if (t < NB_SCAN) bpre[t] = sh[t] - v;   // exclusive
    if (t == 0) rs[Nn] = EP;
}

// level-3: add block offsets, mirror into cursor
__global__ void scanC_kernel(int* __restrict__ rs, const int* __restrict__ bpre,
                             int* __restrict__ cursor) {
    int i = blockIdx.x * 256 + threadIdx.x;
    if (i >= Nn) return;
    int r = rs[i] + bpre[blockIdx.x];
    rs[i] = r;
    cursor[i] = r;
}

__global__ void scatter_kernel(const int* __restrict__ ei, int* __restrict__ cursor,
                               int* __restrict__ csr_src) {
    int e = blockIdx.x * 256 + threadIdx.x;
    if (e >= EP) return;
    int s, d;
    if (e < Ee) { s = ei[e]; d = ei[Ee + e]; }
    else        { s = e - Ee; d = s; }
    int pos = atomicAdd(&cursor[d], 1);
    csr_src[pos] = s;
}

// ---------------- layer 1 GEMM: h1b(bf16) = x@W1, hbuf = x@res1_W + res1_b ----------------

__global__ __launch_bounds__(128) void gemm1_kernel(
        const float* __restrict__ x,
        const float* __restrict__ W1, const float* __restrict__ Wr,
        const float* __restrict__ rb,
        const float* __restrict__ att_s, const float* __restrict__ att_d,
        unsigned short* __restrict__ h1b, float* __restrict__ hbuf,
        float* __restrict__ asrc, float* __restrict__ adst) {
    __shared__ float xs[16][128];
    int t = threadIdx.x;
    int n0 = blockIdx.x * 16;
    #pragma unroll
    for (int i = 0; i < 16; i++) xs[i][t] = x[(size_t)(n0 + i) * 128 + t];
    __syncthreads();

    float acch[16], accr[16];
    #pragma unroll
    for (int i = 0; i < 16; i++) { acch[i] = 0.f; accr[i] = 0.f; }

    for (int k = 0; k < 128; k += 4) {
        float w1a[4], wra[4];
        #pragma unroll
        for (int j = 0; j < 4; j++) {
            w1a[j] = W1[(k + j) * 128 + t];
            wra[j] = Wr[(k + j) * 128 + t];
        }
        #pragma unroll
        for (int i = 0; i < 16; i++) {
            float4 xv = *(const float4*)&xs[i][k];
            acch[i] += xv.x * w1a[0] + xv.y * w1a[1] + xv.z * w1a[2] + xv.w * w1a[3];
            accr[i] += xv.x * wra[0] + xv.y * wra[1] + xv.z * wra[2] + xv.w * wra[3];
        }
    }

    float bias = rb[t];
    float asw = att_s[t];
    float adw = att_d[t];
    #pragma unroll
    for (int i = 0; i < 16; i++) {
        int n = n0 + i;
        h1b[(size_t)n * 128 + t] = f2bf(acch[i]);
        hbuf[(size_t)n * 128 + t] = accr[i] + bias;
        float vs = acch[i] * asw;
        float vd = acch[i] * adw;
        #pragma unroll
        for (int m = 8; m >= 1; m >>= 1) {
            vs += __shfl_xor(vs, m, 16);
            vd += __shfl_xor(vd, m, 16);
        }
        if ((t & 15) == 0) {
            asrc[n * 8 + (t >> 4)] = vs;
            adst[n * 8 + (t >> 4)] = vd;
        }
    }
}

// ---------------- layer 1 gather-aggregate: one wave per dst ----------------

__global__ __launch_bounds__(256) void agg1_kernel(
        const int* __restrict__ rs, const int* __restrict__ csr,
        const float* __restrict__ as, const float* __restrict__ ad,
        const unsigned short* __restrict__ h1b, const float* __restrict__ bias,
        float* __restrict__ hbuf) {
    int lane = threadIdx.x & 63, wv = threadIdx.x >> 6;
    int n = blockIdx.x * 4 + wv;
    if (n >= Nn) return;
    int row = rs[n], end = rs[n + 1];
    int h = lane & 7;
    int j8 = lane >> 3;
    float adh = ad[n * 8 + h];

    // phase 1: per-head max (8 edges in flight across lane groups)
    float m = -3.4e38f;
    for (int j = row + j8; j < end; j += 8) {
        int s = csr[j];
        float v = as[s * 8 + h] + adh;
        v = v > 0.f ? v : SLOPE * v;
        m = fmaxf(m, v);
    }
    m = fmaxf(m, __shfl_xor(m, 8, 64));
    m = fmaxf(m, __shfl_xor(m, 16, 64));
    m = fmaxf(m, __shfl_xor(m, 32, 64));

    // phase 2: per-head sum of exp
    float se = 0.f;
    for (int j = row + j8; j < end; j += 8) {
        int s = csr[j];
        float v = as[s * 8 + h] + adh;
        v = v > 0.f ? v : SLOPE * v;
        se += __expf(v - m);
    }
    se += __shfl_xor(se, 8, 64);
    se += __shfl_xor(se, 16, 64);
    se += __shfl_xor(se, 32, 64);
    float inv = 1.f / se;

    // phase 3: weighted gather. lane owns cols {2*lane, 2*lane+1}; head = lane>>3.
    float acc0 = 0.f, acc1 = 0.f;
    int c0 = lane * 2;
    int hh = lane >> 3;
    for (int j = row; j < end; j++) {
        int s = csr[j];
        float v = as[s * 8 + h] + adh;
        v = v > 0.f ? v : SLOPE * v;
        float alpha = __expf(v - m) * inv;      // for head lane&7
        float aa = __shfl(alpha, hh, 64);       // alpha for head lane>>3
        ushort2 hv = *(const ushort2*)(h1b + (size_t)s * 128 + c0);
        acc0 += aa * bf2f(hv.x);
        acc1 += aa * bf2f(hv.y);
    }

    // epilogue: bias + ELU + residual add (hbuf holds x@res1_W + res1_b)
    float g0 = acc0 + bias[c0];
    float g1 = acc1 + bias[c0 + 1];
    g0 = g0 > 0.f ? g0 : expm1f(g0);
    g1 = g1 > 0.f ? g1 : expm1f(g1);
    float2* hp = (float2*)(hbuf + (size_t)n * 128 + c0);
    float2 r = *hp;
    r.x += g0; r.y += g1;
    *hp = r;
}

// ---------------- layer 2 GEMM: h2b(bf16) = h@W2, res -> out ----------------

__global__ __launch_bounds__(256) void gemm2_kernel(
        const float* __restrict__ h,
        const float* __restrict__ W2, const float* __restrict__ Wr,
        const float* __restrict__ rb,
        const float* __restrict__ att_s, const float* __restrict__ att_d,
        unsigned short* __restrict__ h2b, float* __restrict__ resout,
        float* __restrict__ as2, float* __restrict__ ad2) {
    __shared__ float hs[4][128];
    int lane = threadIdx.x & 63, wv = threadIdx.x >> 6;
    int n = blockIdx.x * 4 + wv;
    hs[wv][lane]      = h[(size_t)n * 128 + lane];
    hs[wv][lane + 64] = h[(size_t)n * 128 + 64 + lane];
    __syncthreads();
    float acc = 0.f, accr = 0.f;
    int c = lane;
    if (c < NC) {
        for (int k = 0; k < 128; k++) {
            float hv = hs[wv][k];
            acc  += hv * W2[k * NC + c];
            accr += hv * Wr[k * NC + c];
        }
    }
    float vs = c < NC ? acc * att_s[c] : 0.f;
    float vd = c < NC ? acc * att_d[c] : 0.f;
    #pragma unroll
    for (int m = 32; m >= 1; m >>= 1) {
        vs += __shfl_xor(vs, m, 64);
        vd += __shfl_xor(vd, m, 64);
    }
    if (c < NC) {
        h2b[(size_t)n * NC + c] = f2bf(acc);
        resout[(size_t)n * NC + c] = accr + rb[c];
    }
    if (lane == 0) { as2[n] = vs; ad2[n] = vd; }
}

// ---------------- layer 2 gather-aggregate + log_softmax ----------------

__global__ __launch_bounds__(256) void agg2_kernel(
        const int* __restrict__ rs, const int* __restrict__ csr,
        const float* __restrict__ as, const float* __restrict__ ad,
        const unsigned short* __restrict__ h2b, const float* __restrict__ b2,
        float* __restrict__ outp) {
    int lane = threadIdx.x & 63, wv = threadIdx.x >> 6;
    int n = blockIdx.x * 4 + wv;
    if (n >= Nn) return;
    int row = rs[n], end = rs[n + 1];
    float adn = ad[n];

    float m = -3.4e38f;
    for (int j = row + lane; j < end; j += 64) {
        float v = as[csr[j]] + adn;
        v = v > 0.f ? v : SLOPE * v;
        m = fmaxf(m, v);
    }
    #pragma unroll
    for (int st = 32; st >= 1; st >>= 1) m = fmaxf(m, __shfl_xor(m, st, 64));

    float se = 0.f;
    for (int j = row + lane; j < end; j += 64) {
        float v = as[csr[j]] + adn;
        v = v > 0.f ? v : SLOPE * v;
        se += __expf(v - m);
    }
    #pragma unroll
    for (int st = 32; st >= 1; st >>= 1) se += __shfl_xor(se, st, 64);
    float inv = 1.f / se;

    float acc = 0.f;
    for (int j = row; j < end; j++) {
        int s = csr[j];
        float v = as[s] + adn;
        v = v > 0.f ? v : SLOPE * v;
        float alpha = __expf(v - m) * inv;
        if (lane < NC) acc += alpha * bf2f(h2b[(size_t)s * NC + lane]);
    }

    // epilogue: + bias2 + residual (outp holds h@res2_W + res2_b), then log_softmax
    bool act = lane < NC;
    float v = act ? acc + b2[lane] + outp[(size_t)n * NC + lane] : -3.4e38f;
    float mm = v;
    #pragma unroll
    for (int st = 32; st >= 1; st >>= 1) mm = fmaxf(mm, __shfl_xor(mm, st, 64));
    float ex = act ? __expf(v - mm) : 0.f;
    float ss = ex;
    #pragma unroll
    for (int st = 32; st >= 1; st >>= 1) ss += __shfl_xor(ss, st, 64);
    if (act) outp[(size_t)n * NC + lane] = v - mm - logf(ss);
}

// ---------------- host ----------------

extern "C" void kernel_launch(void* const* d_in, const int* in_sizes, int n_in,
                              void* d_out, int out_size, void* d_ws, size_t ws_size,
                              hipStream_t stream) {
    const float* x      = (const float*)d_in[0];
    const int*   ei     = (const int*)d_in[1];
    const float* W1     = (const float*)d_in[2];
    const float* att_s1 = (const float*)d_in[3];
    const float* att_d1 = (const float*)d_in[4];
    const float* bias1  = (const float*)d_in[5];
    const float* W2     = (const float*)d_in[6];
    const float* att_s2 = (const float*)d_in[7];
    const float* att_d2 = (const float*)d_in[8];
    const float* bias2  = (const float*)d_in[9];
    const float* r1W    = (const float*)d_in[10];
    const float* r1b    = (const float*)d_in[11];
    const float* r2W    = (const float*)d_in[12];
    const float* r2b    = (const float*)d_in[13];
    float* out = (float*)d_out;

    float* ws   = (float*)d_ws;
    float* hbuf = ws;                            // N*128 f32 (res1, then h)
    float* as1  = hbuf + (size_t)Nn * 128;       // N*8
    float* ad1  = as1 + (size_t)Nn * 8;          // N*8
    float* as2  = ad1 + (size_t)Nn * 8;          // N
    float* ad2  = as2 + Nn;                      // N
    unsigned short* h1b = (unsigned short*)(ad2 + Nn);   // N*128 bf16
    unsigned short* h2b = h1b + (size_t)Nn * 128;        // N*40 bf16
    int* rs     = (int*)(h2b + (size_t)Nn * 40); // N+1
    int* cnt    = rs + Nn + 1;                   // N
    int* cursor = cnt + Nn;                      // N
    int* bsum   = cursor + Nn;                   // NB_SCAN
    int* bpre   = bsum + NB_SCAN;                // NB_SCAN
    int* csr    = bpre + NB_SCAN;                // EP

    // ---- CSR build (by destination) ----
    zero_int_kernel<<<(Nn + 255) / 256, 256, 0, stream>>>(cnt, Nn);
    hist_kernel<<<(EP + 255) / 256, 256, 0, stream>>>(ei, cnt);
    scanA_kernel<<<NB_SCAN, 256, 0, stream>>>(cnt, rs, bsum);
    scanB_kernel<<<1, 512, 0, stream>>>(bsum, bpre, rs);
    scanC_kernel<<<NB_SCAN, 256, 0, stream>>>(rs, bpre, cursor);
    scatter_kernel<<<(EP + 255) / 256, 256, 0, stream>>>(ei, cursor, csr);

    // ---- layer 1 ----
    gemm1_kernel<<<Nn / 16, 128, 0, stream>>>(x, W1, r1W, r1b, att_s1, att_d1,
                                              h1b, hbuf, as1, ad1);
    agg1_kernel<<<(Nn + 3) / 4, 256, 0, stream>>>(rs, csr, as1, ad1, h1b, bias1, hbuf);

    // ---- layer 2 ----
    gemm2_kernel<<<Nn / 4, 256, 0, stream>>>(hbuf, W2, r2W, r2b, att_s2, att_d2,
                                             h2b, out, as2, ad2);
    agg2_kernel<<<(Nn + 3) / 4, 256, 0, stream>>>(rs, csr, as2, ad2, h2b, bias2, out);
}

// Round 4
// 878.763 us; speedup vs baseline: 4.6426x; 1.1851x over previous
//
#include <hip/hip_runtime.h>
#include <math.h>

#define Nn 100000
#define Ee 1600000
#define EP 1700000   /* Ee + Nn self loops */
#define NC 40
#define SLOPE 0.2f
#define NB_SCAN 391  /* ceil(Nn/256) */
#define CAP 128      /* max edges cached in LDS per node (fallback recomputes) */

// ---------- bf16 helpers ----------

__device__ __forceinline__ unsigned short f2bf(float f) {
    unsigned u = __float_as_uint(f);
    unsigned r = u + 0x7FFFu + ((u >> 16) & 1u);
    return (unsigned short)(r >> 16);
}
__device__ __forceinline__ float bf2f(unsigned short u) {
    return __uint_as_float(((unsigned)u) << 16);
}

// ---------------- CSR build ----------------

__global__ void zero_int_kernel(int* __restrict__ p, int n) {
    int i = blockIdx.x * 256 + threadIdx.x;
    if (i < n) p[i] = 0;
}

__global__ void hist_kernel(const int* __restrict__ ei, int* __restrict__ cnt) {
    int e = blockIdx.x * 256 + threadIdx.x;
    if (e >= EP) return;
    int d = (e < Ee) ? ei[Ee + e] : (e - Ee);
    atomicAdd(&cnt[d], 1);
}

__global__ __launch_bounds__(256) void scanA_kernel(const int* __restrict__ cnt,
                                                    int* __restrict__ rs,
                                                    int* __restrict__ bsum) {
    __shared__ int sh[256];
    int t = threadIdx.x;
    int i = blockIdx.x * 256 + t;
    int c = (i < Nn) ? cnt[i] : 0;
    sh[t] = c;
    __syncthreads();
    #pragma unroll
    for (int off = 1; off < 256; off <<= 1) {
        int v = (t >= off) ? sh[t - off] : 0;
        __syncthreads();
        sh[t] += v;
        __syncthreads();
    }
    if (i < Nn) rs[i] = sh[t] - c;
    if (t == 255) bsum[blockIdx.x] = sh[255];
}

__global__ __launch_bounds__(512) void scanB_kernel(const int* __restrict__ bsum,
                                                    int* __restrict__ bpre,
                                                    int* __restrict__ rs) {
    __shared__ int sh[512];
    int t = threadIdx.x;
    int v = (t < NB_SCAN) ? bsum[t] : 0;
    sh[t] = v;
    __syncthreads();
    #pragma unroll
    for (int off = 1; off < 512; off <<= 1) {
        int u = (t >= off) ? sh[t - off] : 0;
        __syncthreads();
        sh[t] += u;
        __syncthreads();
    }
    if (t < NB_SCAN) bpre[t] = sh[t] - v;
    if (t == 0) rs[Nn] = EP;
}

__global__ void scanC_kernel(int* __restrict__ rs, const int* __restrict__ bpre,
                             int* __restrict__ cursor) {
    int i = blockIdx.x * 256 + threadIdx.x;
    if (i >= Nn) return;
    int r = rs[i] + bpre[blockIdx.x];
    rs[i] = r;
    cursor[i] = r;
}

__global__ void scatter_kernel(const int* __restrict__ ei, int* __restrict__ cursor,
                               int* __restrict__ csr_src) {
    int e = blockIdx.x * 256 + threadIdx.x;
    if (e >= EP) return;
    int s, d;
    if (e < Ee) { s = ei[e]; d = ei[Ee + e]; }
    else        { s = e - Ee; d = s; }
    int pos = atomicAdd(&cursor[d], 1);
    csr_src[pos] = s;
}

// ---------------- layer 1 GEMM ----------------

__global__ __launch_bounds__(128) void gemm1_kernel(
        const float* __restrict__ x,
        const float* __restrict__ W1, const float* __restrict__ Wr,
        const float* __restrict__ rb,
        const float* __restrict__ att_s, const float* __restrict__ att_d,
        unsigned short* __restrict__ h1b, float* __restrict__ hbuf,
        float* __restrict__ asrc, float* __restrict__ adst) {
    __shared__ float xs[16][128];
    int t = threadIdx.x;
    int n0 = blockIdx.x * 16;
    #pragma unroll
    for (int i = 0; i < 16; i++) xs[i][t] = x[(size_t)(n0 + i) * 128 + t];
    __syncthreads();

    float acch[16], accr[16];
    #pragma unroll
    for (int i = 0; i < 16; i++) { acch[i] = 0.f; accr[i] = 0.f; }

    for (int k = 0; k < 128; k += 4) {
        float w1a[4], wra[4];
        #pragma unroll
        for (int j = 0; j < 4; j++) {
            w1a[j] = W1[(k + j) * 128 + t];
            wra[j] = Wr[(k + j) * 128 + t];
        }
        #pragma unroll
        for (int i = 0; i < 16; i++) {
            float4 xv = *(const float4*)&xs[i][k];
            acch[i] += xv.x * w1a[0] + xv.y * w1a[1] + xv.z * w1a[2] + xv.w * w1a[3];
            accr[i] += xv.x * wra[0] + xv.y * wra[1] + xv.z * wra[2] + xv.w * wra[3];
        }
    }

    float bias = rb[t];
    float asw = att_s[t];
    float adw = att_d[t];
    #pragma unroll
    for (int i = 0; i < 16; i++) {
        int n = n0 + i;
        h1b[(size_t)n * 128 + t] = f2bf(acch[i]);
        hbuf[(size_t)n * 128 + t] = accr[i] + bias;
        float vs = acch[i] * asw;
        float vd = acch[i] * adw;
        #pragma unroll
        for (int m = 8; m >= 1; m >>= 1) {
            vs += __shfl_xor(vs, m, 16);
            vd += __shfl_xor(vd, m, 16);
        }
        if ((t & 15) == 0) {
            asrc[n * 8 + (t >> 4)] = vs;
            adst[n * 8 + (t >> 4)] = vd;
        }
    }
}

// ---------------- layer 1 gather-aggregate ----------------
// wave per node. LDS caches per-edge logit -> exp across phases.

__global__ __launch_bounds__(256) void agg1_kernel(
        const int* __restrict__ rs, const int* __restrict__ csr,
        const float* __restrict__ as, const float* __restrict__ ad,
        const unsigned short* __restrict__ h1b, const float* __restrict__ bias,
        float* __restrict__ hbuf) {
    __shared__ float ash[4][CAP * 8];
    int lane = threadIdx.x & 63, wv = threadIdx.x >> 6;
    int n = blockIdx.x * 4 + wv;
    if (n >= Nn) return;
    int row = rs[n], end = rs[n + 1];
    int h = lane & 7;
    int j8 = lane >> 3;
    float adh = ad[n * 8 + h];
    float* myash = &ash[wv][0];

    // phase 1: gather logits ONCE, cache in LDS, per-head max
    float m = -3.4e38f;
    for (int j = row + j8; j < end; j += 8) {
        int s = csr[j];
        float v = as[s * 8 + h] + adh;
        v = v > 0.f ? v : SLOPE * v;
        int rel = j - row;
        if (rel < CAP) myash[rel * 8 + h] = v;
        m = fmaxf(m, v);
    }
    m = fmaxf(m, __shfl_xor(m, 8, 64));
    m = fmaxf(m, __shfl_xor(m, 16, 64));
    m = fmaxf(m, __shfl_xor(m, 32, 64));

    // phase 2: exp from LDS, cache exp back, per-head sum
    float se = 0.f;
    for (int j = row + j8; j < end; j += 8) {
        int rel = j - row;
        float v;
        if (rel < CAP) v = myash[rel * 8 + h];
        else {
            int s = csr[j];
            v = as[s * 8 + h] + adh;
            v = v > 0.f ? v : SLOPE * v;
        }
        float e = __expf(v - m);
        se += e;
        if (rel < CAP) myash[rel * 8 + h] = e;
    }
    se += __shfl_xor(se, 8, 64);
    se += __shfl_xor(se, 16, 64);
    se += __shfl_xor(se, 32, 64);
    float inv = 1.f / se;

    // per-lane constants for phase 3: lane owns cols {2*lane, 2*lane+1}, head hh
    int c0 = lane * 2;
    int hh = lane >> 3;
    float inv_hh = __shfl(inv, hh, 64);
    float m_keep = m;  // per-lane m for head h (fallback path)

    // phase 3: weighted gather, 2-edge unroll, alpha from LDS
    float a0a = 0.f, a1a = 0.f, a0b = 0.f, a1b = 0.f;
    int j = row;
    for (; j + 2 <= end; j += 2) {
        int rel = j - row;
        int s0 = csr[j], s1 = csr[j + 1];
        float e0, e1;
        if (rel + 1 < CAP) {
            e0 = myash[rel * 8 + hh];
            e1 = myash[rel * 8 + 8 + hh];
        } else {
            float v0 = as[s0 * 8 + h] + adh; v0 = v0 > 0.f ? v0 : SLOPE * v0;
            float v1 = as[s1 * 8 + h] + adh; v1 = v1 > 0.f ? v1 : SLOPE * v1;
            float q0 = __expf(v0 - m_keep), q1 = __expf(v1 - m_keep);
            e0 = __shfl(q0, hh, 64);
            e1 = __shfl(q1, hh, 64);
        }
        ushort2 u0 = *(const ushort2*)(h1b + (size_t)s0 * 128 + c0);
        ushort2 u1 = *(const ushort2*)(h1b + (size_t)s1 * 128 + c0);
        float al0 = e0 * inv_hh, al1 = e1 * inv_hh;
        a0a += al0 * bf2f(u0.x); a1a += al0 * bf2f(u0.y);
        a0b += al1 * bf2f(u1.x); a1b += al1 * bf2f(u1.y);
    }
    if (j < end) {
        int rel = j - row;
        int s0 = csr[j];
        float e0;
        if (rel < CAP) e0 = myash[rel * 8 + hh];
        else {
            float v0 = as[s0 * 8 + h] + adh; v0 = v0 > 0.f ? v0 : SLOPE * v0;
            float q0 = __expf(v0 - m_keep);
            e0 = __shfl(q0, hh, 64);
        }
        ushort2 u0 = *(const ushort2*)(h1b + (size_t)s0 * 128 + c0);
        float al0 = e0 * inv_hh;
        a0a += al0 * bf2f(u0.x); a1a += al0 * bf2f(u0.y);
    }
    float acc0 = a0a + a0b, acc1 = a1a + a1b;

    // epilogue: bias + ELU + residual add (hbuf holds x@res1_W + res1_b)
    float g0 = acc0 + bias[c0];
    float g1 = acc1 + bias[c0 + 1];
    g0 = g0 > 0.f ? g0 : expm1f(g0);
    g1 = g1 > 0.f ? g1 : expm1f(g1);
    float2* hp = (float2*)(hbuf + (size_t)n * 128 + c0);
    float2 r = *hp;
    r.x += g0; r.y += g1;
    *hp = r;
}

// ---------------- layer 2 GEMM ----------------

__global__ __launch_bounds__(256) void gemm2_kernel(
        const float* __restrict__ h,
        const float* __restrict__ W2, const float* __restrict__ Wr,
        const float* __restrict__ rb,
        const float* __restrict__ att_s, const float* __restrict__ att_d,
        unsigned short* __restrict__ h2b, float* __restrict__ resout,
        float* __restrict__ as2, float* __restrict__ ad2) {
    __shared__ float hs[4][128];
    int lane = threadIdx.x & 63, wv = threadIdx.x >> 6;
    int n = blockIdx.x * 4 + wv;
    hs[wv][lane]      = h[(size_t)n * 128 + lane];
    hs[wv][lane + 64] = h[(size_t)n * 128 + 64 + lane];
    __syncthreads();
    float acc = 0.f, accr = 0.f;
    int c = lane;
    if (c < NC) {
        for (int k = 0; k < 128; k++) {
            float hv = hs[wv][k];
            acc  += hv * W2[k * NC + c];
            accr += hv * Wr[k * NC + c];
        }
    }
    float vs = c < NC ? acc * att_s[c] : 0.f;
    float vd = c < NC ? acc * att_d[c] : 0.f;
    #pragma unroll
    for (int m = 32; m >= 1; m >>= 1) {
        vs += __shfl_xor(vs, m, 64);
        vd += __shfl_xor(vd, m, 64);
    }
    if (c < NC) {
        h2b[(size_t)n * NC + c] = f2bf(acc);
        resout[(size_t)n * NC + c] = accr + rb[c];
    }
    if (lane == 0) { as2[n] = vs; ad2[n] = vd; }
}

// ---------------- layer 2 gather-aggregate + log_softmax ----------------

__global__ __launch_bounds__(256) void agg2_kernel(
        const int* __restrict__ rs, const int* __restrict__ csr,
        const float* __restrict__ as, const float* __restrict__ ad,
        const unsigned short* __restrict__ h2b, const float* __restrict__ b2,
        float* __restrict__ outp) {
    __shared__ float ash[4][CAP];
    int lane = threadIdx.x & 63, wv = threadIdx.x >> 6;
    int n = blockIdx.x * 4 + wv;
    if (n >= Nn) return;
    int row = rs[n], end = rs[n + 1];
    float adn = ad[n];
    float* myash = &ash[wv][0];

    // phase 1: gather logits once, cache, max
    float m = -3.4e38f;
    for (int j = row + lane; j < end; j += 64) {
        float v = as[csr[j]] + adn;
        v = v > 0.f ? v : SLOPE * v;
        int rel = j - row;
        if (rel < CAP) myash[rel] = v;
        m = fmaxf(m, v);
    }
    #pragma unroll
    for (int st = 32; st >= 1; st >>= 1) m = fmaxf(m, __shfl_xor(m, st, 64));

    // phase 2: exp from LDS, cache exp, sum
    float se = 0.f;
    for (int j = row + lane; j < end; j += 64) {
        int rel = j - row;
        float v;
        if (rel < CAP) v = myash[rel];
        else { v = as[csr[j]] + adn; v = v > 0.f ? v : SLOPE * v; }
        float e = __expf(v - m);
        se += e;
        if (rel < CAP) myash[rel] = e;
    }
    #pragma unroll
    for (int st = 32; st >= 1; st >>= 1) se += __shfl_xor(se, st, 64);
    float inv = 1.f / se;

    // phase 3: weighted gather, 2-edge unroll
    float accA = 0.f, accB = 0.f;
    bool act = lane < NC;
    int j = row;
    for (; j + 2 <= end; j += 2) {
        int rel = j - row;
        int s0 = csr[j], s1 = csr[j + 1];
        float e0, e1;
        if (rel + 1 < CAP) { e0 = myash[rel]; e1 = myash[rel + 1]; }
        else {
            float v0 = as[s0] + adn; v0 = v0 > 0.f ? v0 : SLOPE * v0;
            float v1 = as[s1] + adn; v1 = v1 > 0.f ? v1 : SLOPE * v1;
            e0 = __expf(v0 - m); e1 = __expf(v1 - m);
        }
        if (act) {
            float x0 = bf2f(h2b[(size_t)s0 * NC + lane]);
            float x1 = bf2f(h2b[(size_t)s1 * NC + lane]);
            accA += (e0 * inv) * x0;
            accB += (e1 * inv) * x1;
        }
    }
    if (j < end) {
        int rel = j - row;
        int s0 = csr[j];
        float e0;
        if (rel < CAP) e0 = myash[rel];
        else { float v0 = as[s0] + adn; v0 = v0 > 0.f ? v0 : SLOPE * v0; e0 = __expf(v0 - m); }
        if (act) accA += (e0 * inv) * bf2f(h2b[(size_t)s0 * NC + lane]);
    }
    float acc = accA + accB;

    // epilogue: + bias2 + residual (outp holds h@res2_W + res2_b), then log_softmax
    float v = act ? acc + b2[lane] + outp[(size_t)n * NC + lane] : -3.4e38f;
    float mm = v;
    #pragma unroll
    for (int st = 32; st >= 1; st >>= 1) mm = fmaxf(mm, __shfl_xor(mm, st, 64));
    float ex = act ? __expf(v - mm) : 0.f;
    float ss = ex;
    #pragma unroll
    for (int st = 32; st >= 1; st >>= 1) ss += __shfl_xor(ss, st, 64);
    if (act) outp[(size_t)n * NC + lane] = v - mm - logf(ss);
}

// ---------------- host ----------------

extern "C" void kernel_launch(void* const* d_in, const int* in_sizes, int n_in,
                              void* d_out, int out_size, void* d_ws, size_t ws_size,
                              hipStream_t stream) {
    const float* x      = (const float*)d_in[0];
    const int*   ei     = (const int*)d_in[1];
    const float* W1     = (const float*)d_in[2];
    const float* att_s1 = (const float*)d_in[3];
    const float* att_d1 = (const float*)d_in[4];
    const float* bias1  = (const float*)d_in[5];
    const float* W2     = (const float*)d_in[6];
    const float* att_s2 = (const float*)d_in[7];
    const float* att_d2 = (const float*)d_in[8];
    const float* bias2  = (const float*)d_in[9];
    const float* r1W    = (const float*)d_in[10];
    const float* r1b    = (const float*)d_in[11];
    const float* r2W    = (const float*)d_in[12];
    const float* r2b    = (const float*)d_in[13];
    float* out = (float*)d_out;

    float* ws   = (float*)d_ws;
    float* hbuf = ws;                            // N*128 f32 (res1, then h)
    float* as1  = hbuf + (size_t)Nn * 128;       // N*8
    float* ad1  = as1 + (size_t)Nn * 8;          // N*8
    float* as2  = ad1 + (size_t)Nn * 8;          // N
    float* ad2  = as2 + Nn;                      // N
    unsigned short* h1b = (unsigned short*)(ad2 + Nn);   // N*128 bf16
    unsigned short* h2b = h1b + (size_t)Nn * 128;        // N*40 bf16
    int* rs     = (int*)(h2b + (size_t)Nn * 40); // N+1
    int* cnt    = rs + Nn + 1;                   // N
    int* cursor = cnt + Nn;                      // N
    int* bsum   = cursor + Nn;                   // NB_SCAN
    int* bpre   = bsum + NB_SCAN;                // NB_SCAN
    int* csr    = bpre + NB_SCAN;                // EP

    // ---- CSR build (by destination) ----
    zero_int_kernel<<<(Nn + 255) / 256, 256, 0, stream>>>(cnt, Nn);
    hist_kernel<<<(EP + 255) / 256, 256, 0, stream>>>(ei, cnt);
    scanA_kernel<<<NB_SCAN, 256, 0, stream>>>(cnt, rs, bsum);
    scanB_kernel<<<1, 512, 0, stream>>>(bsum, bpre, rs);
    scanC_kernel<<<NB_SCAN, 256, 0, stream>>>(rs, bpre, cursor);
    scatter_kernel<<<(EP + 255) / 256, 256, 0, stream>>>(ei, cursor, csr);

    // ---- layer 1 ----
    gemm1_kernel<<<Nn / 16, 128, 0, stream>>>(x, W1, r1W, r1b, att_s1, att_d1,
                                              h1b, hbuf, as1, ad1);
    agg1_kernel<<<(Nn + 3) / 4, 256, 0, stream>>>(rs, csr, as1, ad1, h1b, bias1, hbuf);

    // ---- layer 2 ----
    gemm2_kernel<<<Nn / 4, 256, 0, stream>>>(hbuf, W2, r2W, r2b, att_s2, att_d2,
                                             h2b, out, as2, ad2);
    agg2_kernel<<<(Nn + 3) / 4, 256, 0, stream>>>(rs, csr, as2, ad2, h2b, bias2, out);
}

// Round 5
// 715.026 us; speedup vs baseline: 5.7057x; 1.2290x over previous
//
#include <hip/hip_runtime.h>
#include <math.h>

#define Nn 100000
#define Ee 1600000
#define EP 1700000   /* Ee + Nn self loops */
#define NC 40
#define SLOPE 0.2f
#define NB_SCAN 391  /* ceil(Nn/256) */
#define CAP 128      /* max edges cached in LDS per node (fallback recomputes) */

typedef short bf16x8 __attribute__((ext_vector_type(8)));
typedef float f32x4 __attribute__((ext_vector_type(4)));

// ---------- bf16 helpers ----------

__device__ __forceinline__ unsigned short f2bf(float f) {
    unsigned u = __float_as_uint(f);
    unsigned r = u + 0x7FFFu + ((u >> 16) & 1u);
    return (unsigned short)(r >> 16);
}
__device__ __forceinline__ float bf2f(unsigned short u) {
    return __uint_as_float(((unsigned)u) << 16);
}

// ---------------- CSR build ----------------

__global__ void zero_int_kernel(int* __restrict__ p, int n) {
    int i = blockIdx.x * 256 + threadIdx.x;
    if (i < n) p[i] = 0;
}

__global__ void hist_kernel(const int* __restrict__ ei, int* __restrict__ cnt) {
    int e = blockIdx.x * 256 + threadIdx.x;
    if (e >= EP) return;
    int d = (e < Ee) ? ei[Ee + e] : (e - Ee);
    atomicAdd(&cnt[d], 1);
}

__global__ __launch_bounds__(256) void scanA_kernel(const int* __restrict__ cnt,
                                                    int* __restrict__ rs,
                                                    int* __restrict__ bsum) {
    __shared__ int sh[256];
    int t = threadIdx.x;
    int i = blockIdx.x * 256 + t;
    int c = (i < Nn) ? cnt[i] : 0;
    sh[t] = c;
    __syncthreads();
    #pragma unroll
    for (int off = 1; off < 256; off <<= 1) {
        int v = (t >= off) ? sh[t - off] : 0;
        __syncthreads();
        sh[t] += v;
        __syncthreads();
    }
    if (i < Nn) rs[i] = sh[t] - c;
    if (t == 255) bsum[blockIdx.x] = sh[255];
}

__global__ __launch_bounds__(512) void scanB_kernel(const int* __restrict__ bsum,
                                                    int* __restrict__ bpre,
                                                    int* __restrict__ rs) {
    __shared__ int sh[512];
    int t = threadIdx.x;
    int v = (t < NB_SCAN) ? bsum[t] : 0;
    sh[t] = v;
    __syncthreads();
    #pragma unroll
    for (int off = 1; off < 512; off <<= 1) {
        int u = (t >= off) ? sh[t - off] : 0;
        __syncthreads();
        sh[t] += u;
        __syncthreads();
    }
    if (t < NB_SCAN) bpre[t] = sh[t] - v;
    if (t == 0) rs[Nn] = EP;
}

__global__ void scanC_kernel(int* __restrict__ rs, const int* __restrict__ bpre,
                             int* __restrict__ cursor) {
    int i = blockIdx.x * 256 + threadIdx.x;
    if (i >= Nn) return;
    int r = rs[i] + bpre[blockIdx.x];
    rs[i] = r;
    cursor[i] = r;
}

__global__ void scatter_kernel(const int* __restrict__ ei, int* __restrict__ cursor,
                               int* __restrict__ csr_src) {
    int e = blockIdx.x * 256 + threadIdx.x;
    if (e >= EP) return;
    int s, d;
    if (e < Ee) { s = ei[e]; d = ei[Ee + e]; }
    else        { s = e - Ee; d = s; }
    int pos = atomicAdd(&cursor[d], 1);
    csr_src[pos] = s;
}

// ---------------- weight cast/transpose: Wb1t[256][128], Wb2t[80][128] ----------------

__global__ void castW_kernel(const float* __restrict__ W1, const float* __restrict__ r1W,
                             const float* __restrict__ W2, const float* __restrict__ r2W,
                             unsigned short* __restrict__ Wb1t, unsigned short* __restrict__ Wb2t) {
    int tid = blockIdx.x * 256 + threadIdx.x;
    if (tid < 256 * 128) {
        int col = tid >> 7, k = tid & 127;
        float v = (col < 128) ? W1[k * 128 + col] : r1W[k * 128 + (col - 128)];
        Wb1t[col * 128 + k] = f2bf(v);
    } else if (tid < 256 * 128 + 80 * 128) {
        int t2 = tid - 256 * 128;
        int col = t2 >> 7, k = t2 & 127;
        float v = (col < NC) ? W2[k * NC + col] : r2W[k * NC + (col - NC)];
        Wb2t[col * 128 + k] = f2bf(v);
    }
}

// ---------------- layer 1 GEMM (MFMA): h1b = bf16(x@W1), hbuf = x@r1W + r1b, as1/ad1 ----------------
// 16 rows per block, 4 waves; wave w covers col-tiles 4w..4w+3 (cols 64w..64w+63) of N=256.
// C/D layout: col=lane&15, row=(lane>>4)*4+reg. A: A[m=lane&15][k=quad*8+j].

__global__ __launch_bounds__(256) void gemm1_kernel(
        const float* __restrict__ x, const unsigned short* __restrict__ Wb1t,
        const float* __restrict__ r1b,
        const float* __restrict__ att_s, const float* __restrict__ att_d,
        unsigned short* __restrict__ h1b, float* __restrict__ hbuf,
        float* __restrict__ as1, float* __restrict__ ad1) {
    __shared__ float sh_as[16][8], sh_ad[16][8];
    int lane = threadIdx.x & 63, wv = threadIdx.x >> 6;
    int m = lane & 15, q = lane >> 4;
    int row0 = blockIdx.x * 16;

    // A fragments: x row (fp32) -> bf16, 4 K-steps of 32
    union { unsigned short u[8]; bf16x8 v; } af[4];
    const float* xr = x + (size_t)(row0 + m) * 128 + q * 8;
    #pragma unroll
    for (int kk = 0; kk < 4; kk++) {
        float4 a0 = *(const float4*)(xr + kk * 32);
        float4 a1 = *(const float4*)(xr + kk * 32 + 4);
        af[kk].u[0] = f2bf(a0.x); af[kk].u[1] = f2bf(a0.y);
        af[kk].u[2] = f2bf(a0.z); af[kk].u[3] = f2bf(a0.w);
        af[kk].u[4] = f2bf(a1.x); af[kk].u[5] = f2bf(a1.y);
        af[kk].u[6] = f2bf(a1.z); af[kk].u[7] = f2bf(a1.w);
    }

    f32x4 acc[4];
    #pragma unroll
    for (int t = 0; t < 4; t++) acc[t] = (f32x4){0.f, 0.f, 0.f, 0.f};

    #pragma unroll
    for (int t = 0; t < 4; t++) {
        int tile = wv * 4 + t;
        const unsigned short* bp = Wb1t + (size_t)(tile * 16 + m) * 128 + q * 8;
        #pragma unroll
        for (int kk = 0; kk < 4; kk++) {
            bf16x8 bv = *(const bf16x8*)(bp + kk * 32);
            acc[t] = __builtin_amdgcn_mfma_f32_16x16x32_bf16(af[kk].v, bv, acc[t], 0, 0, 0);
        }
    }

    // epilogue
    #pragma unroll
    for (int t = 0; t < 4; t++) {
        int tile = wv * 4 + t;
        int col = tile * 16 + m;
        if (col < 128) {
            float wsv = att_s[col], wdv = att_d[col];
            #pragma unroll
            for (int r = 0; r < 4; r++) {
                float v = acc[t][r];
                h1b[(size_t)(row0 + q * 4 + r) * 128 + col] = f2bf(v);
                float ps = v * wsv, pd = v * wdv;
                ps += __shfl_xor(ps, 1, 64); pd += __shfl_xor(pd, 1, 64);
                ps += __shfl_xor(ps, 2, 64); pd += __shfl_xor(pd, 2, 64);
                ps += __shfl_xor(ps, 4, 64); pd += __shfl_xor(pd, 4, 64);
                ps += __shfl_xor(ps, 8, 64); pd += __shfl_xor(pd, 8, 64);
                if (m == 0) { sh_as[q * 4 + r][tile] = ps; sh_ad[q * 4 + r][tile] = pd; }
            }
        } else {
            int cc = col - 128;
            float bias = r1b[cc];
            #pragma unroll
            for (int r = 0; r < 4; r++)
                hbuf[(size_t)(row0 + q * 4 + r) * 128 + cc] = acc[t][r] + bias;
        }
    }
    __syncthreads();
    int tt = threadIdx.x;
    if (tt < 128) {
        int i = tt >> 3, h = tt & 7;
        as1[(row0 + i) * 8 + h] = sh_as[i][h];
        ad1[(row0 + i) * 8 + h] = sh_ad[i][h];
    }
}

// ---------------- layer 1 gather-aggregate ----------------

__global__ __launch_bounds__(256) void agg1_kernel(
        const int* __restrict__ rs, const int* __restrict__ csr,
        const float* __restrict__ as, const float* __restrict__ ad,
        const unsigned short* __restrict__ h1b, const float* __restrict__ bias,
        const float* __restrict__ hbuf, unsigned short* __restrict__ hb) {
    __shared__ float ash[4][CAP * 8];
    int lane = threadIdx.x & 63, wv = threadIdx.x >> 6;
    int n = blockIdx.x * 4 + wv;
    if (n >= Nn) return;
    int row = rs[n], end = rs[n + 1];
    int h = lane & 7;
    int j8 = lane >> 3;
    float adh = ad[n * 8 + h];
    float* myash = &ash[wv][0];

    // phase 1: gather logits once, cache, per-head max
    float m = -3.4e38f;
    for (int j = row + j8; j < end; j += 8) {
        int s = csr[j];
        float v = as[s * 8 + h] + adh;
        v = v > 0.f ? v : SLOPE * v;
        int rel = j - row;
        if (rel < CAP) myash[rel * 8 + h] = v;
        m = fmaxf(m, v);
    }
    m = fmaxf(m, __shfl_xor(m, 8, 64));
    m = fmaxf(m, __shfl_xor(m, 16, 64));
    m = fmaxf(m, __shfl_xor(m, 32, 64));

    // phase 2: exp, cache back, per-head sum
    float se = 0.f;
    for (int j = row + j8; j < end; j += 8) {
        int rel = j - row;
        float v;
        if (rel < CAP) v = myash[rel * 8 + h];
        else {
            int s = csr[j];
            v = as[s * 8 + h] + adh;
            v = v > 0.f ? v : SLOPE * v;
        }
        float e = __expf(v - m);
        se += e;
        if (rel < CAP) myash[rel * 8 + h] = e;
    }
    se += __shfl_xor(se, 8, 64);
    se += __shfl_xor(se, 16, 64);
    se += __shfl_xor(se, 32, 64);
    float inv = 1.f / se;

    int c0 = lane * 2;
    int hh = lane >> 3;
    float inv_hh = __shfl(inv, hh, 64);
    float m_keep = m;

    // phase 3: weighted gather, 2-edge unroll
    float a0a = 0.f, a1a = 0.f, a0b = 0.f, a1b = 0.f;
    int j = row;
    for (; j + 2 <= end; j += 2) {
        int rel = j - row;
        int s0 = csr[j], s1 = csr[j + 1];
        float e0, e1;
        if (rel + 1 < CAP) {
            e0 = myash[rel * 8 + hh];
            e1 = myash[rel * 8 + 8 + hh];
        } else {
            float v0 = as[s0 * 8 + h] + adh; v0 = v0 > 0.f ? v0 : SLOPE * v0;
            float v1 = as[s1 * 8 + h] + adh; v1 = v1 > 0.f ? v1 : SLOPE * v1;
            float q0 = __expf(v0 - m_keep), q1 = __expf(v1 - m_keep);
            e0 = __shfl(q0, hh, 64);
            e1 = __shfl(q1, hh, 64);
        }
        ushort2 u0 = *(const ushort2*)(h1b + (size_t)s0 * 128 + c0);
        ushort2 u1 = *(const ushort2*)(h1b + (size_t)s1 * 128 + c0);
        float al0 = e0 * inv_hh, al1 = e1 * inv_hh;
        a0a += al0 * bf2f(u0.x); a1a += al0 * bf2f(u0.y);
        a0b += al1 * bf2f(u1.x); a1b += al1 * bf2f(u1.y);
    }
    if (j < end) {
        int rel = j - row;
        int s0 = csr[j];
        float e0;
        if (rel < CAP) e0 = myash[rel * 8 + hh];
        else {
            float v0 = as[s0 * 8 + h] + adh; v0 = v0 > 0.f ? v0 : SLOPE * v0;
            float q0 = __expf(v0 - m_keep);
            e0 = __shfl(q0, hh, 64);
        }
        ushort2 u0 = *(const ushort2*)(h1b + (size_t)s0 * 128 + c0);
        float al0 = e0 * inv_hh;
        a0a += al0 * bf2f(u0.x); a1a += al0 * bf2f(u0.y);
    }
    float acc0 = a0a + a0b, acc1 = a1a + a1b;

    // epilogue: bias + ELU + residual; emit bf16 h
    float2 rres = *(const float2*)(hbuf + (size_t)n * 128 + c0);
    float g0 = acc0 + bias[c0];
    float g1 = acc1 + bias[c0 + 1];
    g0 = (g0 > 0.f ? g0 : expm1f(g0)) + rres.x;
    g1 = (g1 > 0.f ? g1 : expm1f(g1)) + rres.y;
    ushort2 o; o.x = f2bf(g0); o.y = f2bf(g1);
    *(ushort2*)(hb + (size_t)n * 128 + c0) = o;
}

// ---------------- layer 2 GEMM (MFMA): h2b = bf16(h@W2), out = h@r2W + r2b, as2/ad2 ----------------
// 16 rows per block, 5 waves; wave w = col-tile w of N=80 ([W2 | r2W]).

__global__ __launch_bounds__(320) void gemm2_kernel(
        const unsigned short* __restrict__ hb, const unsigned short* __restrict__ Wb2t,
        const float* __restrict__ r2b,
        const float* __restrict__ att_s, const float* __restrict__ att_d,
        unsigned short* __restrict__ h2b, float* __restrict__ outp,
        float* __restrict__ as2, float* __restrict__ ad2) {
    __shared__ float sh_as[16], sh_ad[16];
    int lane = threadIdx.x & 63, wv = threadIdx.x >> 6;   // wv 0..4
    int m = lane & 15, q = lane >> 4;
    int row0 = blockIdx.x * 16;
    if (threadIdx.x < 16) { sh_as[threadIdx.x] = 0.f; sh_ad[threadIdx.x] = 0.f; }
    __syncthreads();

    const unsigned short* hr = hb + (size_t)(row0 + m) * 128 + q * 8;
    const unsigned short* bp = Wb2t + (size_t)(wv * 16 + m) * 128 + q * 8;
    f32x4 acc = (f32x4){0.f, 0.f, 0.f, 0.f};
    #pragma unroll
    for (int kk = 0; kk < 4; kk++) {
        bf16x8 av = *(const bf16x8*)(hr + kk * 32);
        bf16x8 bv = *(const bf16x8*)(bp + kk * 32);
        acc = __builtin_amdgcn_mfma_f32_16x16x32_bf16(av, bv, acc, 0, 0, 0);
    }

    int col = wv * 16 + m;
    if (col < NC) {
        float wsv = att_s[col], wdv = att_d[col];
        #pragma unroll
        for (int r = 0; r < 4; r++) {
            float v = acc[r];
            h2b[(size_t)(row0 + q * 4 + r) * NC + col] = f2bf(v);
            atomicAdd(&sh_as[q * 4 + r], v * wsv);
            atomicAdd(&sh_ad[q * 4 + r], v * wdv);
        }
    } else {
        int cc = col - NC;
        float bias = r2b[cc];
        #pragma unroll
        for (int r = 0; r < 4; r++)
            outp[(size_t)(row0 + q * 4 + r) * NC + cc] = acc[r] + bias;
    }
    __syncthreads();
    if (threadIdx.x < 16) {
        as2[row0 + threadIdx.x] = sh_as[threadIdx.x];
        ad2[row0 + threadIdx.x] = sh_ad[threadIdx.x];
    }
}

// ---------------- layer 2 gather-aggregate + log_softmax ----------------

__global__ __launch_bounds__(256) void agg2_kernel(
        const int* __restrict__ rs, const int* __restrict__ csr,
        const float* __restrict__ as, const float* __restrict__ ad,
        const unsigned short* __restrict__ h2b, const float* __restrict__ b2,
        float* __restrict__ outp) {
    __shared__ float ash[4][CAP];
    int lane = threadIdx.x & 63, wv = threadIdx.x >> 6;
    int n = blockIdx.x * 4 + wv;
    if (n >= Nn) return;
    int row = rs[n], end = rs[n + 1];
    float adn = ad[n];
    float* myash = &ash[wv][0];

    float m = -3.4e38f;
    for (int j = row + lane; j < end; j += 64) {
        float v = as[csr[j]] + adn;
        v = v > 0.f ? v : SLOPE * v;
        int rel = j - row;
        if (rel < CAP) myash[rel] = v;
        m = fmaxf(m, v);
    }
    #pragma unroll
    for (int st = 32; st >= 1; st >>= 1) m = fmaxf(m, __shfl_xor(m, st, 64));

    float se = 0.f;
    for (int j = row + lane; j < end; j += 64) {
        int rel = j - row;
        float v;
        if (rel < CAP) v = myash[rel];
        else { v = as[csr[j]] + adn; v = v > 0.f ? v : SLOPE * v; }
        float e = __expf(v - m);
        se += e;
        if (rel < CAP) myash[rel] = e;
    }
    #pragma unroll
    for (int st = 32; st >= 1; st >>= 1) se += __shfl_xor(se, st, 64);
    float inv = 1.f / se;

    float accA = 0.f, accB = 0.f;
    bool act = lane < NC;
    int j = row;
    for (; j + 2 <= end; j += 2) {
        int rel = j - row;
        int s0 = csr[j], s1 = csr[j + 1];
        float e0, e1;
        if (rel + 1 < CAP) { e0 = myash[rel]; e1 = myash[rel + 1]; }
        else {
            float v0 = as[s0] + adn; v0 = v0 > 0.f ? v0 : SLOPE * v0;
            float v1 = as[s1] + adn; v1 = v1 > 0.f ? v1 : SLOPE * v1;
            e0 = __expf(v0 - m); e1 = __expf(v1 - m);
        }
        if (act) {
            float x0 = bf2f(h2b[(size_t)s0 * NC + lane]);
            float x1 = bf2f(h2b[(size_t)s1 * NC + lane]);
            accA += (e0 * inv) * x0;
            accB += (e1 * inv) * x1;
        }
    }
    if (j < end) {
        int rel = j - row;
        int s0 = csr[j];
        float e0;
        if (rel < CAP) e0 = myash[rel];
        else { float v0 = as[s0] + adn; v0 = v0 > 0.f ? v0 : SLOPE * v0; e0 = __expf(v0 - m); }
        if (act) accA += (e0 * inv) * bf2f(h2b[(size_t)s0 * NC + lane]);
    }
    float acc = accA + accB;

    float v = act ? acc + b2[lane] + outp[(size_t)n * NC + lane] : -3.4e38f;
    float mm = v;
    #pragma unroll
    for (int st = 32; st >= 1; st >>= 1) mm = fmaxf(mm, __shfl_xor(mm, st, 64));
    float ex = act ? __expf(v - mm) : 0.f;
    float ss = ex;
    #pragma unroll
    for (int st = 32; st >= 1; st >>= 1) ss += __shfl_xor(ss, st, 64);
    if (act) outp[(size_t)n * NC + lane] = v - mm - logf(ss);
}

// ---------------- host ----------------

extern "C" void kernel_launch(void* const* d_in, const int* in_sizes, int n_in,
                              void* d_out, int out_size, void* d_ws, size_t ws_size,
                              hipStream_t stream) {
    const float* x      = (const float*)d_in[0];
    const int*   ei     = (const int*)d_in[1];
    const float* W1     = (const float*)d_in[2];
    const float* att_s1 = (const float*)d_in[3];
    const float* att_d1 = (const float*)d_in[4];
    const float* bias1  = (const float*)d_in[5];
    const float* W2     = (const float*)d_in[6];
    const float* att_s2 = (const float*)d_in[7];
    const float* att_d2 = (const float*)d_in[8];
    const float* bias2  = (const float*)d_in[9];
    const float* r1W    = (const float*)d_in[10];
    const float* r1b    = (const float*)d_in[11];
    const float* r2W    = (const float*)d_in[12];
    const float* r2b    = (const float*)d_in[13];
    float* out = (float*)d_out;

    float* ws   = (float*)d_ws;
    float* hbuf = ws;                            // N*128 f32 (res1)
    float* as1  = hbuf + (size_t)Nn * 128;       // N*8
    float* ad1  = as1 + (size_t)Nn * 8;          // N*8
    float* as2  = ad1 + (size_t)Nn * 8;          // N
    float* ad2  = as2 + Nn;                      // N
    unsigned short* h1b = (unsigned short*)(ad2 + Nn);   // N*128 bf16
    unsigned short* hb  = h1b + (size_t)Nn * 128;        // N*128 bf16 (post-agg1 h)
    unsigned short* h2b = hb + (size_t)Nn * 128;         // N*40 bf16
    unsigned short* Wb1t = h2b + (size_t)Nn * 40;        // 256*128 bf16
    unsigned short* Wb2t = Wb1t + 256 * 128;             // 80*128 bf16
    int* rs     = (int*)(Wb2t + 80 * 128);       // N+1
    int* cnt    = rs + Nn + 1;                   // N
    int* cursor = cnt + Nn;                      // N
    int* bsum   = cursor + Nn;                   // NB_SCAN
    int* bpre   = bsum + NB_SCAN;                // NB_SCAN
    int* csr    = bpre + NB_SCAN;                // EP

    // ---- CSR build + weight prep ----
    zero_int_kernel<<<(Nn + 255) / 256, 256, 0, stream>>>(cnt, Nn);
    hist_kernel<<<(EP + 255) / 256, 256, 0, stream>>>(ei, cnt);
    scanA_kernel<<<NB_SCAN, 256, 0, stream>>>(cnt, rs, bsum);
    scanB_kernel<<<1, 512, 0, stream>>>(bsum, bpre, rs);
    scanC_kernel<<<NB_SCAN, 256, 0, stream>>>(rs, bpre, cursor);
    scatter_kernel<<<(EP + 255) / 256, 256, 0, stream>>>(ei, cursor, csr);
    castW_kernel<<<(256 * 128 + 80 * 128 + 255) / 256, 256, 0, stream>>>(
        W1, r1W, W2, r2W, Wb1t, Wb2t);

    // ---- layer 1 ----
    gemm1_kernel<<<Nn / 16, 256, 0, stream>>>(x, Wb1t, r1b, att_s1, att_d1,
                                              h1b, hbuf, as1, ad1);
    agg1_kernel<<<(Nn + 3) / 4, 256, 0, stream>>>(rs, csr, as1, ad1, h1b, bias1, hbuf, hb);

    // ---- layer 2 ----
    gemm2_kernel<<<Nn / 16, 320, 0, stream>>>(hb, Wb2t, r2b, att_s2, att_d2,
                                              h2b, out, as2, ad2);
    agg2_kernel<<<(Nn + 3) / 4, 256, 0, stream>>>(rs, csr, as2, ad2, h2b, bias2, out);
}

// Round 6
// 704.675 us; speedup vs baseline: 5.7895x; 1.0147x over previous
//
#include <hip/hip_runtime.h>
#include <math.h>

#define Nn 100000
#define Ee 1600000
#define EP 1700000   /* Ee + Nn self loops */
#define NC 40
#define SLOPE 0.2f
#define NB_SCAN 391  /* ceil(Nn/256) */

typedef short bf16x8 __attribute__((ext_vector_type(8)));
typedef float f32x4 __attribute__((ext_vector_type(4)));

// ---------- bf16 helpers ----------

__device__ __forceinline__ unsigned short f2bf(float f) {
    unsigned u = __float_as_uint(f);
    unsigned r = u + 0x7FFFu + ((u >> 16) & 1u);
    return (unsigned short)(r >> 16);
}
__device__ __forceinline__ float bf2f(unsigned short u) {
    return __uint_as_float(((unsigned)u) << 16);
}

// ---------------- CSR build ----------------

__global__ void zero_int_kernel(int* __restrict__ p, int n) {
    int i = blockIdx.x * 256 + threadIdx.x;
    if (i < n) p[i] = 0;
}

__global__ void hist_kernel(const int* __restrict__ ei, int* __restrict__ cnt) {
    int e = blockIdx.x * 256 + threadIdx.x;
    if (e >= EP) return;
    int d = (e < Ee) ? ei[Ee + e] : (e - Ee);
    atomicAdd(&cnt[d], 1);
}

__global__ __launch_bounds__(256) void scanA_kernel(const int* __restrict__ cnt,
                                                    int* __restrict__ rs,
                                                    int* __restrict__ bsum) {
    __shared__ int sh[256];
    int t = threadIdx.x;
    int i = blockIdx.x * 256 + t;
    int c = (i < Nn) ? cnt[i] : 0;
    sh[t] = c;
    __syncthreads();
    #pragma unroll
    for (int off = 1; off < 256; off <<= 1) {
        int v = (t >= off) ? sh[t - off] : 0;
        __syncthreads();
        sh[t] += v;
        __syncthreads();
    }
    if (i < Nn) rs[i] = sh[t] - c;
    if (t == 255) bsum[blockIdx.x] = sh[255];
}

__global__ __launch_bounds__(512) void scanB_kernel(const int* __restrict__ bsum,
                                                    int* __restrict__ bpre,
                                                    int* __restrict__ rs) {
    __shared__ int sh[512];
    int t = threadIdx.x;
    int v = (t < NB_SCAN) ? bsum[t] : 0;
    sh[t] = v;
    __syncthreads();
    #pragma unroll
    for (int off = 1; off < 512; off <<= 1) {
        int u = (t >= off) ? sh[t - off] : 0;
        __syncthreads();
        sh[t] += u;
        __syncthreads();
    }
    if (t < NB_SCAN) bpre[t] = sh[t] - v;
    if (t == 0) rs[Nn] = EP;
}

__global__ void scanC_kernel(int* __restrict__ rs, const int* __restrict__ bpre,
                             int* __restrict__ cursor) {
    int i = blockIdx.x * 256 + threadIdx.x;
    if (i >= Nn) return;
    int r = rs[i] + bpre[blockIdx.x];
    rs[i] = r;
    cursor[i] = r;
}

__global__ void scatter_kernel(const int* __restrict__ ei, int* __restrict__ cursor,
                               int* __restrict__ csr_src) {
    int e = blockIdx.x * 256 + threadIdx.x;
    if (e >= EP) return;
    int s, d;
    if (e < Ee) { s = ei[e]; d = ei[Ee + e]; }
    else        { s = e - Ee; d = s; }
    int pos = atomicAdd(&cursor[d], 1);
    csr_src[pos] = s;
}

// ---------------- weight cast/transpose: Wb1t[256][128], Wb2t[80][128] ----------------

__global__ void castW_kernel(const float* __restrict__ W1, const float* __restrict__ r1W,
                             const float* __restrict__ W2, const float* __restrict__ r2W,
                             unsigned short* __restrict__ Wb1t, unsigned short* __restrict__ Wb2t) {
    int tid = blockIdx.x * 256 + threadIdx.x;
    if (tid < 256 * 128) {
        int col = tid >> 7, k = tid & 127;
        float v = (col < 128) ? W1[k * 128 + col] : r1W[k * 128 + (col - 128)];
        Wb1t[col * 128 + k] = f2bf(v);
    } else if (tid < 256 * 128 + 80 * 128) {
        int t2 = tid - 256 * 128;
        int col = t2 >> 7, k = t2 & 127;
        float v = (col < NC) ? W2[k * NC + col] : r2W[k * NC + (col - NC)];
        Wb2t[col * 128 + k] = f2bf(v);
    }
}

// ---------------- layer 1 GEMM (MFMA) ----------------

__global__ __launch_bounds__(256) void gemm1_kernel(
        const float* __restrict__ x, const unsigned short* __restrict__ Wb1t,
        const float* __restrict__ r1b,
        const float* __restrict__ att_s, const float* __restrict__ att_d,
        unsigned short* __restrict__ h1b, float* __restrict__ hbuf,
        float* __restrict__ as1, float* __restrict__ ad1) {
    __shared__ float sh_as[16][8], sh_ad[16][8];
    int lane = threadIdx.x & 63, wv = threadIdx.x >> 6;
    int m = lane & 15, q = lane >> 4;
    int row0 = blockIdx.x * 16;

    union { unsigned short u[8]; bf16x8 v; } af[4];
    const float* xr = x + (size_t)(row0 + m) * 128 + q * 8;
    #pragma unroll
    for (int kk = 0; kk < 4; kk++) {
        float4 a0 = *(const float4*)(xr + kk * 32);
        float4 a1 = *(const float4*)(xr + kk * 32 + 4);
        af[kk].u[0] = f2bf(a0.x); af[kk].u[1] = f2bf(a0.y);
        af[kk].u[2] = f2bf(a0.z); af[kk].u[3] = f2bf(a0.w);
        af[kk].u[4] = f2bf(a1.x); af[kk].u[5] = f2bf(a1.y);
        af[kk].u[6] = f2bf(a1.z); af[kk].u[7] = f2bf(a1.w);
    }

    f32x4 acc[4];
    #pragma unroll
    for (int t = 0; t < 4; t++) acc[t] = (f32x4){0.f, 0.f, 0.f, 0.f};

    #pragma unroll
    for (int t = 0; t < 4; t++) {
        int tile = wv * 4 + t;
        const unsigned short* bp = Wb1t + (size_t)(tile * 16 + m) * 128 + q * 8;
        #pragma unroll
        for (int kk = 0; kk < 4; kk++) {
            bf16x8 bv = *(const bf16x8*)(bp + kk * 32);
            acc[t] = __builtin_amdgcn_mfma_f32_16x16x32_bf16(af[kk].v, bv, acc[t], 0, 0, 0);
        }
    }

    #pragma unroll
    for (int t = 0; t < 4; t++) {
        int tile = wv * 4 + t;
        int col = tile * 16 + m;
        if (col < 128) {
            float wsv = att_s[col], wdv = att_d[col];
            #pragma unroll
            for (int r = 0; r < 4; r++) {
                float v = acc[t][r];
                h1b[(size_t)(row0 + q * 4 + r) * 128 + col] = f2bf(v);
                float ps = v * wsv, pd = v * wdv;
                ps += __shfl_xor(ps, 1, 64); pd += __shfl_xor(pd, 1, 64);
                ps += __shfl_xor(ps, 2, 64); pd += __shfl_xor(pd, 2, 64);
                ps += __shfl_xor(ps, 4, 64); pd += __shfl_xor(pd, 4, 64);
                ps += __shfl_xor(ps, 8, 64); pd += __shfl_xor(pd, 8, 64);
                if (m == 0) { sh_as[q * 4 + r][tile] = ps; sh_ad[q * 4 + r][tile] = pd; }
            }
        } else {
            int cc = col - 128;
            float bias = r1b[cc];
            #pragma unroll
            for (int r = 0; r < 4; r++)
                hbuf[(size_t)(row0 + q * 4 + r) * 128 + cc] = acc[t][r] + bias;
        }
    }
    __syncthreads();
    int tt = threadIdx.x;
    if (tt < 128) {
        int i = tt >> 3, h = tt & 7;
        as1[(row0 + i) * 8 + h] = sh_as[i][h];
        ad1[(row0 + i) * 8 + h] = sh_ad[i][h];
    }
}

// ---------------- layer 1 gather-aggregate: ONE PASS (no-max softmax, deferred norm) ----------------
// wave per node; lane owns cols {2*lane, 2*lane+1}, head hh = lane>>3.
// acc = sum_j exp(v_j)*h_j ; den = sum_j exp(v_j) ; out = acc/den.

__global__ __launch_bounds__(256) void agg1_kernel(
        const int* __restrict__ rs, const int* __restrict__ csr,
        const float* __restrict__ as, const float* __restrict__ ad,
        const unsigned short* __restrict__ h1b, const float* __restrict__ bias,
        const float* __restrict__ hbuf, unsigned short* __restrict__ hb) {
    int lane = threadIdx.x & 63, wv = threadIdx.x >> 6;
    int n = blockIdx.x * 4 + wv;
    if (n >= Nn) return;
    int row = rs[n], end = rs[n + 1];
    int hh = lane >> 3;            // head for this lane's columns
    int c0 = lane * 2;
    float adh = ad[n * 8 + hh];

    float a0a = 0.f, a1a = 0.f, a0b = 0.f, a1b = 0.f;
    float denA = 0.f, denB = 0.f;
    int j = row;
    for (; j + 2 <= end; j += 2) {
        int s0 = csr[j], s1 = csr[j + 1];
        float v0 = as[s0 * 8 + hh] + adh;
        float v1 = as[s1 * 8 + hh] + adh;
        v0 = v0 > 0.f ? v0 : SLOPE * v0;
        v1 = v1 > 0.f ? v1 : SLOPE * v1;
        float e0 = __expf(v0), e1 = __expf(v1);
        ushort2 u0 = *(const ushort2*)(h1b + (size_t)s0 * 128 + c0);
        ushort2 u1 = *(const ushort2*)(h1b + (size_t)s1 * 128 + c0);
        denA += e0; denB += e1;
        a0a += e0 * bf2f(u0.x); a1a += e0 * bf2f(u0.y);
        a0b += e1 * bf2f(u1.x); a1b += e1 * bf2f(u1.y);
    }
    if (j < end) {
        int s0 = csr[j];
        float v0 = as[s0 * 8 + hh] + adh;
        v0 = v0 > 0.f ? v0 : SLOPE * v0;
        float e0 = __expf(v0);
        ushort2 u0 = *(const ushort2*)(h1b + (size_t)s0 * 128 + c0);
        denA += e0;
        a0a += e0 * bf2f(u0.x); a1a += e0 * bf2f(u0.y);
    }
    float inv = 1.f / (denA + denB);
    float acc0 = (a0a + a0b) * inv, acc1 = (a1a + a1b) * inv;

    // epilogue: bias + ELU + residual; emit bf16 h
    float2 rres = *(const float2*)(hbuf + (size_t)n * 128 + c0);
    float g0 = acc0 + bias[c0];
    float g1 = acc1 + bias[c0 + 1];
    g0 = (g0 > 0.f ? g0 : expm1f(g0)) + rres.x;
    g1 = (g1 > 0.f ? g1 : expm1f(g1)) + rres.y;
    ushort2 o; o.x = f2bf(g0); o.y = f2bf(g1);
    *(ushort2*)(hb + (size_t)n * 128 + c0) = o;
}

// ---------------- layer 2 GEMM (MFMA) ----------------

__global__ __launch_bounds__(320) void gemm2_kernel(
        const unsigned short* __restrict__ hb, const unsigned short* __restrict__ Wb2t,
        const float* __restrict__ r2b,
        const float* __restrict__ att_s, const float* __restrict__ att_d,
        unsigned short* __restrict__ h2b, float* __restrict__ outp,
        float* __restrict__ as2, float* __restrict__ ad2) {
    __shared__ float sh_as[16], sh_ad[16];
    int lane = threadIdx.x & 63, wv = threadIdx.x >> 6;   // wv 0..4
    int m = lane & 15, q = lane >> 4;
    int row0 = blockIdx.x * 16;
    if (threadIdx.x < 16) { sh_as[threadIdx.x] = 0.f; sh_ad[threadIdx.x] = 0.f; }
    __syncthreads();

    const unsigned short* hr = hb + (size_t)(row0 + m) * 128 + q * 8;
    const unsigned short* bp = Wb2t + (size_t)(wv * 16 + m) * 128 + q * 8;
    f32x4 acc = (f32x4){0.f, 0.f, 0.f, 0.f};
    #pragma unroll
    for (int kk = 0; kk < 4; kk++) {
        bf16x8 av = *(const bf16x8*)(hr + kk * 32);
        bf16x8 bv = *(const bf16x8*)(bp + kk * 32);
        acc = __builtin_amdgcn_mfma_f32_16x16x32_bf16(av, bv, acc, 0, 0, 0);
    }

    int col = wv * 16 + m;
    if (col < NC) {
        float wsv = att_s[col], wdv = att_d[col];
        #pragma unroll
        for (int r = 0; r < 4; r++) {
            float v = acc[r];
            h2b[(size_t)(row0 + q * 4 + r) * NC + col] = f2bf(v);
            atomicAdd(&sh_as[q * 4 + r], v * wsv);
            atomicAdd(&sh_ad[q * 4 + r], v * wdv);
        }
    } else {
        int cc = col - NC;
        float bias = r2b[cc];
        #pragma unroll
        for (int r = 0; r < 4; r++)
            outp[(size_t)(row0 + q * 4 + r) * NC + cc] = acc[r] + bias;
    }
    __syncthreads();
    if (threadIdx.x < 16) {
        as2[row0 + threadIdx.x] = sh_as[threadIdx.x];
        ad2[row0 + threadIdx.x] = sh_ad[threadIdx.x];
    }
}

// ---------------- layer 2 gather-aggregate: ONE PASS + log_softmax ----------------

__global__ __launch_bounds__(256) void agg2_kernel(
        const int* __restrict__ rs, const int* __restrict__ csr,
        const float* __restrict__ as, const float* __restrict__ ad,
        const unsigned short* __restrict__ h2b, const float* __restrict__ b2,
        float* __restrict__ outp) {
    int lane = threadIdx.x & 63, wv = threadIdx.x >> 6;
    int n = blockIdx.x * 4 + wv;
    if (n >= Nn) return;
    int row = rs[n], end = rs[n + 1];
    float adn = ad[n];
    bool act = lane < NC;

    float accA = 0.f, accB = 0.f, denA = 0.f, denB = 0.f;
    int j = row;
    for (; j + 2 <= end; j += 2) {
        int s0 = csr[j], s1 = csr[j + 1];
        float v0 = as[s0] + adn;
        float v1 = as[s1] + adn;
        v0 = v0 > 0.f ? v0 : SLOPE * v0;
        v1 = v1 > 0.f ? v1 : SLOPE * v1;
        float e0 = __expf(v0), e1 = __expf(v1);
        denA += e0; denB += e1;
        if (act) {
            accA += e0 * bf2f(h2b[(size_t)s0 * NC + lane]);
            accB += e1 * bf2f(h2b[(size_t)s1 * NC + lane]);
        }
    }
    if (j < end) {
        int s0 = csr[j];
        float v0 = as[s0] + adn;
        v0 = v0 > 0.f ? v0 : SLOPE * v0;
        float e0 = __expf(v0);
        denA += e0;
        if (act) accA += e0 * bf2f(h2b[(size_t)s0 * NC + lane]);
    }
    float acc = (accA + accB) / (denA + denB);

    // epilogue: + bias2 + residual (outp holds h@res2_W + r2b), then log_softmax
    float v = act ? acc + b2[lane] + outp[(size_t)n * NC + lane] : -3.4e38f;
    float mm = v;
    #pragma unroll
    for (int st = 32; st >= 1; st >>= 1) mm = fmaxf(mm, __shfl_xor(mm, st, 64));
    float ex = act ? __expf(v - mm) : 0.f;
    float ss = ex;
    #pragma unroll
    for (int st = 32; st >= 1; st >>= 1) ss += __shfl_xor(ss, st, 64);
    if (act) outp[(size_t)n * NC + lane] = v - mm - logf(ss);
}

// ---------------- host ----------------

extern "C" void kernel_launch(void* const* d_in, const int* in_sizes, int n_in,
                              void* d_out, int out_size, void* d_ws, size_t ws_size,
                              hipStream_t stream) {
    const float* x      = (const float*)d_in[0];
    const int*   ei     = (const int*)d_in[1];
    const float* W1     = (const float*)d_in[2];
    const float* att_s1 = (const float*)d_in[3];
    const float* att_d1 = (const float*)d_in[4];
    const float* bias1  = (const float*)d_in[5];
    const float* W2     = (const float*)d_in[6];
    const float* att_s2 = (const float*)d_in[7];
    const float* att_d2 = (const float*)d_in[8];
    const float* bias2  = (const float*)d_in[9];
    const float* r1W    = (const float*)d_in[10];
    const float* r1b    = (const float*)d_in[11];
    const float* r2W    = (const float*)d_in[12];
    const float* r2b    = (const float*)d_in[13];
    float* out = (float*)d_out;

    float* ws   = (float*)d_ws;
    float* hbuf = ws;                            // N*128 f32 (res1)
    float* as1  = hbuf + (size_t)Nn * 128;       // N*8
    float* ad1  = as1 + (size_t)Nn * 8;          // N*8
    float* as2  = ad1 + (size_t)Nn * 8;          // N
    float* ad2  = as2 + Nn;                      // N
    unsigned short* h1b = (unsigned short*)(ad2 + Nn);   // N*128 bf16
    unsigned short* hb  = h1b + (size_t)Nn * 128;        // N*128 bf16 (post-agg1 h)
    unsigned short* h2b = hb + (size_t)Nn * 128;         // N*40 bf16
    unsigned short* Wb1t = h2b + (size_t)Nn * 40;        // 256*128 bf16
    unsigned short* Wb2t = Wb1t + 256 * 128;             // 80*128 bf16
    int* rs     = (int*)(Wb2t + 80 * 128);       // N+1
    int* cnt    = rs + Nn + 1;                   // N
    int* cursor = cnt + Nn;                      // N
    int* bsum   = cursor + Nn;                   // NB_SCAN
    int* bpre   = bsum + NB_SCAN;                // NB_SCAN
    int* csr    = bpre + NB_SCAN;                // EP

    // ---- CSR build + weight prep ----
    zero_int_kernel<<<(Nn + 255) / 256, 256, 0, stream>>>(cnt, Nn);
    hist_kernel<<<(EP + 255) / 256, 256, 0, stream>>>(ei, cnt);
    scanA_kernel<<<NB_SCAN, 256, 0, stream>>>(cnt, rs, bsum);
    scanB_kernel<<<1, 512, 0, stream>>>(bsum, bpre, rs);
    scanC_kernel<<<NB_SCAN, 256, 0, stream>>>(rs, bpre, cursor);
    scatter_kernel<<<(EP + 255) / 256, 256, 0, stream>>>(ei, cursor, csr);
    castW_kernel<<<(256 * 128 + 80 * 128 + 255) / 256, 256, 0, stream>>>(
        W1, r1W, W2, r2W, Wb1t, Wb2t);

    // ---- layer 1 ----
    gemm1_kernel<<<Nn / 16, 256, 0, stream>>>(x, Wb1t, r1b, att_s1, att_d1,
                                              h1b, hbuf, as1, ad1);
    agg1_kernel<<<(Nn + 3) / 4, 256, 0, stream>>>(rs, csr, as1, ad1, h1b, bias1, hbuf, hb);

    // ---- layer 2 ----
    gemm2_kernel<<<Nn / 16, 320, 0, stream>>>(hb, Wb2t, r2b, att_s2, att_d2,
                                              h2b, out, as2, ad2);
    agg2_kernel<<<(Nn + 3) / 4, 256, 0, stream>>>(rs, csr, as2, ad2, h2b, bias2, out);
}

// Round 7
// 647.812 us; speedup vs baseline: 6.2977x; 1.0878x over previous
//
#include <hip/hip_runtime.h>
#include <math.h>

#define Nn 100000
#define Ee 1600000
#define EP 1700000   /* Ee + Nn self loops */
#define NC 40
#define SLOPE 0.2f
#define NB_SCAN 391  /* ceil(Nn/256) */

typedef short bf16x8 __attribute__((ext_vector_type(8)));
typedef float f32x4 __attribute__((ext_vector_type(4)));

// ---------- bf16 helpers ----------

__device__ __forceinline__ unsigned short f2bf(float f) {
    unsigned u = __float_as_uint(f);
    unsigned r = u + 0x7FFFu + ((u >> 16) & 1u);
    return (unsigned short)(r >> 16);
}
__device__ __forceinline__ float bf2f(unsigned short u) {
    return __uint_as_float(((unsigned)u) << 16);
}

// ---------------- CSR build ----------------

__global__ void zero_int_kernel(int* __restrict__ p, int n) {
    int i = blockIdx.x * 256 + threadIdx.x;
    if (i < n) p[i] = 0;
}

__global__ void hist_kernel(const int* __restrict__ ei, int* __restrict__ cnt) {
    int e = blockIdx.x * 256 + threadIdx.x;
    if (e >= EP) return;
    int d = (e < Ee) ? ei[Ee + e] : (e - Ee);
    atomicAdd(&cnt[d], 1);
}

__global__ __launch_bounds__(256) void scanA_kernel(const int* __restrict__ cnt,
                                                    int* __restrict__ rs,
                                                    int* __restrict__ bsum) {
    __shared__ int sh[256];
    int t = threadIdx.x;
    int i = blockIdx.x * 256 + t;
    int c = (i < Nn) ? cnt[i] : 0;
    sh[t] = c;
    __syncthreads();
    #pragma unroll
    for (int off = 1; off < 256; off <<= 1) {
        int v = (t >= off) ? sh[t - off] : 0;
        __syncthreads();
        sh[t] += v;
        __syncthreads();
    }
    if (i < Nn) rs[i] = sh[t] - c;
    if (t == 255) bsum[blockIdx.x] = sh[255];
}

__global__ __launch_bounds__(512) void scanB_kernel(const int* __restrict__ bsum,
                                                    int* __restrict__ bpre,
                                                    int* __restrict__ rs) {
    __shared__ int sh[512];
    int t = threadIdx.x;
    int v = (t < NB_SCAN) ? bsum[t] : 0;
    sh[t] = v;
    __syncthreads();
    #pragma unroll
    for (int off = 1; off < 512; off <<= 1) {
        int u = (t >= off) ? sh[t - off] : 0;
        __syncthreads();
        sh[t] += u;
        __syncthreads();
    }
    if (t < NB_SCAN) bpre[t] = sh[t] - v;
    if (t == 0) rs[Nn] = EP;
}

__global__ void scanC_kernel(int* __restrict__ rs, const int* __restrict__ bpre,
                             int* __restrict__ cursor) {
    int i = blockIdx.x * 256 + threadIdx.x;
    if (i >= Nn) return;
    int r = rs[i] + bpre[blockIdx.x];
    rs[i] = r;
    cursor[i] = r;
}

__global__ void scatter_kernel(const int* __restrict__ ei, int* __restrict__ cursor,
                               int* __restrict__ csr_src) {
    int e = blockIdx.x * 256 + threadIdx.x;
    if (e >= EP) return;
    int s, d;
    if (e < Ee) { s = ei[e]; d = ei[Ee + e]; }
    else        { s = e - Ee; d = s; }
    int pos = atomicAdd(&cursor[d], 1);
    csr_src[pos] = s;
}

// ---------------- weight cast/transpose: Wb1t[256][128], Wb2t[80][128] ----------------

__global__ void castW_kernel(const float* __restrict__ W1, const float* __restrict__ r1W,
                             const float* __restrict__ W2, const float* __restrict__ r2W,
                             unsigned short* __restrict__ Wb1t, unsigned short* __restrict__ Wb2t) {
    int tid = blockIdx.x * 256 + threadIdx.x;
    if (tid < 256 * 128) {
        int col = tid >> 7, k = tid & 127;
        float v = (col < 128) ? W1[k * 128 + col] : r1W[k * 128 + (col - 128)];
        Wb1t[col * 128 + k] = f2bf(v);
    } else if (tid < 256 * 128 + 80 * 128) {
        int t2 = tid - 256 * 128;
        int col = t2 >> 7, k = t2 & 127;
        float v = (col < NC) ? W2[k * NC + col] : r2W[k * NC + (col - NC)];
        Wb2t[col * 128 + k] = f2bf(v);
    }
}

// ---------------- layer 1 GEMM (MFMA) ----------------

__global__ __launch_bounds__(256) void gemm1_kernel(
        const float* __restrict__ x, const unsigned short* __restrict__ Wb1t,
        const float* __restrict__ r1b,
        const float* __restrict__ att_s, const float* __restrict__ att_d,
        unsigned short* __restrict__ h1b, float* __restrict__ hbuf,
        float* __restrict__ as1, float* __restrict__ ad1) {
    __shared__ float sh_as[16][8], sh_ad[16][8];
    int lane = threadIdx.x & 63, wv = threadIdx.x >> 6;
    int m = lane & 15, q = lane >> 4;
    int row0 = blockIdx.x * 16;

    union { unsigned short u[8]; bf16x8 v; } af[4];
    const float* xr = x + (size_t)(row0 + m) * 128 + q * 8;
    #pragma unroll
    for (int kk = 0; kk < 4; kk++) {
        float4 a0 = *(const float4*)(xr + kk * 32);
        float4 a1 = *(const float4*)(xr + kk * 32 + 4);
        af[kk].u[0] = f2bf(a0.x); af[kk].u[1] = f2bf(a0.y);
        af[kk].u[2] = f2bf(a0.z); af[kk].u[3] = f2bf(a0.w);
        af[kk].u[4] = f2bf(a1.x); af[kk].u[5] = f2bf(a1.y);
        af[kk].u[6] = f2bf(a1.z); af[kk].u[7] = f2bf(a1.w);
    }

    f32x4 acc[4];
    #pragma unroll
    for (int t = 0; t < 4; t++) acc[t] = (f32x4){0.f, 0.f, 0.f, 0.f};

    #pragma unroll
    for (int t = 0; t < 4; t++) {
        int tile = wv * 4 + t;
        const unsigned short* bp = Wb1t + (size_t)(tile * 16 + m) * 128 + q * 8;
        #pragma unroll
        for (int kk = 0; kk < 4; kk++) {
            bf16x8 bv = *(const bf16x8*)(bp + kk * 32);
            acc[t] = __builtin_amdgcn_mfma_f32_16x16x32_bf16(af[kk].v, bv, acc[t], 0, 0, 0);
        }
    }

    #pragma unroll
    for (int t = 0; t < 4; t++) {
        int tile = wv * 4 + t;
        int col = tile * 16 + m;
        if (col < 128) {
            float wsv = att_s[col], wdv = att_d[col];
            #pragma unroll
            for (int r = 0; r < 4; r++) {
                float v = acc[t][r];
                h1b[(size_t)(row0 + q * 4 + r) * 128 + col] = f2bf(v);
                float ps = v * wsv, pd = v * wdv;
                ps += __shfl_xor(ps, 1, 64); pd += __shfl_xor(pd, 1, 64);
                ps += __shfl_xor(ps, 2, 64); pd += __shfl_xor(pd, 2, 64);
                ps += __shfl_xor(ps, 4, 64); pd += __shfl_xor(pd, 4, 64);
                ps += __shfl_xor(ps, 8, 64); pd += __shfl_xor(pd, 8, 64);
                if (m == 0) { sh_as[q * 4 + r][tile] = ps; sh_ad[q * 4 + r][tile] = pd; }
            }
        } else {
            int cc = col - 128;
            float bias = r1b[cc];
            #pragma unroll
            for (int r = 0; r < 4; r++)
                hbuf[(size_t)(row0 + q * 4 + r) * 128 + cc] = acc[t][r] + bias;
        }
    }
    __syncthreads();
    int tt = threadIdx.x;
    if (tt < 128) {
        int i = tt >> 3, h = tt & 7;
        as1[(row0 + i) * 8 + h] = sh_as[i][h];
        ad1[(row0 + i) * 8 + h] = sh_ad[i][h];
    }
}

// ---------------- layer 1 gather-aggregate: parallel logits + shfl-fed serial gather ----------------
// wave per node. Chunk of 8 edges: lane = edge-slot (lane>>3) x head (lane&7) -> 64 parallel exps.
// Serial loop per edge: 2 shfl + 256B coalesced gather + 2 fma. No dependent-load chain.

__global__ __launch_bounds__(256) void agg1_kernel(
        const int* __restrict__ rs, const int* __restrict__ csr,
        const float* __restrict__ as, const float* __restrict__ ad,
        const unsigned short* __restrict__ h1b, const float* __restrict__ bias,
        const float* __restrict__ hbuf, unsigned short* __restrict__ hb) {
    int lane = threadIdx.x & 63, wv = threadIdx.x >> 6;
    int n = blockIdx.x * 4 + wv;
    if (n >= Nn) return;
    int row = rs[n], end = rs[n + 1];
    int h = lane & 7;        // head for parallel-logit phase
    int j8 = lane >> 3;      // edge-slot for parallel-logit phase
    int hh = lane >> 3;      // head owning this lane's columns
    int c0 = lane * 2;
    float adh = ad[n * 8 + h];

    float den_l = 0.f;
    float acc0 = 0.f, acc1 = 0.f, acc0b = 0.f, acc1b = 0.f;
    for (int base = row; base < end; base += 8) {
        int cnt = min(8, end - base);
        int s_l = 0; float e_l = 0.f;
        if (j8 < cnt) {
            s_l = csr[base + j8];
            float v = as[s_l * 8 + h] + adh;
            v = v > 0.f ? v : SLOPE * v;
            e_l = __expf(v);
        }
        den_l += e_l;
        int t = 0;
        for (; t + 2 <= cnt; t += 2) {
            int sA = __shfl(s_l, t * 8, 64);
            int sB = __shfl(s_l, t * 8 + 8, 64);
            float eA = __shfl(e_l, t * 8 + hh, 64);
            float eB = __shfl(e_l, t * 8 + 8 + hh, 64);
            ushort2 uA = *(const ushort2*)(h1b + (size_t)sA * 128 + c0);
            ushort2 uB = *(const ushort2*)(h1b + (size_t)sB * 128 + c0);
            acc0  += eA * bf2f(uA.x); acc1  += eA * bf2f(uA.y);
            acc0b += eB * bf2f(uB.x); acc1b += eB * bf2f(uB.y);
        }
        if (t < cnt) {
            int sA = __shfl(s_l, t * 8, 64);
            float eA = __shfl(e_l, t * 8 + hh, 64);
            ushort2 uA = *(const ushort2*)(h1b + (size_t)sA * 128 + c0);
            acc0 += eA * bf2f(uA.x); acc1 += eA * bf2f(uA.y);
        }
    }
    // den: lane holds partial for head (lane&7) over edge-slots; reduce over slots
    den_l += __shfl_xor(den_l, 8, 64);
    den_l += __shfl_xor(den_l, 16, 64);
    den_l += __shfl_xor(den_l, 32, 64);
    float inv = 1.f / __shfl(den_l, hh, 64);   // lane hh holds head hh's den
    float g0 = (acc0 + acc0b) * inv + bias[c0];
    float g1 = (acc1 + acc1b) * inv + bias[c0 + 1];

    // epilogue: ELU + residual; emit bf16 h
    float2 rres = *(const float2*)(hbuf + (size_t)n * 128 + c0);
    g0 = (g0 > 0.f ? g0 : expm1f(g0)) + rres.x;
    g1 = (g1 > 0.f ? g1 : expm1f(g1)) + rres.y;
    ushort2 o; o.x = f2bf(g0); o.y = f2bf(g1);
    *(ushort2*)(hb + (size_t)n * 128 + c0) = o;
}

// ---------------- layer 2 GEMM (MFMA) ----------------

__global__ __launch_bounds__(320) void gemm2_kernel(
        const unsigned short* __restrict__ hb, const unsigned short* __restrict__ Wb2t,
        const float* __restrict__ r2b,
        const float* __restrict__ att_s, const float* __restrict__ att_d,
        unsigned short* __restrict__ h2b, float* __restrict__ outp,
        float* __restrict__ as2, float* __restrict__ ad2) {
    __shared__ float sh_as[16], sh_ad[16];
    int lane = threadIdx.x & 63, wv = threadIdx.x >> 6;   // wv 0..4
    int m = lane & 15, q = lane >> 4;
    int row0 = blockIdx.x * 16;
    if (threadIdx.x < 16) { sh_as[threadIdx.x] = 0.f; sh_ad[threadIdx.x] = 0.f; }
    __syncthreads();

    const unsigned short* hr = hb + (size_t)(row0 + m) * 128 + q * 8;
    const unsigned short* bp = Wb2t + (size_t)(wv * 16 + m) * 128 + q * 8;
    f32x4 acc = (f32x4){0.f, 0.f, 0.f, 0.f};
    #pragma unroll
    for (int kk = 0; kk < 4; kk++) {
        bf16x8 av = *(const bf16x8*)(hr + kk * 32);
        bf16x8 bv = *(const bf16x8*)(bp + kk * 32);
        acc = __builtin_amdgcn_mfma_f32_16x16x32_bf16(av, bv, acc, 0, 0, 0);
    }

    int col = wv * 16 + m;
    if (col < NC) {
        float wsv = att_s[col], wdv = att_d[col];
        #pragma unroll
        for (int r = 0; r < 4; r++) {
            float v = acc[r];
            h2b[(size_t)(row0 + q * 4 + r) * NC + col] = f2bf(v);
            atomicAdd(&sh_as[q * 4 + r], v * wsv);
            atomicAdd(&sh_ad[q * 4 + r], v * wdv);
        }
    } else {
        int cc = col - NC;
        float bias = r2b[cc];
        #pragma unroll
        for (int r = 0; r < 4; r++)
            outp[(size_t)(row0 + q * 4 + r) * NC + cc] = acc[r] + bias;
    }
    __syncthreads();
    if (threadIdx.x < 16) {
        as2[row0 + threadIdx.x] = sh_as[threadIdx.x];
        ad2[row0 + threadIdx.x] = sh_ad[threadIdx.x];
    }
}

// ---------------- layer 2 gather-aggregate: parallel logits + shfl-fed serial gather ----------------

__global__ __launch_bounds__(256) void agg2_kernel(
        const int* __restrict__ rs, const int* __restrict__ csr,
        const float* __restrict__ as, const float* __restrict__ ad,
        const unsigned short* __restrict__ h2b, const float* __restrict__ b2,
        float* __restrict__ outp) {
    int lane = threadIdx.x & 63, wv = threadIdx.x >> 6;
    int n = blockIdx.x * 4 + wv;
    if (n >= Nn) return;
    int row = rs[n], end = rs[n + 1];
    float adn = ad[n];
    bool act = lane < NC;

    float den_l = 0.f, accA = 0.f, accB = 0.f;
    for (int base = row; base < end; base += 64) {
        int cnt = min(64, end - base);
        int s_l = 0; float e_l = 0.f;
        if (lane < cnt) {
            s_l = csr[base + lane];
            float v = as[s_l] + adn;
            v = v > 0.f ? v : SLOPE * v;
            e_l = __expf(v);
        }
        den_l += e_l;
        int t = 0;
        for (; t + 2 <= cnt; t += 2) {
            int sA = __shfl(s_l, t, 64);
            int sB = __shfl(s_l, t + 1, 64);
            float eA = __shfl(e_l, t, 64);
            float eB = __shfl(e_l, t + 1, 64);
            if (act) {
                accA += eA * bf2f(h2b[(size_t)sA * NC + lane]);
                accB += eB * bf2f(h2b[(size_t)sB * NC + lane]);
            }
        }
        if (t < cnt) {
            int sA = __shfl(s_l, t, 64);
            float eA = __shfl(e_l, t, 64);
            if (act) accA += eA * bf2f(h2b[(size_t)sA * NC + lane]);
        }
    }
    #pragma unroll
    for (int st = 32; st >= 1; st >>= 1) den_l += __shfl_xor(den_l, st, 64);
    float acc = (accA + accB) / den_l;

    // epilogue: + bias2 + residual (outp holds h@res2_W + r2b), then log_softmax
    float v = act ? acc + b2[lane] + outp[(size_t)n * NC + lane] : -3.4e38f;
    float mm = v;
    #pragma unroll
    for (int st = 32; st >= 1; st >>= 1) mm = fmaxf(mm, __shfl_xor(mm, st, 64));
    float ex = act ? __expf(v - mm) : 0.f;
    float ss = ex;
    #pragma unroll
    for (int st = 32; st >= 1; st >>= 1) ss += __shfl_xor(ss, st, 64);
    if (act) outp[(size_t)n * NC + lane] = v - mm - logf(ss);
}

// ---------------- host ----------------

extern "C" void kernel_launch(void* const* d_in, const int* in_sizes, int n_in,
                              void* d_out, int out_size, void* d_ws, size_t ws_size,
                              hipStream_t stream) {
    const float* x      = (const float*)d_in[0];
    const int*   ei     = (const int*)d_in[1];
    const float* W1     = (const float*)d_in[2];
    const float* att_s1 = (const float*)d_in[3];
    const float* att_d1 = (const float*)d_in[4];
    const float* bias1  = (const float*)d_in[5];
    const float* W2     = (const float*)d_in[6];
    const float* att_s2 = (const float*)d_in[7];
    const float* att_d2 = (const float*)d_in[8];
    const float* bias2  = (const float*)d_in[9];
    const float* r1W    = (const float*)d_in[10];
    const float* r1b    = (const float*)d_in[11];
    const float* r2W    = (const float*)d_in[12];
    const float* r2b    = (const float*)d_in[13];
    float* out = (float*)d_out;

    float* ws   = (float*)d_ws;
    float* hbuf = ws;                            // N*128 f32 (res1)
    float* as1  = hbuf + (size_t)Nn * 128;       // N*8
    float* ad1  = as1 + (size_t)Nn * 8;          // N*8
    float* as2  = ad1 + (size_t)Nn * 8;          // N
    float* ad2  = as2 + Nn;                      // N
    unsigned short* h1b = (unsigned short*)(ad2 + Nn);   // N*128 bf16
    unsigned short* hb  = h1b + (size_t)Nn * 128;        // N*128 bf16 (post-agg1 h)
    unsigned short* h2b = hb + (size_t)Nn * 128;         // N*40 bf16
    unsigned short* Wb1t = h2b + (size_t)Nn * 40;        // 256*128 bf16
    unsigned short* Wb2t = Wb1t + 256 * 128;             // 80*128 bf16
    int* rs     = (int*)(Wb2t + 80 * 128);       // N+1
    int* cnt    = rs + Nn + 1;                   // N
    int* cursor = cnt + Nn;                      // N
    int* bsum   = cursor + Nn;                   // NB_SCAN
    int* bpre   = bsum + NB_SCAN;                // NB_SCAN
    int* csr    = bpre + NB_SCAN;                // EP

    // ---- CSR build + weight prep ----
    zero_int_kernel<<<(Nn + 255) / 256, 256, 0, stream>>>(cnt, Nn);
    hist_kernel<<<(EP + 255) / 256, 256, 0, stream>>>(ei, cnt);
    scanA_kernel<<<NB_SCAN, 256, 0, stream>>>(cnt, rs, bsum);
    scanB_kernel<<<1, 512, 0, stream>>>(bsum, bpre, rs);
    scanC_kernel<<<NB_SCAN, 256, 0, stream>>>(rs, bpre, cursor);
    scatter_kernel<<<(EP + 255) / 256, 256, 0, stream>>>(ei, cursor, csr);
    castW_kernel<<<(256 * 128 + 80 * 128 + 255) / 256, 256, 0, stream>>>(
        W1, r1W, W2, r2W, Wb1t, Wb2t);

    // ---- layer 1 ----
    gemm1_kernel<<<Nn / 16, 256, 0, stream>>>(x, Wb1t, r1b, att_s1, att_d1,
                                              h1b, hbuf, as1, ad1);
    agg1_kernel<<<(Nn + 3) / 4, 256, 0, stream>>>(rs, csr, as1, ad1, h1b, bias1, hbuf, hb);

    // ---- layer 2 ----
    gemm2_kernel<<<Nn / 16, 320, 0, stream>>>(hb, Wb2t, r2b, att_s2, att_d2,
                                              h2b, out, as2, ad2);
    agg2_kernel<<<(Nn + 3) / 4, 256, 0, stream>>>(rs, csr, as2, ad2, h2b, bias2, out);
}

// Round 8
// 564.770 us; speedup vs baseline: 7.2237x; 1.1470x over previous
//
#include <hip/hip_runtime.h>
#include <math.h>

#define Nn 100000
#define Ee 1600000
#define EP 1700000   /* Ee + Nn self loops */
#define NC 40
#define SLOPE 0.2f
#define NB_SCAN 391  /* ceil(Nn/256) */
#define GSZ 256      /* nodes per bucket */
#define NBUK 391     /* ceil(Nn/GSZ) */
#define CHA 4096     /* edges per phase-A block */
#define NBA ((EP + CHA - 1) / CHA)

typedef short bf16x8 __attribute__((ext_vector_type(8)));
typedef float f32x4 __attribute__((ext_vector_type(4)));

// ---------- bf16 helpers ----------

__device__ __forceinline__ unsigned short f2bf(float f) {
    unsigned u = __float_as_uint(f);
    unsigned r = u + 0x7FFFu + ((u >> 16) & 1u);
    return (unsigned short)(r >> 16);
}
__device__ __forceinline__ float bf2f(unsigned short u) {
    return __uint_as_float(((unsigned)u) << 16);
}

// ---------------- CSR build ----------------

__global__ void zero_int_kernel(int* __restrict__ p, int n) {
    int i = blockIdx.x * 256 + threadIdx.x;
    if (i < n) p[i] = 0;
}

__global__ void hist_kernel(const int* __restrict__ ei, int* __restrict__ cnt) {
    int e = blockIdx.x * 256 + threadIdx.x;
    if (e >= EP) return;
    int d = (e < Ee) ? ei[Ee + e] : (e - Ee);
    atomicAdd(&cnt[d], 1);
}

__global__ __launch_bounds__(256) void scanA_kernel(const int* __restrict__ cnt,
                                                    int* __restrict__ rs,
                                                    int* __restrict__ bsum) {
    __shared__ int sh[256];
    int t = threadIdx.x;
    int i = blockIdx.x * 256 + t;
    int c = (i < Nn) ? cnt[i] : 0;
    sh[t] = c;
    __syncthreads();
    #pragma unroll
    for (int off = 1; off < 256; off <<= 1) {
        int v = (t >= off) ? sh[t - off] : 0;
        __syncthreads();
        sh[t] += v;
        __syncthreads();
    }
    if (i < Nn) rs[i] = sh[t] - c;
    if (t == 255) bsum[blockIdx.x] = sh[255];
}

__global__ __launch_bounds__(512) void scanB_kernel(const int* __restrict__ bsum,
                                                    int* __restrict__ bpre,
                                                    int* __restrict__ rs) {
    __shared__ int sh[512];
    int t = threadIdx.x;
    int v = (t < NB_SCAN) ? bsum[t] : 0;
    sh[t] = v;
    __syncthreads();
    #pragma unroll
    for (int off = 1; off < 512; off <<= 1) {
        int u = (t >= off) ? sh[t - off] : 0;
        __syncthreads();
        sh[t] += u;
        __syncthreads();
    }
    if (t < NB_SCAN) bpre[t] = sh[t] - v;
    if (t == 0) rs[Nn] = EP;
}

__global__ void scanC_kernel(int* __restrict__ rs, const int* __restrict__ bpre) {
    int i = blockIdx.x * 256 + threadIdx.x;
    if (i >= Nn) return;
    rs[i] = rs[i] + bpre[blockIdx.x];
}

__global__ void bukinit_kernel(const int* __restrict__ rs, int* __restrict__ bukcur) {
    int b = blockIdx.x * 256 + threadIdx.x;
    if (b < NBUK) bukcur[b] = rs[b * GSZ];
}

// phase A: bucket-partition edges into (dst,src) pairs, bucket-major.
__global__ __launch_bounds__(256) void partA_kernel(const int* __restrict__ ei,
                                                    int* __restrict__ bukcur,
                                                    long long* __restrict__ pairs) {
    __shared__ int cntA[NBUK], resA[NBUK];
    int t = threadIdx.x;
    for (int i = t; i < NBUK; i += 256) cntA[i] = 0;
    __syncthreads();
    int e0 = blockIdx.x * CHA;
    int cnt = EP - e0; if (cnt > CHA) cnt = CHA;

    int sarr[16], darr[16], rarr[16];
    #pragma unroll
    for (int k = 0; k < 16; k++) {
        int idx = k * 256 + t;
        darr[k] = -1;
        if (idx < cnt) {
            int e = e0 + idx;
            int s, d;
            if (e < Ee) { s = ei[e]; d = ei[Ee + e]; }
            else        { s = e - Ee; d = s; }
            sarr[k] = s; darr[k] = d;
            rarr[k] = atomicAdd(&cntA[d >> 8], 1);
        }
    }
    __syncthreads();
    for (int b = t; b < NBUK; b += 256) {
        int c = cntA[b];
        resA[b] = (c > 0) ? atomicAdd(&bukcur[b], c) : 0;
    }
    __syncthreads();
    #pragma unroll
    for (int k = 0; k < 16; k++) {
        int d = darr[k];
        if (d >= 0) {
            int g = resA[d >> 8] + rarr[k];
            pairs[g] = ((long long)d << 32) | (unsigned)sarr[k];
        }
    }
}

// phase B: within each bucket, place src into final CSR slot (LDS rank cursors).
__global__ __launch_bounds__(256) void partB_kernel(const long long* __restrict__ pairs,
                                                    const int* __restrict__ rs,
                                                    int* __restrict__ csr) {
    __shared__ int percur[GSZ];
    __shared__ int rbase[GSZ];
    int b = blockIdx.x;
    int t = threadIdx.x;
    int node0 = b * GSZ;
    int nodes = Nn - node0; if (nodes > GSZ) nodes = GSZ;
    if (t < nodes) { rbase[t] = rs[node0 + t]; percur[t] = 0; }
    __syncthreads();
    int lo = rs[node0];
    int hi = rs[node0 + nodes];
    for (int j = lo + t; j < hi; j += 256) {
        long long p = pairs[j];
        int s = (int)(p & 0xffffffffLL);
        int d = (int)(p >> 32);
        int li = d - node0;
        int r = atomicAdd(&percur[li], 1);
        csr[rbase[li] + r] = s;
    }
}

// ---------------- weight cast/transpose: Wb1t[256][128], Wb2t[80][128] ----------------

__global__ void castW_kernel(const float* __restrict__ W1, const float* __restrict__ r1W,
                             const float* __restrict__ W2, const float* __restrict__ r2W,
                             unsigned short* __restrict__ Wb1t, unsigned short* __restrict__ Wb2t) {
    int tid = blockIdx.x * 256 + threadIdx.x;
    if (tid < 256 * 128) {
        int col = tid >> 7, k = tid & 127;
        float v = (col < 128) ? W1[k * 128 + col] : r1W[k * 128 + (col - 128)];
        Wb1t[col * 128 + k] = f2bf(v);
    } else if (tid < 256 * 128 + 80 * 128) {
        int t2 = tid - 256 * 128;
        int col = t2 >> 7, k = t2 & 127;
        float v = (col < NC) ? W2[k * NC + col] : r2W[k * NC + (col - NC)];
        Wb2t[col * 128 + k] = f2bf(v);
    }
}

// ---------------- layer 1 GEMM (MFMA) ----------------

__global__ __launch_bounds__(256) void gemm1_kernel(
        const float* __restrict__ x, const unsigned short* __restrict__ Wb1t,
        const float* __restrict__ r1b,
        const float* __restrict__ att_s, const float* __restrict__ att_d,
        unsigned short* __restrict__ h1b, float* __restrict__ hbuf,
        float* __restrict__ as1, float* __restrict__ ad1) {
    __shared__ float sh_as[16][8], sh_ad[16][8];
    int lane = threadIdx.x & 63, wv = threadIdx.x >> 6;
    int m = lane & 15, q = lane >> 4;
    int row0 = blockIdx.x * 16;

    union { unsigned short u[8]; bf16x8 v; } af[4];
    const float* xr = x + (size_t)(row0 + m) * 128 + q * 8;
    #pragma unroll
    for (int kk = 0; kk < 4; kk++) {
        float4 a0 = *(const float4*)(xr + kk * 32);
        float4 a1 = *(const float4*)(xr + kk * 32 + 4);
        af[kk].u[0] = f2bf(a0.x); af[kk].u[1] = f2bf(a0.y);
        af[kk].u[2] = f2bf(a0.z); af[kk].u[3] = f2bf(a0.w);
        af[kk].u[4] = f2bf(a1.x); af[kk].u[5] = f2bf(a1.y);
        af[kk].u[6] = f2bf(a1.z); af[kk].u[7] = f2bf(a1.w);
    }

    f32x4 acc[4];
    #pragma unroll
    for (int t = 0; t < 4; t++) acc[t] = (f32x4){0.f, 0.f, 0.f, 0.f};

    #pragma unroll
    for (int t = 0; t < 4; t++) {
        int tile = wv * 4 + t;
        const unsigned short* bp = Wb1t + (size_t)(tile * 16 + m) * 128 + q * 8;
        #pragma unroll
        for (int kk = 0; kk < 4; kk++) {
            bf16x8 bv = *(const bf16x8*)(bp + kk * 32);
            acc[t] = __builtin_amdgcn_mfma_f32_16x16x32_bf16(af[kk].v, bv, acc[t], 0, 0, 0);
        }
    }

    #pragma unroll
    for (int t = 0; t < 4; t++) {
        int tile = wv * 4 + t;
        int col = tile * 16 + m;
        if (col < 128) {
            float wsv = att_s[col], wdv = att_d[col];
            #pragma unroll
            for (int r = 0; r < 4; r++) {
                float v = acc[t][r];
                h1b[(size_t)(row0 + q * 4 + r) * 128 + col] = f2bf(v);
                float ps = v * wsv, pd = v * wdv;
                ps += __shfl_xor(ps, 1, 64); pd += __shfl_xor(pd, 1, 64);
                ps += __shfl_xor(ps, 2, 64); pd += __shfl_xor(pd, 2, 64);
                ps += __shfl_xor(ps, 4, 64); pd += __shfl_xor(pd, 4, 64);
                ps += __shfl_xor(ps, 8, 64); pd += __shfl_xor(pd, 8, 64);
                if (m == 0) { sh_as[q * 4 + r][tile] = ps; sh_ad[q * 4 + r][tile] = pd; }
            }
        } else {
            int cc = col - 128;
            float bias = r1b[cc];
            #pragma unroll
            for (int r = 0; r < 4; r++)
                hbuf[(size_t)(row0 + q * 4 + r) * 128 + cc] = acc[t][r] + bias;
        }
    }
    __syncthreads();
    int tt = threadIdx.x;
    if (tt < 128) {
        int i = tt >> 3, h = tt & 7;
        as1[(row0 + i) * 8 + h] = sh_as[i][h];
        ad1[(row0 + i) * 8 + h] = sh_ad[i][h];
    }
}

// ---------------- layer 1 gather-aggregate: parallel logits + shfl-fed serial gather ----------------

__global__ __launch_bounds__(256) void agg1_kernel(
        const int* __restrict__ rs, const int* __restrict__ csr,
        const float* __restrict__ as, const float* __restrict__ ad,
        const unsigned short* __restrict__ h1b, const float* __restrict__ bias,
        const float* __restrict__ hbuf, unsigned short* __restrict__ hb) {
    int lane = threadIdx.x & 63, wv = threadIdx.x >> 6;
    int n = blockIdx.x * 4 + wv;
    if (n >= Nn) return;
    int row = rs[n], end = rs[n + 1];
    int h = lane & 7;        // head for parallel-logit phase
    int j8 = lane >> 3;      // edge-slot for parallel-logit phase
    int hh = lane >> 3;      // head owning this lane's columns
    int c0 = lane * 2;
    float adh = ad[n * 8 + h];

    float den_l = 0.f;
    float acc0 = 0.f, acc1 = 0.f, acc0b = 0.f, acc1b = 0.f;
    for (int base = row; base < end; base += 8) {
        int cnt = min(8, end - base);
        int s_l = 0; float e_l = 0.f;
        if (j8 < cnt) {
            s_l = csr[base + j8];
            float v = as[s_l * 8 + h] + adh;
            v = v > 0.f ? v : SLOPE * v;
            e_l = __expf(v);
        }
        den_l += e_l;
        int t = 0;
        for (; t + 2 <= cnt; t += 2) {
            int sA = __shfl(s_l, t * 8, 64);
            int sB = __shfl(s_l, t * 8 + 8, 64);
            float eA = __shfl(e_l, t * 8 + hh, 64);
            float eB = __shfl(e_l, t * 8 + 8 + hh, 64);
            ushort2 uA = *(const ushort2*)(h1b + (size_t)sA * 128 + c0);
            ushort2 uB = *(const ushort2*)(h1b + (size_t)sB * 128 + c0);
            acc0  += eA * bf2f(uA.x); acc1  += eA * bf2f(uA.y);
            acc0b += eB * bf2f(uB.x); acc1b += eB * bf2f(uB.y);
        }
        if (t < cnt) {
            int sA = __shfl(s_l, t * 8, 64);
            float eA = __shfl(e_l, t * 8 + hh, 64);
            ushort2 uA = *(const ushort2*)(h1b + (size_t)sA * 128 + c0);
            acc0 += eA * bf2f(uA.x); acc1 += eA * bf2f(uA.y);
        }
    }
    den_l += __shfl_xor(den_l, 8, 64);
    den_l += __shfl_xor(den_l, 16, 64);
    den_l += __shfl_xor(den_l, 32, 64);
    float inv = 1.f / __shfl(den_l, hh, 64);
    float g0 = (acc0 + acc0b) * inv + bias[c0];
    float g1 = (acc1 + acc1b) * inv + bias[c0 + 1];

    float2 rres = *(const float2*)(hbuf + (size_t)n * 128 + c0);
    g0 = (g0 > 0.f ? g0 : expm1f(g0)) + rres.x;
    g1 = (g1 > 0.f ? g1 : expm1f(g1)) + rres.y;
    ushort2 o; o.x = f2bf(g0); o.y = f2bf(g1);
    *(ushort2*)(hb + (size_t)n * 128 + c0) = o;
}

// ---------------- layer 2 GEMM (MFMA) ----------------

__global__ __launch_bounds__(320) void gemm2_kernel(
        const unsigned short* __restrict__ hb, const unsigned short* __restrict__ Wb2t,
        const float* __restrict__ r2b,
        const float* __restrict__ att_s, const float* __restrict__ att_d,
        unsigned short* __restrict__ h2b, float* __restrict__ outp,
        float* __restrict__ as2, float* __restrict__ ad2) {
    __shared__ float sh_as[16], sh_ad[16];
    int lane = threadIdx.x & 63, wv = threadIdx.x >> 6;   // wv 0..4
    int m = lane & 15, q = lane >> 4;
    int row0 = blockIdx.x * 16;
    if (threadIdx.x < 16) { sh_as[threadIdx.x] = 0.f; sh_ad[threadIdx.x] = 0.f; }
    __syncthreads();

    const unsigned short* hr = hb + (size_t)(row0 + m) * 128 + q * 8;
    const unsigned short* bp = Wb2t + (size_t)(wv * 16 + m) * 128 + q * 8;
    f32x4 acc = (f32x4){0.f, 0.f, 0.f, 0.f};
    #pragma unroll
    for (int kk = 0; kk < 4; kk++) {
        bf16x8 av = *(const bf16x8*)(hr + kk * 32);
        bf16x8 bv = *(const bf16x8*)(bp + kk * 32);
        acc = __builtin_amdgcn_mfma_f32_16x16x32_bf16(av, bv, acc, 0, 0, 0);
    }

    int col = wv * 16 + m;
    if (col < NC) {
        float wsv = att_s[col], wdv = att_d[col];
        #pragma unroll
        for (int r = 0; r < 4; r++) {
            float v = acc[r];
            h2b[(size_t)(row0 + q * 4 + r) * NC + col] = f2bf(v);
            atomicAdd(&sh_as[q * 4 + r], v * wsv);
            atomicAdd(&sh_ad[q * 4 + r], v * wdv);
        }
    } else {
        int cc = col - NC;
        float bias = r2b[cc];
        #pragma unroll
        for (int r = 0; r < 4; r++)
            outp[(size_t)(row0 + q * 4 + r) * NC + cc] = acc[r] + bias;
    }
    __syncthreads();
    if (threadIdx.x < 16) {
        as2[row0 + threadIdx.x] = sh_as[threadIdx.x];
        ad2[row0 + threadIdx.x] = sh_ad[threadIdx.x];
    }
}

// ---------------- layer 2 gather-aggregate: parallel logits + shfl-fed serial gather ----------------

__global__ __launch_bounds__(256) void agg2_kernel(
        const int* __restrict__ rs, const int* __restrict__ csr,
        const float* __restrict__ as, const float* __restrict__ ad,
        const unsigned short* __restrict__ h2b, const float* __restrict__ b2,
        float* __restrict__ outp) {
    int lane = threadIdx.x & 63, wv = threadIdx.x >> 6;
    int n = blockIdx.x * 4 + wv;
    if (n >= Nn) return;
    int row = rs[n], end = rs[n + 1];
    float adn = ad[n];
    bool act = lane < NC;

    float den_l = 0.f, accA = 0.f, accB = 0.f;
    for (int base = row; base < end; base += 64) {
        int cnt = min(64, end - base);
        int s_l = 0; float e_l = 0.f;
        if (lane < cnt) {
            s_l = csr[base + lane];
            float v = as[s_l] + adn;
            v = v > 0.f ? v : SLOPE * v;
            e_l = __expf(v);
        }
        den_l += e_l;
        int t = 0;
        for (; t + 2 <= cnt; t += 2) {
            int sA = __shfl(s_l, t, 64);
            int sB = __shfl(s_l, t + 1, 64);
            float eA = __shfl(e_l, t, 64);
            float eB = __shfl(e_l, t + 1, 64);
            if (act) {
                accA += eA * bf2f(h2b[(size_t)sA * NC + lane]);
                accB += eB * bf2f(h2b[(size_t)sB * NC + lane]);
            }
        }
        if (t < cnt) {
            int sA = __shfl(s_l, t, 64);
            float eA = __shfl(e_l, t, 64);
            if (act) accA += eA * bf2f(h2b[(size_t)sA * NC + lane]);
        }
    }
    #pragma unroll
    for (int st = 32; st >= 1; st >>= 1) den_l += __shfl_xor(den_l, st, 64);
    float acc = (accA + accB) / den_l;

    float v = act ? acc + b2[lane] + outp[(size_t)n * NC + lane] : -3.4e38f;
    float mm = v;
    #pragma unroll
    for (int st = 32; st >= 1; st >>= 1) mm = fmaxf(mm, __shfl_xor(mm, st, 64));
    float ex = act ? __expf(v - mm) : 0.f;
    float ss = ex;
    #pragma unroll
    for (int st = 32; st >= 1; st >>= 1) ss += __shfl_xor(ss, st, 64);
    if (act) outp[(size_t)n * NC + lane] = v - mm - logf(ss);
}

// ---------------- host ----------------

extern "C" void kernel_launch(void* const* d_in, const int* in_sizes, int n_in,
                              void* d_out, int out_size, void* d_ws, size_t ws_size,
                              hipStream_t stream) {
    const float* x      = (const float*)d_in[0];
    const int*   ei     = (const int*)d_in[1];
    const float* W1     = (const float*)d_in[2];
    const float* att_s1 = (const float*)d_in[3];
    const float* att_d1 = (const float*)d_in[4];
    const float* bias1  = (const float*)d_in[5];
    const float* W2     = (const float*)d_in[6];
    const float* att_s2 = (const float*)d_in[7];
    const float* att_d2 = (const float*)d_in[8];
    const float* bias2  = (const float*)d_in[9];
    const float* r1W    = (const float*)d_in[10];
    const float* r1b    = (const float*)d_in[11];
    const float* r2W    = (const float*)d_in[12];
    const float* r2b    = (const float*)d_in[13];
    float* out = (float*)d_out;

    float* ws   = (float*)d_ws;
    float* hbuf = ws;                            // N*128 f32 (res1)
    float* as1  = hbuf + (size_t)Nn * 128;       // N*8
    float* ad1  = as1 + (size_t)Nn * 8;          // N*8
    float* as2  = ad1 + (size_t)Nn * 8;          // N
    float* ad2  = as2 + Nn;                      // N
    unsigned short* h1b = (unsigned short*)(ad2 + Nn);   // N*128 bf16
    unsigned short* hb  = h1b + (size_t)Nn * 128;        // N*128 bf16 (post-agg1 h)
    unsigned short* h2b = hb + (size_t)Nn * 128;         // N*40 bf16
    unsigned short* Wb1t = h2b + (size_t)Nn * 40;        // 256*128 bf16
    unsigned short* Wb2t = Wb1t + 256 * 128;             // 80*128 bf16
    long long* pairs = (long long*)(Wb2t + 80 * 128);    // EP pairs (8B-aligned by layout)
    int* rs     = (int*)(pairs + EP);            // N+1
    int* cnt    = rs + Nn + 1;                   // N
    int* bukcur = cnt + Nn;                      // NBUK
    int* bsum   = bukcur + NBUK;                 // NB_SCAN
    int* bpre   = bsum + NB_SCAN;                // NB_SCAN
    int* csr    = bpre + NB_SCAN;                // EP

    // ---- CSR build (bucketed two-phase partition) + weight prep ----
    zero_int_kernel<<<(Nn + 255) / 256, 256, 0, stream>>>(cnt, Nn);
    hist_kernel<<<(EP + 255) / 256, 256, 0, stream>>>(ei, cnt);
    scanA_kernel<<<NB_SCAN, 256, 0, stream>>>(cnt, rs, bsum);
    scanB_kernel<<<1, 512, 0, stream>>>(bsum, bpre, rs);
    scanC_kernel<<<NB_SCAN, 256, 0, stream>>>(rs, bpre);
    bukinit_kernel<<<(NBUK + 255) / 256, 256, 0, stream>>>(rs, bukcur);
    partA_kernel<<<NBA, 256, 0, stream>>>(ei, bukcur, pairs);
    partB_kernel<<<NBUK, 256, 0, stream>>>(pairs, rs, csr);
    castW_kernel<<<(256 * 128 + 80 * 128 + 255) / 256, 256, 0, stream>>>(
        W1, r1W, W2, r2W, Wb1t, Wb2t);

    // ---- layer 1 ----
    gemm1_kernel<<<Nn / 16, 256, 0, stream>>>(x, Wb1t, r1b, att_s1, att_d1,
                                              h1b, hbuf, as1, ad1);
    agg1_kernel<<<(Nn + 3) / 4, 256, 0, stream>>>(rs, csr, as1, ad1, h1b, bias1, hbuf, hb);

    // ---- layer 2 ----
    gemm2_kernel<<<Nn / 16, 320, 0, stream>>>(hb, Wb2t, r2b, att_s2, att_d2,
                                              h2b, out, as2, ad2);
    agg2_kernel<<<(Nn + 3) / 4, 256, 0, stream>>>(rs, csr, as2, ad2, h2b, bias2, out);
}

// Round 9
// 488.384 us; speedup vs baseline: 8.3535x; 1.1564x over previous
//
#include <hip/hip_runtime.h>
#include <math.h>

#define Nn 100000
#define Ee 1600000
#define EP 1700000   /* Ee + Nn self loops */
#define NC 40
#define SLOPE 0.2f
#define GSZ 256      /* nodes per bucket */
#define NBUK 391     /* ceil(Nn/GSZ) */
#define CHA 4096     /* edges per partition block */
#define NBA ((EP + CHA - 1) / CHA)

typedef short bf16x8 __attribute__((ext_vector_type(8)));
typedef float f32x4 __attribute__((ext_vector_type(4)));

// ---------- bf16 helpers ----------

__device__ __forceinline__ unsigned short f2bf(float f) {
    unsigned u = __float_as_uint(f);
    unsigned r = u + 0x7FFFu + ((u >> 16) & 1u);
    return (unsigned short)(r >> 16);
}
__device__ __forceinline__ float bf2f(unsigned short u) {
    return __uint_as_float(((unsigned)u) << 16);
}

// ---------------- CSR build (bucketed, no per-node global histogram) ----------------

// bucket histogram: LDS hist over 391 buckets, one global atomic per (block,bucket)
__global__ __launch_bounds__(256) void bukhist_kernel(const int* __restrict__ ei,
                                                      int* __restrict__ bukcnt) {
    __shared__ int lh[NBUK];
    int t = threadIdx.x;
    for (int i = t; i < NBUK; i += 256) lh[i] = 0;
    __syncthreads();
    int e0 = blockIdx.x * CHA;
    int cnt = EP - e0; if (cnt > CHA) cnt = CHA;
    for (int k = t; k < cnt; k += 256) {
        int e = e0 + k;
        int d = (e < Ee) ? ei[Ee + e] : (e - Ee);
        atomicAdd(&lh[d >> 8], 1);
    }
    __syncthreads();
    for (int i = t; i < NBUK; i += 256) {
        int c = lh[i];
        if (c) atomicAdd(&bukcnt[i], c);
    }
}

// scan 391 bucket counts -> bukbase (exclusive), init bukcur, set rs[Nn]
__global__ __launch_bounds__(512) void bukscan_kernel(const int* __restrict__ bukcnt,
                                                      int* __restrict__ bukbase,
                                                      int* __restrict__ bukcur,
                                                      int* __restrict__ rs) {
    __shared__ int sh[512];
    int t = threadIdx.x;
    int v = (t < NBUK) ? bukcnt[t] : 0;
    sh[t] = v;
    __syncthreads();
    #pragma unroll
    for (int off = 1; off < 512; off <<= 1) {
        int u = (t >= off) ? sh[t - off] : 0;
        __syncthreads();
        sh[t] += u;
        __syncthreads();
    }
    if (t < NBUK) {
        int ex = sh[t] - v;
        bukbase[t] = ex;
        bukcur[t] = ex;
    }
    if (t == 0) { bukbase[NBUK] = EP; rs[Nn] = EP; }
}

// phase A: bucket-partition edges into (dst,src) pairs, bucket-major.
__global__ __launch_bounds__(256) void partA_kernel(const int* __restrict__ ei,
                                                    int* __restrict__ bukcur,
                                                    long long* __restrict__ pairs) {
    __shared__ int cntA[NBUK], resA[NBUK];
    int t = threadIdx.x;
    for (int i = t; i < NBUK; i += 256) cntA[i] = 0;
    __syncthreads();
    int e0 = blockIdx.x * CHA;
    int cnt = EP - e0; if (cnt > CHA) cnt = CHA;

    int sarr[16], darr[16], rarr[16];
    #pragma unroll
    for (int k = 0; k < 16; k++) {
        int idx = k * 256 + t;
        darr[k] = -1;
        if (idx < cnt) {
            int e = e0 + idx;
            int s, d;
            if (e < Ee) { s = ei[e]; d = ei[Ee + e]; }
            else        { s = e - Ee; d = s; }
            sarr[k] = s; darr[k] = d;
            rarr[k] = atomicAdd(&cntA[d >> 8], 1);
        }
    }
    __syncthreads();
    for (int b = t; b < NBUK; b += 256) {
        int c = cntA[b];
        resA[b] = (c > 0) ? atomicAdd(&bukcur[b], c) : 0;
    }
    __syncthreads();
    #pragma unroll
    for (int k = 0; k < 16; k++) {
        int d = darr[k];
        if (d >= 0) {
            int g = resA[d >> 8] + rarr[k];
            pairs[g] = ((long long)d << 32) | (unsigned)sarr[k];
        }
    }
}

// phase B: derive per-node rs (LDS count+scan), place src into final CSR slots.
__global__ __launch_bounds__(256) void partB_kernel(const long long* __restrict__ pairs,
                                                    const int* __restrict__ bukbase,
                                                    int* __restrict__ rs,
                                                    int* __restrict__ csr) {
    __shared__ int lcnt[GSZ];
    __shared__ int lbase[GSZ];
    int b = blockIdx.x;
    int t = threadIdx.x;
    int node0 = b * GSZ;
    int nodes = Nn - node0; if (nodes > GSZ) nodes = GSZ;
    lcnt[t] = 0;
    __syncthreads();
    int lo = bukbase[b], hi = bukbase[b + 1];
    for (int j = lo + t; j < hi; j += 256) {
        int li = (int)(pairs[j] >> 32) - node0;
        atomicAdd(&lcnt[li], 1);
    }
    __syncthreads();
    int c = lcnt[t];
    lbase[t] = c;
    __syncthreads();
    #pragma unroll
    for (int off = 1; off < 256; off <<= 1) {
        int u = (t >= off) ? lbase[t - off] : 0;
        __syncthreads();
        lbase[t] += u;
        __syncthreads();
    }
    int myBase = bukbase[b] + lbase[t] - c;   // exclusive prefix + bucket base
    if (t < nodes) rs[node0 + t] = myBase;
    lbase[t] = myBase;
    lcnt[t] = 0;
    __syncthreads();
    for (int j = lo + t; j < hi; j += 256) {
        long long p = pairs[j];
        int li = (int)(p >> 32) - node0;
        int r = atomicAdd(&lcnt[li], 1);
        csr[lbase[li] + r] = (int)(p & 0xffffffffLL);
    }
}

// ---------------- weight cast/transpose: Wb1t[256][128], Wb2t[80][128] ----------------

__global__ void castW_kernel(const float* __restrict__ W1, const float* __restrict__ r1W,
                             const float* __restrict__ W2, const float* __restrict__ r2W,
                             unsigned short* __restrict__ Wb1t, unsigned short* __restrict__ Wb2t) {
    int tid = blockIdx.x * 256 + threadIdx.x;
    if (tid < 256 * 128) {
        int col = tid >> 7, k = tid & 127;
        float v = (col < 128) ? W1[k * 128 + col] : r1W[k * 128 + (col - 128)];
        Wb1t[col * 128 + k] = f2bf(v);
    } else if (tid < 256 * 128 + 80 * 128) {
        int t2 = tid - 256 * 128;
        int col = t2 >> 7, k = t2 & 127;
        float v = (col < NC) ? W2[k * NC + col] : r2W[k * NC + (col - NC)];
        Wb2t[col * 128 + k] = f2bf(v);
    }
}

// ---------------- layer 1 GEMM (MFMA) ----------------

__global__ __launch_bounds__(256) void gemm1_kernel(
        const float* __restrict__ x, const unsigned short* __restrict__ Wb1t,
        const float* __restrict__ r1b,
        const float* __restrict__ att_s, const float* __restrict__ att_d,
        unsigned short* __restrict__ h1b, float* __restrict__ hbuf,
        float* __restrict__ as1, float* __restrict__ ad1) {
    __shared__ float sh_as[16][8], sh_ad[16][8];
    int lane = threadIdx.x & 63, wv = threadIdx.x >> 6;
    int m = lane & 15, q = lane >> 4;
    int row0 = blockIdx.x * 16;

    union { unsigned short u[8]; bf16x8 v; } af[4];
    const float* xr = x + (size_t)(row0 + m) * 128 + q * 8;
    #pragma unroll
    for (int kk = 0; kk < 4; kk++) {
        float4 a0 = *(const float4*)(xr + kk * 32);
        float4 a1 = *(const float4*)(xr + kk * 32 + 4);
        af[kk].u[0] = f2bf(a0.x); af[kk].u[1] = f2bf(a0.y);
        af[kk].u[2] = f2bf(a0.z); af[kk].u[3] = f2bf(a0.w);
        af[kk].u[4] = f2bf(a1.x); af[kk].u[5] = f2bf(a1.y);
        af[kk].u[6] = f2bf(a1.z); af[kk].u[7] = f2bf(a1.w);
    }

    f32x4 acc[4];
    #pragma unroll
    for (int t = 0; t < 4; t++) acc[t] = (f32x4){0.f, 0.f, 0.f, 0.f};

    #pragma unroll
    for (int t = 0; t < 4; t++) {
        int tile = wv * 4 + t;
        const unsigned short* bp = Wb1t + (size_t)(tile * 16 + m) * 128 + q * 8;
        #pragma unroll
        for (int kk = 0; kk < 4; kk++) {
            bf16x8 bv = *(const bf16x8*)(bp + kk * 32);
            acc[t] = __builtin_amdgcn_mfma_f32_16x16x32_bf16(af[kk].v, bv, acc[t], 0, 0, 0);
        }
    }

    #pragma unroll
    for (int t = 0; t < 4; t++) {
        int tile = wv * 4 + t;
        int col = tile * 16 + m;
        if (col < 128) {
            float wsv = att_s[col], wdv = att_d[col];
            #pragma unroll
            for (int r = 0; r < 4; r++) {
                float v = acc[t][r];
                h1b[(size_t)(row0 + q * 4 + r) * 128 + col] = f2bf(v);
                float ps = v * wsv, pd = v * wdv;
                ps += __shfl_xor(ps, 1, 64); pd += __shfl_xor(pd, 1, 64);
                ps += __shfl_xor(ps, 2, 64); pd += __shfl_xor(pd, 2, 64);
                ps += __shfl_xor(ps, 4, 64); pd += __shfl_xor(pd, 4, 64);
                ps += __shfl_xor(ps, 8, 64); pd += __shfl_xor(pd, 8, 64);
                if (m == 0) { sh_as[q * 4 + r][tile] = ps; sh_ad[q * 4 + r][tile] = pd; }
            }
        } else {
            int cc = col - 128;
            float bias = r1b[cc];
            #pragma unroll
            for (int r = 0; r < 4; r++)
                hbuf[(size_t)(row0 + q * 4 + r) * 128 + cc] = acc[t][r] + bias;
        }
    }
    __syncthreads();
    int tt = threadIdx.x;
    if (tt < 128) {
        int i = tt >> 3, h = tt & 7;
        as1[(row0 + i) * 8 + h] = sh_as[i][h];
        ad1[(row0 + i) * 8 + h] = sh_ad[i][h];
    }
}

// ---------------- layer 1 gather-aggregate: 8-wide MLP fast path ----------------

__global__ __launch_bounds__(256) void agg1_kernel(
        const int* __restrict__ rs, const int* __restrict__ csr,
        const float* __restrict__ as, const float* __restrict__ ad,
        const unsigned short* __restrict__ h1b, const float* __restrict__ bias,
        const float* __restrict__ hbuf, unsigned short* __restrict__ hb) {
    int lane = threadIdx.x & 63, wv = threadIdx.x >> 6;
    int n = blockIdx.x * 4 + wv;
    if (n >= Nn) return;
    int row = rs[n], end = rs[n + 1];
    int h = lane & 7;        // head for parallel-logit phase
    int j8 = lane >> 3;      // edge-slot for parallel-logit phase
    int hh = lane >> 3;      // head owning this lane's columns
    int c0 = lane * 2;
    float adh = ad[n * 8 + h];

    float den_l = 0.f;
    float p0 = 0.f, q0 = 0.f, p1 = 0.f, q1 = 0.f;
    float p2 = 0.f, q2 = 0.f, p3 = 0.f, q3 = 0.f;

    int j = row;
    // fast path: full chunks of 8 edges, 8 gathers in flight
    for (; j + 8 <= end; j += 8) {
        int s_l = csr[j + j8];
        float v = as[s_l * 8 + h] + adh;
        v = v > 0.f ? v : SLOPE * v;
        float e_l = __expf(v);
        den_l += e_l;
        int s0 = __shfl(s_l, 0, 64);  float f0 = __shfl(e_l, hh, 64);
        int s1 = __shfl(s_l, 8, 64);  float f1 = __shfl(e_l, 8 + hh, 64);
        int s2 = __shfl(s_l, 16, 64); float f2 = __shfl(e_l, 16 + hh, 64);
        int s3 = __shfl(s_l, 24, 64); float f3 = __shfl(e_l, 24 + hh, 64);
        int s4 = __shfl(s_l, 32, 64); float f4 = __shfl(e_l, 32 + hh, 64);
        int s5 = __shfl(s_l, 40, 64); float f5 = __shfl(e_l, 40 + hh, 64);
        int s6 = __shfl(s_l, 48, 64); float f6 = __shfl(e_l, 48 + hh, 64);
        int s7 = __shfl(s_l, 56, 64); float f7 = __shfl(e_l, 56 + hh, 64);
        ushort2 u0 = *(const ushort2*)(h1b + (size_t)s0 * 128 + c0);
        ushort2 u1 = *(const ushort2*)(h1b + (size_t)s1 * 128 + c0);
        ushort2 u2 = *(const ushort2*)(h1b + (size_t)s2 * 128 + c0);
        ushort2 u3 = *(const ushort2*)(h1b + (size_t)s3 * 128 + c0);
        ushort2 u4 = *(const ushort2*)(h1b + (size_t)s4 * 128 + c0);
        ushort2 u5 = *(const ushort2*)(h1b + (size_t)s5 * 128 + c0);
        ushort2 u6 = *(const ushort2*)(h1b + (size_t)s6 * 128 + c0);
        ushort2 u7 = *(const ushort2*)(h1b + (size_t)s7 * 128 + c0);
        p0 += f0 * bf2f(u0.x); q0 += f0 * bf2f(u0.y);
        p1 += f1 * bf2f(u1.x); q1 += f1 * bf2f(u1.y);
        p2 += f2 * bf2f(u2.x); q2 += f2 * bf2f(u2.y);
        p3 += f3 * bf2f(u3.x); q3 += f3 * bf2f(u3.y);
        p0 += f4 * bf2f(u4.x); q0 += f4 * bf2f(u4.y);
        p1 += f5 * bf2f(u5.x); q1 += f5 * bf2f(u5.y);
        p2 += f6 * bf2f(u6.x); q2 += f6 * bf2f(u6.y);
        p3 += f7 * bf2f(u7.x); q3 += f7 * bf2f(u7.y);
    }
    // tail: < 8 edges
    int cnt = end - j;
    if (cnt > 0) {
        int s_l = 0; float e_l = 0.f;
        if (j8 < cnt) {
            s_l = csr[j + j8];
            float v = as[s_l * 8 + h] + adh;
            v = v > 0.f ? v : SLOPE * v;
            e_l = __expf(v);
        }
        den_l += e_l;
        for (int t2 = 0; t2 < cnt; t2++) {
            int sA = __shfl(s_l, t2 * 8, 64);
            float fA = __shfl(e_l, t2 * 8 + hh, 64);
            ushort2 uA = *(const ushort2*)(h1b + (size_t)sA * 128 + c0);
            p0 += fA * bf2f(uA.x); q0 += fA * bf2f(uA.y);
        }
    }
    den_l += __shfl_xor(den_l, 8, 64);
    den_l += __shfl_xor(den_l, 16, 64);
    den_l += __shfl_xor(den_l, 32, 64);
    float inv = 1.f / __shfl(den_l, hh, 64);
    float g0 = (p0 + p1 + p2 + p3) * inv + bias[c0];
    float g1 = (q0 + q1 + q2 + q3) * inv + bias[c0 + 1];

    float2 rres = *(const float2*)(hbuf + (size_t)n * 128 + c0);
    g0 = (g0 > 0.f ? g0 : expm1f(g0)) + rres.x;
    g1 = (g1 > 0.f ? g1 : expm1f(g1)) + rres.y;
    ushort2 o; o.x = f2bf(g0); o.y = f2bf(g1);
    *(ushort2*)(hb + (size_t)n * 128 + c0) = o;
}

// ---------------- layer 2 GEMM (MFMA) ----------------

__global__ __launch_bounds__(320) void gemm2_kernel(
        const unsigned short* __restrict__ hb, const unsigned short* __restrict__ Wb2t,
        const float* __restrict__ r2b,
        const float* __restrict__ att_s, const float* __restrict__ att_d,
        unsigned short* __restrict__ h2b, float* __restrict__ outp,
        float* __restrict__ as2, float* __restrict__ ad2) {
    __shared__ float sh_as[16], sh_ad[16];
    int lane = threadIdx.x & 63, wv = threadIdx.x >> 6;   // wv 0..4
    int m = lane & 15, q = lane >> 4;
    int row0 = blockIdx.x * 16;
    if (threadIdx.x < 16) { sh_as[threadIdx.x] = 0.f; sh_ad[threadIdx.x] = 0.f; }
    __syncthreads();

    const unsigned short* hr = hb + (size_t)(row0 + m) * 128 + q * 8;
    const unsigned short* bp = Wb2t + (size_t)(wv * 16 + m) * 128 + q * 8;
    f32x4 acc = (f32x4){0.f, 0.f, 0.f, 0.f};
    #pragma unroll
    for (int kk = 0; kk < 4; kk++) {
        bf16x8 av = *(const bf16x8*)(hr + kk * 32);
        bf16x8 bv = *(const bf16x8*)(bp + kk * 32);
        acc = __builtin_amdgcn_mfma_f32_16x16x32_bf16(av, bv, acc, 0, 0, 0);
    }

    int col = wv * 16 + m;
    if (col < NC) {
        float wsv = att_s[col], wdv = att_d[col];
        #pragma unroll
        for (int r = 0; r < 4; r++) {
            float v = acc[r];
            h2b[(size_t)(row0 + q * 4 + r) * NC + col] = f2bf(v);
            atomicAdd(&sh_as[q * 4 + r], v * wsv);
            atomicAdd(&sh_ad[q * 4 + r], v * wdv);
        }
    } else {
        int cc = col - NC;
        float bias = r2b[cc];
        #pragma unroll
        for (int r = 0; r < 4; r++)
            outp[(size_t)(row0 + q * 4 + r) * NC + cc] = acc[r] + bias;
    }
    __syncthreads();
    if (threadIdx.x < 16) {
        as2[row0 + threadIdx.x] = sh_as[threadIdx.x];
        ad2[row0 + threadIdx.x] = sh_ad[threadIdx.x];
    }
}

// ---------------- layer 2 gather-aggregate: 8-wide MLP inner loop ----------------

__global__ __launch_bounds__(256) void agg2_kernel(
        const int* __restrict__ rs, const int* __restrict__ csr,
        const float* __restrict__ as, const float* __restrict__ ad,
        const unsigned short* __restrict__ h2b, const float* __restrict__ b2,
        float* __restrict__ outp) {
    int lane = threadIdx.x & 63, wv = threadIdx.x >> 6;
    int n = blockIdx.x * 4 + wv;
    if (n >= Nn) return;
    int row = rs[n], end = rs[n + 1];
    float adn = ad[n];
    bool act = lane < NC;

    float den_l = 0.f, a0 = 0.f, a1 = 0.f, a2 = 0.f, a3 = 0.f;
    for (int base = row; base < end; base += 64) {
        int cnt = min(64, end - base);
        int s_l = 0; float e_l = 0.f;
        if (lane < cnt) {
            s_l = csr[base + lane];
            float v = as[s_l] + adn;
            v = v > 0.f ? v : SLOPE * v;
            e_l = __expf(v);
        }
        den_l += e_l;
        int t = 0;
        for (; t + 8 <= cnt; t += 8) {
            int s0 = __shfl(s_l, t, 64);     float f0 = __shfl(e_l, t, 64);
            int s1 = __shfl(s_l, t + 1, 64); float f1 = __shfl(e_l, t + 1, 64);
            int s2 = __shfl(s_l, t + 2, 64); float f2 = __shfl(e_l, t + 2, 64);
            int s3 = __shfl(s_l, t + 3, 64); float f3 = __shfl(e_l, t + 3, 64);
            int s4 = __shfl(s_l, t + 4, 64); float f4 = __shfl(e_l, t + 4, 64);
            int s5 = __shfl(s_l, t + 5, 64); float f5 = __shfl(e_l, t + 5, 64);
            int s6 = __shfl(s_l, t + 6, 64); float f6 = __shfl(e_l, t + 6, 64);
            int s7 = __shfl(s_l, t + 7, 64); float f7 = __shfl(e_l, t + 7, 64);
            if (act) {
                float x0 = bf2f(h2b[(size_t)s0 * NC + lane]);
                float x1 = bf2f(h2b[(size_t)s1 * NC + lane]);
                float x2 = bf2f(h2b[(size_t)s2 * NC + lane]);
                float x3 = bf2f(h2b[(size_t)s3 * NC + lane]);
                float x4 = bf2f(h2b[(size_t)s4 * NC + lane]);
                float x5 = bf2f(h2b[(size_t)s5 * NC + lane]);
                float x6 = bf2f(h2b[(size_t)s6 * NC + lane]);
                float x7 = bf2f(h2b[(size_t)s7 * NC + lane]);
                a0 += f0 * x0; a1 += f1 * x1; a2 += f2 * x2; a3 += f3 * x3;
                a0 += f4 * x4; a1 += f5 * x5; a2 += f6 * x6; a3 += f7 * x7;
            }
        }
        for (; t < cnt; t++) {
            int sA = __shfl(s_l, t, 64);
            float fA = __shfl(e_l, t, 64);
            if (act) a0 += fA * bf2f(h2b[(size_t)sA * NC + lane]);
        }
    }
    #pragma unroll
    for (int st = 32; st >= 1; st >>= 1) den_l += __shfl_xor(den_l, st, 64);
    float acc = (a0 + a1 + a2 + a3) / den_l;

    float v = act ? acc + b2[lane] + outp[(size_t)n * NC + lane] : -3.4e38f;
    float mm = v;
    #pragma unroll
    for (int st = 32; st >= 1; st >>= 1) mm = fmaxf(mm, __shfl_xor(mm, st, 64));
    float ex = act ? __expf(v - mm) : 0.f;
    float ss = ex;
    #pragma unroll
    for (int st = 32; st >= 1; st >>= 1) ss += __shfl_xor(ss, st, 64);
    if (act) outp[(size_t)n * NC + lane] = v - mm - logf(ss);
}

// ---------------- host ----------------

extern "C" void kernel_launch(void* const* d_in, const int* in_sizes, int n_in,
                              void* d_out, int out_size, void* d_ws, size_t ws_size,
                              hipStream_t stream) {
    const float* x      = (const float*)d_in[0];
    const int*   ei     = (const int*)d_in[1];
    const float* W1     = (const float*)d_in[2];
    const float* att_s1 = (const float*)d_in[3];
    const float* att_d1 = (const float*)d_in[4];
    const float* bias1  = (const float*)d_in[5];
    const float* W2     = (const float*)d_in[6];
    const float* att_s2 = (const float*)d_in[7];
    const float* att_d2 = (const float*)d_in[8];
    const float* bias2  = (const float*)d_in[9];
    const float* r1W    = (const float*)d_in[10];
    const float* r1b    = (const float*)d_in[11];
    const float* r2W    = (const float*)d_in[12];
    const float* r2b    = (const float*)d_in[13];
    float* out = (float*)d_out;

    float* ws   = (float*)d_ws;
    float* hbuf = ws;                            // N*128 f32 (res1)
    float* as1  = hbuf + (size_t)Nn * 128;       // N*8
    float* ad1  = as1 + (size_t)Nn * 8;          // N*8
    float* as2  = ad1 + (size_t)Nn * 8;          // N
    float* ad2  = as2 + Nn;                      // N
    unsigned short* h1b = (unsigned short*)(ad2 + Nn);   // N*128 bf16
    unsigned short* hb  = h1b + (size_t)Nn * 128;        // N*128 bf16 (post-agg1 h)
    unsigned short* h2b = hb + (size_t)Nn * 128;         // N*40 bf16
    unsigned short* Wb1t = h2b + (size_t)Nn * 40;        // 256*128 bf16
    unsigned short* Wb2t = Wb1t + 256 * 128;             // 80*128 bf16
    long long* pairs = (long long*)(Wb2t + 80 * 128);    // EP pairs (8B aligned)
    int* rs      = (int*)(pairs + EP);           // N+1
    int* bukcnt  = rs + Nn + 1;                  // NBUK
    int* bukbase = bukcnt + NBUK;                // NBUK+1
    int* bukcur  = bukbase + NBUK + 1;           // NBUK
    int* csr     = bukcur + NBUK;                // EP

    // ---- CSR build (bucketed two-phase partition) + weight prep ----
    hipMemsetAsync(bukcnt, 0, NBUK * sizeof(int), stream);
    bukhist_kernel<<<NBA, 256, 0, stream>>>(ei, bukcnt);
    bukscan_kernel<<<1, 512, 0, stream>>>(bukcnt, bukbase, bukcur, rs);
    partA_kernel<<<NBA, 256, 0, stream>>>(ei, bukcur, pairs);
    partB_kernel<<<NBUK, 256, 0, stream>>>(pairs, bukbase, rs, csr);
    castW_kernel<<<(256 * 128 + 80 * 128 + 255) / 256, 256, 0, stream>>>(
        W1, r1W, W2, r2W, Wb1t, Wb2t);

    // ---- layer 1 ----
    gemm1_kernel<<<Nn / 16, 256, 0, stream>>>(x, Wb1t, r1b, att_s1, att_d1,
                                              h1b, hbuf, as1, ad1);
    agg1_kernel<<<(Nn + 3) / 4, 256, 0, stream>>>(rs, csr, as1, ad1, h1b, bias1, hbuf, hb);

    // ---- layer 2 ----
    gemm2_kernel<<<Nn / 16, 320, 0, stream>>>(hb, Wb2t, r2b, att_s2, att_d2,
                                              h2b, out, as2, ad2);
    agg2_kernel<<<(Nn + 3) / 4, 256, 0, stream>>>(rs, csr, as2, ad2, h2b, bias2, out);
}

// Round 10
// 464.402 us; speedup vs baseline: 8.7849x; 1.0516x over previous
//
#include <hip/hip_runtime.h>
#include <math.h>

#define Nn 100000
#define Ee 1600000
#define EP 1700000   /* Ee + Nn self loops */
#define NC 40
#define SLOPE 0.2f
#define GSZ 256      /* nodes per bucket */
#define NBUK 391     /* ceil(Nn/GSZ) */
#define CHA 8192     /* edges per partition block */
#define NBA ((EP + CHA - 1) / CHA)

typedef short bf16x8 __attribute__((ext_vector_type(8)));
typedef float f32x4 __attribute__((ext_vector_type(4)));

// ---------- bf16 helpers ----------

__device__ __forceinline__ unsigned short f2bf(float f) {
    unsigned u = __float_as_uint(f);
    unsigned r = u + 0x7FFFu + ((u >> 16) & 1u);
    return (unsigned short)(r >> 16);
}
__device__ __forceinline__ float bf2f(unsigned short u) {
    return __uint_as_float(((unsigned)u) << 16);
}

// ---------------- CSR build (bucketed two-phase partition) ----------------

__global__ __launch_bounds__(256) void bukhist_kernel(const int* __restrict__ ei,
                                                      int* __restrict__ bukcnt) {
    __shared__ int lh[NBUK];
    int t = threadIdx.x;
    for (int i = t; i < NBUK; i += 256) lh[i] = 0;
    __syncthreads();
    int e0 = blockIdx.x * CHA;
    int cnt = EP - e0; if (cnt > CHA) cnt = CHA;
    for (int k = t; k < cnt; k += 256) {
        int e = e0 + k;
        int d = (e < Ee) ? ei[Ee + e] : (e - Ee);
        atomicAdd(&lh[d >> 8], 1);
    }
    __syncthreads();
    for (int i = t; i < NBUK; i += 256) {
        int c = lh[i];
        if (c) atomicAdd(&bukcnt[i], c);
    }
}

__global__ __launch_bounds__(512) void bukscan_kernel(const int* __restrict__ bukcnt,
                                                      int* __restrict__ bukbase,
                                                      int* __restrict__ bukcur,
                                                      int* __restrict__ rs) {
    __shared__ int sh[512];
    int t = threadIdx.x;
    int v = (t < NBUK) ? bukcnt[t] : 0;
    sh[t] = v;
    __syncthreads();
    #pragma unroll
    for (int off = 1; off < 512; off <<= 1) {
        int u = (t >= off) ? sh[t - off] : 0;
        __syncthreads();
        sh[t] += u;
        __syncthreads();
    }
    if (t < NBUK) {
        int ex = sh[t] - v;
        bukbase[t] = ex;
        bukcur[t] = ex;
    }
    if (t == 0) { bukbase[NBUK] = EP; rs[Nn] = EP; }
}

// phase A: LDS count -> reserve -> re-read & write (dst,src) pairs bucket-major
__global__ __launch_bounds__(256) void partA_kernel(const int* __restrict__ ei,
                                                    int* __restrict__ bukcur,
                                                    long long* __restrict__ pairs) {
    __shared__ int cntA[NBUK], resA[NBUK];
    int t = threadIdx.x;
    for (int i = t; i < NBUK; i += 256) cntA[i] = 0;
    __syncthreads();
    int e0 = blockIdx.x * CHA;
    int cnt = EP - e0; if (cnt > CHA) cnt = CHA;
    for (int k = t; k < cnt; k += 256) {
        int e = e0 + k;
        int d = (e < Ee) ? ei[Ee + e] : (e - Ee);
        atomicAdd(&cntA[d >> 8], 1);
    }
    __syncthreads();
    for (int b = t; b < NBUK; b += 256) {
        int c = cntA[b];
        resA[b] = c ? atomicAdd(&bukcur[b], c) : 0;
        cntA[b] = 0;
    }
    __syncthreads();
    for (int k = t; k < cnt; k += 256) {
        int e = e0 + k;
        int s, d;
        if (e < Ee) { s = ei[e]; d = ei[Ee + e]; }
        else        { s = e - Ee; d = s; }
        int r = atomicAdd(&cntA[d >> 8], 1);
        pairs[resA[d >> 8] + r] = ((long long)d << 32) | (unsigned)s;
    }
}

// phase B: derive per-node rs (LDS count+scan), place src into final CSR slots.
__global__ __launch_bounds__(256) void partB_kernel(const long long* __restrict__ pairs,
                                                    const int* __restrict__ bukbase,
                                                    int* __restrict__ rs,
                                                    int* __restrict__ csr) {
    __shared__ int lcnt[GSZ];
    __shared__ int lbase[GSZ];
    int b = blockIdx.x;
    int t = threadIdx.x;
    int node0 = b * GSZ;
    int nodes = Nn - node0; if (nodes > GSZ) nodes = GSZ;
    lcnt[t] = 0;
    __syncthreads();
    int lo = bukbase[b], hi = bukbase[b + 1];
    for (int j = lo + t; j < hi; j += 256) {
        int li = (int)(pairs[j] >> 32) - node0;
        atomicAdd(&lcnt[li], 1);
    }
    __syncthreads();
    int c = lcnt[t];
    lbase[t] = c;
    __syncthreads();
    #pragma unroll
    for (int off = 1; off < 256; off <<= 1) {
        int u = (t >= off) ? lbase[t - off] : 0;
        __syncthreads();
        lbase[t] += u;
        __syncthreads();
    }
    int myBase = bukbase[b] + lbase[t] - c;
    if (t < nodes) rs[node0 + t] = myBase;
    lbase[t] = myBase;
    lcnt[t] = 0;
    __syncthreads();
    for (int j = lo + t; j < hi; j += 256) {
        long long p = pairs[j];
        int li = (int)(p >> 32) - node0;
        int r = atomicAdd(&lcnt[li], 1);
        csr[lbase[li] + r] = (int)(p & 0xffffffffLL);
    }
}

// ---------------- weight cast/transpose + w~ vectors ----------------

__global__ void castW_kernel(const float* __restrict__ W1, const float* __restrict__ r1W,
                             const float* __restrict__ W2, const float* __restrict__ r2W,
                             const float* __restrict__ att_s2, const float* __restrict__ att_d2,
                             unsigned short* __restrict__ Wb1t, unsigned short* __restrict__ Wb2t,
                             float* __restrict__ wts, float* __restrict__ wtd) {
    int tid = blockIdx.x * 256 + threadIdx.x;
    if (tid < 256 * 128) {
        int col = tid >> 7, k = tid & 127;
        float v = (col < 128) ? W1[k * 128 + col] : r1W[k * 128 + (col - 128)];
        Wb1t[col * 128 + k] = f2bf(v);
    } else if (tid < 256 * 128 + 80 * 128) {
        int t2 = tid - 256 * 128;
        int col = t2 >> 7, k = t2 & 127;
        float v = (col < NC) ? W2[k * NC + col] : r2W[k * NC + (col - NC)];
        Wb2t[col * 128 + k] = f2bf(v);
    } else {
        int t3 = tid - 256 * 128 - 80 * 128;
        if (t3 < 128) {
            float s = 0.f;
            for (int c = 0; c < NC; c++) s += W2[t3 * NC + c] * att_s2[c];
            wts[t3] = s;
        } else if (t3 < 256) {
            int k = t3 - 128;
            float s = 0.f;
            for (int c = 0; c < NC; c++) s += W2[k * NC + c] * att_d2[c];
            wtd[k] = s;
        }
    }
}

// ---------------- layer 1 GEMM (MFMA): h1b, res1 (bf16), as1/ad1 ----------------

__global__ __launch_bounds__(256) void gemm1_kernel(
        const float* __restrict__ x, const unsigned short* __restrict__ Wb1t,
        const float* __restrict__ r1b,
        const float* __restrict__ att_s, const float* __restrict__ att_d,
        unsigned short* __restrict__ h1b, unsigned short* __restrict__ hbufb,
        float* __restrict__ as1, float* __restrict__ ad1) {
    __shared__ float sh_as[16][8], sh_ad[16][8];
    int lane = threadIdx.x & 63, wv = threadIdx.x >> 6;
    int m = lane & 15, q = lane >> 4;
    int row0 = blockIdx.x * 16;

    union { unsigned short u[8]; bf16x8 v; } af[4];
    const float* xr = x + (size_t)(row0 + m) * 128 + q * 8;
    #pragma unroll
    for (int kk = 0; kk < 4; kk++) {
        float4 a0 = *(const float4*)(xr + kk * 32);
        float4 a1 = *(const float4*)(xr + kk * 32 + 4);
        af[kk].u[0] = f2bf(a0.x); af[kk].u[1] = f2bf(a0.y);
        af[kk].u[2] = f2bf(a0.z); af[kk].u[3] = f2bf(a0.w);
        af[kk].u[4] = f2bf(a1.x); af[kk].u[5] = f2bf(a1.y);
        af[kk].u[6] = f2bf(a1.z); af[kk].u[7] = f2bf(a1.w);
    }

    f32x4 acc[4];
    #pragma unroll
    for (int t = 0; t < 4; t++) acc[t] = (f32x4){0.f, 0.f, 0.f, 0.f};

    #pragma unroll
    for (int t = 0; t < 4; t++) {
        int tile = wv * 4 + t;
        const unsigned short* bp = Wb1t + (size_t)(tile * 16 + m) * 128 + q * 8;
        #pragma unroll
        for (int kk = 0; kk < 4; kk++) {
            bf16x8 bv = *(const bf16x8*)(bp + kk * 32);
            acc[t] = __builtin_amdgcn_mfma_f32_16x16x32_bf16(af[kk].v, bv, acc[t], 0, 0, 0);
        }
    }

    #pragma unroll
    for (int t = 0; t < 4; t++) {
        int tile = wv * 4 + t;
        int col = tile * 16 + m;
        if (col < 128) {
            float wsv = att_s[col], wdv = att_d[col];
            #pragma unroll
            for (int r = 0; r < 4; r++) {
                float v = acc[t][r];
                h1b[(size_t)(row0 + q * 4 + r) * 128 + col] = f2bf(v);
                float ps = v * wsv, pd = v * wdv;
                ps += __shfl_xor(ps, 1, 64); pd += __shfl_xor(pd, 1, 64);
                ps += __shfl_xor(ps, 2, 64); pd += __shfl_xor(pd, 2, 64);
                ps += __shfl_xor(ps, 4, 64); pd += __shfl_xor(pd, 4, 64);
                ps += __shfl_xor(ps, 8, 64); pd += __shfl_xor(pd, 8, 64);
                if (m == 0) { sh_as[q * 4 + r][tile] = ps; sh_ad[q * 4 + r][tile] = pd; }
            }
        } else {
            int cc = col - 128;
            float bias = r1b[cc];
            #pragma unroll
            for (int r = 0; r < 4; r++)
                hbufb[(size_t)(row0 + q * 4 + r) * 128 + cc] = f2bf(acc[t][r] + bias);
        }
    }
    __syncthreads();
    int tt = threadIdx.x;
    if (tt < 128) {
        int i = tt >> 3, h = tt & 7;
        as1[(row0 + i) * 8 + h] = sh_as[i][h];
        ad1[(row0 + i) * 8 + h] = sh_ad[i][h];
    }
}

// ---------------- layer 1 gather-aggregate: 8-wide MLP + fused as2/ad2 epilogue ----------------

__global__ __launch_bounds__(256) void agg1_kernel(
        const int* __restrict__ rs, const int* __restrict__ csr,
        const float* __restrict__ as, const float* __restrict__ ad,
        const unsigned short* __restrict__ h1b, const float* __restrict__ bias,
        const unsigned short* __restrict__ hbufb, unsigned short* __restrict__ hb,
        const float* __restrict__ wts, const float* __restrict__ wtd,
        float* __restrict__ as2, float* __restrict__ ad2) {
    int lane = threadIdx.x & 63, wv = threadIdx.x >> 6;
    int n = blockIdx.x * 4 + wv;
    if (n >= Nn) return;
    int row = rs[n], end = rs[n + 1];
    int h = lane & 7;        // head for parallel-logit phase
    int j8 = lane >> 3;      // edge-slot for parallel-logit phase
    int hh = lane >> 3;      // head owning this lane's columns
    int c0 = lane * 2;
    float adh = ad[n * 8 + h];

    float den_l = 0.f;
    float p0 = 0.f, q0 = 0.f, p1 = 0.f, q1 = 0.f;
    float p2 = 0.f, q2 = 0.f, p3 = 0.f, q3 = 0.f;

    int j = row;
    for (; j + 8 <= end; j += 8) {
        int s_l = csr[j + j8];
        float v = as[s_l * 8 + h] + adh;
        v = v > 0.f ? v : SLOPE * v;
        float e_l = __expf(v);
        den_l += e_l;
        int s0 = __shfl(s_l, 0, 64);  float f0 = __shfl(e_l, hh, 64);
        int s1 = __shfl(s_l, 8, 64);  float f1 = __shfl(e_l, 8 + hh, 64);
        int s2 = __shfl(s_l, 16, 64); float f2 = __shfl(e_l, 16 + hh, 64);
        int s3 = __shfl(s_l, 24, 64); float f3 = __shfl(e_l, 24 + hh, 64);
        int s4 = __shfl(s_l, 32, 64); float f4 = __shfl(e_l, 32 + hh, 64);
        int s5 = __shfl(s_l, 40, 64); float f5 = __shfl(e_l, 40 + hh, 64);
        int s6 = __shfl(s_l, 48, 64); float f6 = __shfl(e_l, 48 + hh, 64);
        int s7 = __shfl(s_l, 56, 64); float f7 = __shfl(e_l, 56 + hh, 64);
        ushort2 u0 = *(const ushort2*)(h1b + (size_t)s0 * 128 + c0);
        ushort2 u1 = *(const ushort2*)(h1b + (size_t)s1 * 128 + c0);
        ushort2 u2 = *(const ushort2*)(h1b + (size_t)s2 * 128 + c0);
        ushort2 u3 = *(const ushort2*)(h1b + (size_t)s3 * 128 + c0);
        ushort2 u4 = *(const ushort2*)(h1b + (size_t)s4 * 128 + c0);
        ushort2 u5 = *(const ushort2*)(h1b + (size_t)s5 * 128 + c0);
        ushort2 u6 = *(const ushort2*)(h1b + (size_t)s6 * 128 + c0);
        ushort2 u7 = *(const ushort2*)(h1b + (size_t)s7 * 128 + c0);
        p0 += f0 * bf2f(u0.x); q0 += f0 * bf2f(u0.y);
        p1 += f1 * bf2f(u1.x); q1 += f1 * bf2f(u1.y);
        p2 += f2 * bf2f(u2.x); q2 += f2 * bf2f(u2.y);
        p3 += f3 * bf2f(u3.x); q3 += f3 * bf2f(u3.y);
        p0 += f4 * bf2f(u4.x); q0 += f4 * bf2f(u4.y);
        p1 += f5 * bf2f(u5.x); q1 += f5 * bf2f(u5.y);
        p2 += f6 * bf2f(u6.x); q2 += f6 * bf2f(u6.y);
        p3 += f7 * bf2f(u7.x); q3 += f7 * bf2f(u7.y);
    }
    int cnt = end - j;
    if (cnt > 0) {
        int s_l = 0; float e_l = 0.f;
        if (j8 < cnt) {
            s_l = csr[j + j8];
            float v = as[s_l * 8 + h] + adh;
            v = v > 0.f ? v : SLOPE * v;
            e_l = __expf(v);
        }
        den_l += e_l;
        for (int t2 = 0; t2 < cnt; t2++) {
            int sA = __shfl(s_l, t2 * 8, 64);
            float fA = __shfl(e_l, t2 * 8 + hh, 64);
            ushort2 uA = *(const ushort2*)(h1b + (size_t)sA * 128 + c0);
            p0 += fA * bf2f(uA.x); q0 += fA * bf2f(uA.y);
        }
    }
    den_l += __shfl_xor(den_l, 8, 64);
    den_l += __shfl_xor(den_l, 16, 64);
    den_l += __shfl_xor(den_l, 32, 64);
    float inv = 1.f / __shfl(den_l, hh, 64);
    float g0 = (p0 + p1 + p2 + p3) * inv + bias[c0];
    float g1 = (q0 + q1 + q2 + q3) * inv + bias[c0 + 1];

    // epilogue: ELU + residual (bf16), emit bf16 h, fused layer-2 logit dots
    ushort2 rr = *(const ushort2*)(hbufb + (size_t)n * 128 + c0);
    g0 = (g0 > 0.f ? g0 : expm1f(g0)) + bf2f(rr.x);
    g1 = (g1 > 0.f ? g1 : expm1f(g1)) + bf2f(rr.y);
    ushort2 o; o.x = f2bf(g0); o.y = f2bf(g1);
    *(ushort2*)(hb + (size_t)n * 128 + c0) = o;

    float2 wsv = *(const float2*)(wts + c0);
    float2 wdv = *(const float2*)(wtd + c0);
    float ps = g0 * wsv.x + g1 * wsv.y;
    float pd = g0 * wdv.x + g1 * wdv.y;
    #pragma unroll
    for (int st = 32; st >= 1; st >>= 1) {
        ps += __shfl_xor(ps, st, 64);
        pd += __shfl_xor(pd, st, 64);
    }
    if (lane == 0) { as2[n] = ps; ad2[n] = pd; }
}

// ---------------- layer 2 GEMM (MFMA, pure): h2b + residual-out ----------------

__global__ __launch_bounds__(320) void gemm2_kernel(
        const unsigned short* __restrict__ hb, const unsigned short* __restrict__ Wb2t,
        const float* __restrict__ r2b,
        unsigned short* __restrict__ h2b, float* __restrict__ outp) {
    int lane = threadIdx.x & 63, wv = threadIdx.x >> 6;   // wv 0..4
    int m = lane & 15, q = lane >> 4;
    int row0 = blockIdx.x * 16;

    const unsigned short* hr = hb + (size_t)(row0 + m) * 128 + q * 8;
    const unsigned short* bp = Wb2t + (size_t)(wv * 16 + m) * 128 + q * 8;
    f32x4 acc = (f32x4){0.f, 0.f, 0.f, 0.f};
    #pragma unroll
    for (int kk = 0; kk < 4; kk++) {
        bf16x8 av = *(const bf16x8*)(hr + kk * 32);
        bf16x8 bv = *(const bf16x8*)(bp + kk * 32);
        acc = __builtin_amdgcn_mfma_f32_16x16x32_bf16(av, bv, acc, 0, 0, 0);
    }

    int col = wv * 16 + m;
    if (col < NC) {
        #pragma unroll
        for (int r = 0; r < 4; r++)
            h2b[(size_t)(row0 + q * 4 + r) * NC + col] = f2bf(acc[r]);
    } else {
        int cc = col - NC;
        float bias = r2b[cc];
        #pragma unroll
        for (int r = 0; r < 4; r++)
            outp[(size_t)(row0 + q * 4 + r) * NC + cc] = acc[r] + bias;
    }
}

// ---------------- layer 2 gather-aggregate: 8-wide MLP + log_softmax ----------------

__global__ __launch_bounds__(256) void agg2_kernel(
        const int* __restrict__ rs, const int* __restrict__ csr,
        const float* __restrict__ as, const float* __restrict__ ad,
        const unsigned short* __restrict__ h2b, const float* __restrict__ b2,
        float* __restrict__ outp) {
    int lane = threadIdx.x & 63, wv = threadIdx.x >> 6;
    int n = blockIdx.x * 4 + wv;
    if (n >= Nn) return;
    int row = rs[n], end = rs[n + 1];
    float adn = ad[n];
    bool act = lane < NC;

    float den_l = 0.f, a0 = 0.f, a1 = 0.f, a2 = 0.f, a3 = 0.f;
    for (int base = row; base < end; base += 64) {
        int cnt = min(64, end - base);
        int s_l = 0; float e_l = 0.f;
        if (lane < cnt) {
            s_l = csr[base + lane];
            float v = as[s_l] + adn;
            v = v > 0.f ? v : SLOPE * v;
            e_l = __expf(v);
        }
        den_l += e_l;
        int t = 0;
        for (; t + 8 <= cnt; t += 8) {
            int s0 = __shfl(s_l, t, 64);     float f0 = __shfl(e_l, t, 64);
            int s1 = __shfl(s_l, t + 1, 64); float f1 = __shfl(e_l, t + 1, 64);
            int s2 = __shfl(s_l, t + 2, 64); float f2 = __shfl(e_l, t + 2, 64);
            int s3 = __shfl(s_l, t + 3, 64); float f3 = __shfl(e_l, t + 3, 64);
            int s4 = __shfl(s_l, t + 4, 64); float f4 = __shfl(e_l, t + 4, 64);
            int s5 = __shfl(s_l, t + 5, 64); float f5 = __shfl(e_l, t + 5, 64);
            int s6 = __shfl(s_l, t + 6, 64); float f6 = __shfl(e_l, t + 6, 64);
            int s7 = __shfl(s_l, t + 7, 64); float f7 = __shfl(e_l, t + 7, 64);
            if (act) {
                float x0 = bf2f(h2b[(size_t)s0 * NC + lane]);
                float x1 = bf2f(h2b[(size_t)s1 * NC + lane]);
                float x2 = bf2f(h2b[(size_t)s2 * NC + lane]);
                float x3 = bf2f(h2b[(size_t)s3 * NC + lane]);
                float x4 = bf2f(h2b[(size_t)s4 * NC + lane]);
                float x5 = bf2f(h2b[(size_t)s5 * NC + lane]);
                float x6 = bf2f(h2b[(size_t)s6 * NC + lane]);
                float x7 = bf2f(h2b[(size_t)s7 * NC + lane]);
                a0 += f0 * x0; a1 += f1 * x1; a2 += f2 * x2; a3 += f3 * x3;
                a0 += f4 * x4; a1 += f5 * x5; a2 += f6 * x6; a3 += f7 * x7;
            }
        }
        for (; t < cnt; t++) {
            int sA = __shfl(s_l, t, 64);
            float fA = __shfl(e_l, t, 64);
            if (act) a0 += fA * bf2f(h2b[(size_t)sA * NC + lane]);
        }
    }
    #pragma unroll
    for (int st = 32; st >= 1; st >>= 1) den_l += __shfl_xor(den_l, st, 64);
    float acc = (a0 + a1 + a2 + a3) / den_l;

    float v = act ? acc + b2[lane] + outp[(size_t)n * NC + lane] : -3.4e38f;
    float mm = v;
    #pragma unroll
    for (int st = 32; st >= 1; st >>= 1) mm = fmaxf(mm, __shfl_xor(mm, st, 64));
    float ex = act ? __expf(v - mm) : 0.f;
    float ss = ex;
    #pragma unroll
    for (int st = 32; st >= 1; st >>= 1) ss += __shfl_xor(ss, st, 64);
    if (act) outp[(size_t)n * NC + lane] = v - mm - logf(ss);
}

// ---------------- host ----------------

extern "C" void kernel_launch(void* const* d_in, const int* in_sizes, int n_in,
                              void* d_out, int out_size, void* d_ws, size_t ws_size,
                              hipStream_t stream) {
    const float* x      = (const float*)d_in[0];
    const int*   ei     = (const int*)d_in[1];
    const float* W1     = (const float*)d_in[2];
    const float* att_s1 = (const float*)d_in[3];
    const float* att_d1 = (const float*)d_in[4];
    const float* bias1  = (const float*)d_in[5];
    const float* W2     = (const float*)d_in[6];
    const float* att_s2 = (const float*)d_in[7];
    const float* att_d2 = (const float*)d_in[8];
    const float* bias2  = (const float*)d_in[9];
    const float* r1W    = (const float*)d_in[10];
    const float* r1b    = (const float*)d_in[11];
    const float* r2W    = (const float*)d_in[12];
    const float* r2b    = (const float*)d_in[13];
    float* out = (float*)d_out;

    float* ws   = (float*)d_ws;
    float* as1  = ws;                            // N*8
    float* ad1  = as1 + (size_t)Nn * 8;          // N*8
    float* as2  = ad1 + (size_t)Nn * 8;          // N
    float* ad2  = as2 + Nn;                      // N
    float* wts  = ad2 + Nn;                      // 128
    float* wtd  = wts + 128;                     // 128
    unsigned short* hbufb = (unsigned short*)(wtd + 128);  // N*128 bf16 (res1)
    unsigned short* h1b = hbufb + (size_t)Nn * 128;        // N*128 bf16
    unsigned short* hb  = h1b + (size_t)Nn * 128;          // N*128 bf16 (post-agg1 h)
    unsigned short* h2b = hb + (size_t)Nn * 128;           // N*40 bf16
    unsigned short* Wb1t = h2b + (size_t)Nn * 40;          // 256*128 bf16
    unsigned short* Wb2t = Wb1t + 256 * 128;               // 80*128 bf16
    uintptr_t pal = ((uintptr_t)(Wb2t + 80 * 128) + 7) & ~(uintptr_t)7;
    long long* pairs = (long long*)pal;          // EP pairs
    int* rs      = (int*)(pairs + EP);           // N+1
    int* bukcnt  = rs + Nn + 1;                  // NBUK
    int* bukbase = bukcnt + NBUK;                // NBUK+1
    int* bukcur  = bukbase + NBUK + 1;           // NBUK
    int* csr     = bukcur + NBUK;                // EP

    // ---- CSR build + weight prep ----
    hipMemsetAsync(bukcnt, 0, NBUK * sizeof(int), stream);
    bukhist_kernel<<<NBA, 256, 0, stream>>>(ei, bukcnt);
    bukscan_kernel<<<1, 512, 0, stream>>>(bukcnt, bukbase, bukcur, rs);
    partA_kernel<<<NBA, 256, 0, stream>>>(ei, bukcur, pairs);
    partB_kernel<<<NBUK, 256, 0, stream>>>(pairs, bukbase, rs, csr);
    castW_kernel<<<(256 * 128 + 80 * 128 + 256 + 255) / 256, 256, 0, stream>>>(
        W1, r1W, W2, r2W, att_s2, att_d2, Wb1t, Wb2t, wts, wtd);

    // ---- layer 1 ----
    gemm1_kernel<<<Nn / 16, 256, 0, stream>>>(x, Wb1t, r1b, att_s1, att_d1,
                                              h1b, hbufb, as1, ad1);
    agg1_kernel<<<(Nn + 3) / 4, 256, 0, stream>>>(rs, csr, as1, ad1, h1b, bias1,
                                                  hbufb, hb, wts, wtd, as2, ad2);

    // ---- layer 2 ----
    gemm2_kernel<<<Nn / 16, 320, 0, stream>>>(hb, Wb2t, r2b, h2b, out);
    agg2_kernel<<<(Nn + 3) / 4, 256, 0, stream>>>(rs, csr, as2, ad2, h2b, bias2, out);
}

// Round 11
// 448.348 us; speedup vs baseline: 9.0995x; 1.0358x over previous
//
#include <hip/hip_runtime.h>
#include <math.h>

#define Nn 100000
#define Ee 1600000
#define EP 1700000   /* Ee + Nn self loops */
#define NC 40
#define SLOPE 0.2f
#define GSZ 256      /* nodes per bucket */
#define NBUK 391     /* ceil(Nn/GSZ) */
#define CAPB 8192    /* padded capacity per bucket (avg 4348, 58 sigma headroom) */
#define CHA 8192     /* edges per partition block */
#define NBA ((EP + CHA - 1) / CHA)

typedef short bf16x8 __attribute__((ext_vector_type(8)));
typedef float f32x4 __attribute__((ext_vector_type(4)));

// ---------- bf16 helpers ----------

__device__ __forceinline__ unsigned short f2bf(float f) {
    unsigned u = __float_as_uint(f);
    unsigned r = u + 0x7FFFu + ((u >> 16) & 1u);
    return (unsigned short)(r >> 16);
}
__device__ __forceinline__ float bf2f(unsigned short u) {
    return __uint_as_float(((unsigned)u) << 16);
}

// ---------------- CSR build (padded-bucket partition, no global histogram pass) ----------------

// phase A: LDS count -> reserve in padded region -> re-read & write (dst,src) pairs
__global__ __launch_bounds__(256) void partA_kernel(const int* __restrict__ ei,
                                                    int* __restrict__ bukcnt,
                                                    long long* __restrict__ pairs) {
    __shared__ int cntA[NBUK], resA[NBUK];
    int t = threadIdx.x;
    for (int i = t; i < NBUK; i += 256) cntA[i] = 0;
    __syncthreads();
    int e0 = blockIdx.x * CHA;
    int cnt = EP - e0; if (cnt > CHA) cnt = CHA;
    for (int k = t; k < cnt; k += 256) {
        int e = e0 + k;
        int d = (e < Ee) ? ei[Ee + e] : (e - Ee);
        atomicAdd(&cntA[d >> 8], 1);
    }
    __syncthreads();
    for (int b = t; b < NBUK; b += 256) {
        int c = cntA[b];
        resA[b] = c ? atomicAdd(&bukcnt[b], c) : 0;
        cntA[b] = 0;
    }
    __syncthreads();
    for (int k = t; k < cnt; k += 256) {
        int e = e0 + k;
        int s, d;
        if (e < Ee) { s = ei[e]; d = ei[Ee + e]; }
        else        { s = e - Ee; d = s; }
        int b = d >> 8;
        int r = atomicAdd(&cntA[b], 1);
        pairs[(size_t)b * CAPB + resA[b] + r] = ((long long)d << 32) | (unsigned)s;
    }
}

// scan final bucket counts -> bukbase (exclusive); rs[Nn]=EP
__global__ __launch_bounds__(512) void bukscan_kernel(const int* __restrict__ bukcnt,
                                                      int* __restrict__ bukbase,
                                                      int* __restrict__ rs) {
    __shared__ int sh[512];
    int t = threadIdx.x;
    int v = (t < NBUK) ? bukcnt[t] : 0;
    sh[t] = v;
    __syncthreads();
    #pragma unroll
    for (int off = 1; off < 512; off <<= 1) {
        int u = (t >= off) ? sh[t - off] : 0;
        __syncthreads();
        sh[t] += u;
        __syncthreads();
    }
    if (t < NBUK) bukbase[t] = sh[t] - v;
    if (t == 0) { bukbase[NBUK] = EP; rs[Nn] = EP; }
}

// phase B: derive per-node rs (LDS count+scan), place src into final CSR slots.
__global__ __launch_bounds__(256) void partB_kernel(const long long* __restrict__ pairs,
                                                    const int* __restrict__ bukcnt,
                                                    const int* __restrict__ bukbase,
                                                    int* __restrict__ rs,
                                                    int* __restrict__ csr) {
    __shared__ int lcnt[GSZ];
    __shared__ int lbase[GSZ];
    int b = blockIdx.x;
    int t = threadIdx.x;
    int node0 = b * GSZ;
    int nodes = Nn - node0; if (nodes > GSZ) nodes = GSZ;
    lcnt[t] = 0;
    __syncthreads();
    int lo = b * CAPB;
    int hi = lo + bukcnt[b];
    for (int j = lo + t; j < hi; j += 256) {
        int li = (int)(pairs[j] >> 32) - node0;
        atomicAdd(&lcnt[li], 1);
    }
    __syncthreads();
    int c = lcnt[t];
    lbase[t] = c;
    __syncthreads();
    #pragma unroll
    for (int off = 1; off < 256; off <<= 1) {
        int u = (t >= off) ? lbase[t - off] : 0;
        __syncthreads();
        lbase[t] += u;
        __syncthreads();
    }
    int myBase = bukbase[b] + lbase[t] - c;
    if (t < nodes) rs[node0 + t] = myBase;
    lbase[t] = myBase;
    lcnt[t] = 0;
    __syncthreads();
    for (int j = lo + t; j < hi; j += 256) {
        long long p = pairs[j];
        int li = (int)(p >> 32) - node0;
        int r = atomicAdd(&lcnt[li], 1);
        csr[lbase[li] + r] = (int)(p & 0xffffffffLL);
    }
}

// ---------------- weight cast/transpose + w~ vectors ----------------

__global__ void castW_kernel(const float* __restrict__ W1, const float* __restrict__ r1W,
                             const float* __restrict__ W2, const float* __restrict__ r2W,
                             const float* __restrict__ att_s2, const float* __restrict__ att_d2,
                             unsigned short* __restrict__ Wb1t, unsigned short* __restrict__ Wb2t,
                             float* __restrict__ wts, float* __restrict__ wtd) {
    int tid = blockIdx.x * 256 + threadIdx.x;
    if (tid < 256 * 128) {
        int col = tid >> 7, k = tid & 127;
        float v = (col < 128) ? W1[k * 128 + col] : r1W[k * 128 + (col - 128)];
        Wb1t[col * 128 + k] = f2bf(v);
    } else if (tid < 256 * 128 + 80 * 128) {
        int t2 = tid - 256 * 128;
        int col = t2 >> 7, k = t2 & 127;
        float v = (col < NC) ? W2[k * NC + col] : r2W[k * NC + (col - NC)];
        Wb2t[col * 128 + k] = f2bf(v);
    } else {
        int t3 = tid - 256 * 128 - 80 * 128;
        if (t3 < 128) {
            float s = 0.f;
            for (int c = 0; c < NC; c++) s += W2[t3 * NC + c] * att_s2[c];
            wts[t3] = s;
        } else if (t3 < 256) {
            int k = t3 - 128;
            float s = 0.f;
            for (int c = 0; c < NC; c++) s += W2[k * NC + c] * att_d2[c];
            wtd[k] = s;
        }
    }
}

// ---------------- layer 1 GEMM (MFMA): h1b, res1 (bf16), as1/ad1 ----------------

__global__ __launch_bounds__(256) void gemm1_kernel(
        const float* __restrict__ x, const unsigned short* __restrict__ Wb1t,
        const float* __restrict__ r1b,
        const float* __restrict__ att_s, const float* __restrict__ att_d,
        unsigned short* __restrict__ h1b, unsigned short* __restrict__ hbufb,
        float* __restrict__ as1, float* __restrict__ ad1) {
    __shared__ float sh_as[16][8], sh_ad[16][8];
    int lane = threadIdx.x & 63, wv = threadIdx.x >> 6;
    int m = lane & 15, q = lane >> 4;
    int row0 = blockIdx.x * 16;

    union { unsigned short u[8]; bf16x8 v; } af[4];
    const float* xr = x + (size_t)(row0 + m) * 128 + q * 8;
    #pragma unroll
    for (int kk = 0; kk < 4; kk++) {
        float4 a0 = *(const float4*)(xr + kk * 32);
        float4 a1 = *(const float4*)(xr + kk * 32 + 4);
        af[kk].u[0] = f2bf(a0.x); af[kk].u[1] = f2bf(a0.y);
        af[kk].u[2] = f2bf(a0.z); af[kk].u[3] = f2bf(a0.w);
        af[kk].u[4] = f2bf(a1.x); af[kk].u[5] = f2bf(a1.y);
        af[kk].u[6] = f2bf(a1.z); af[kk].u[7] = f2bf(a1.w);
    }

    f32x4 acc[4];
    #pragma unroll
    for (int t = 0; t < 4; t++) acc[t] = (f32x4){0.f, 0.f, 0.f, 0.f};

    #pragma unroll
    for (int t = 0; t < 4; t++) {
        int tile = wv * 4 + t;
        const unsigned short* bp = Wb1t + (size_t)(tile * 16 + m) * 128 + q * 8;
        #pragma unroll
        for (int kk = 0; kk < 4; kk++) {
            bf16x8 bv = *(const bf16x8*)(bp + kk * 32);
            acc[t] = __builtin_amdgcn_mfma_f32_16x16x32_bf16(af[kk].v, bv, acc[t], 0, 0, 0);
        }
    }

    #pragma unroll
    for (int t = 0; t < 4; t++) {
        int tile = wv * 4 + t;
        int col = tile * 16 + m;
        if (col < 128) {
            float wsv = att_s[col], wdv = att_d[col];
            #pragma unroll
            for (int r = 0; r < 4; r++) {
                float v = acc[t][r];
                h1b[(size_t)(row0 + q * 4 + r) * 128 + col] = f2bf(v);
                float ps = v * wsv, pd = v * wdv;
                ps += __shfl_xor(ps, 1, 64); pd += __shfl_xor(pd, 1, 64);
                ps += __shfl_xor(ps, 2, 64); pd += __shfl_xor(pd, 2, 64);
                ps += __shfl_xor(ps, 4, 64); pd += __shfl_xor(pd, 4, 64);
                ps += __shfl_xor(ps, 8, 64); pd += __shfl_xor(pd, 8, 64);
                if (m == 0) { sh_as[q * 4 + r][tile] = ps; sh_ad[q * 4 + r][tile] = pd; }
            }
        } else {
            int cc = col - 128;
            float bias = r1b[cc];
            #pragma unroll
            for (int r = 0; r < 4; r++)
                hbufb[(size_t)(row0 + q * 4 + r) * 128 + cc] = f2bf(acc[t][r] + bias);
        }
    }
    __syncthreads();
    int tt = threadIdx.x;
    if (tt < 128) {
        int i = tt >> 3, h = tt & 7;
        as1[(row0 + i) * 8 + h] = sh_as[i][h];
        ad1[(row0 + i) * 8 + h] = sh_ad[i][h];
    }
}

// ---------------- layer 1 gather-aggregate: half-wave edge pairing ----------------
// lanes 0-31 process even edges, 32-63 odd edges; each half covers the 128-col row
// with ushort4 (4 cols/lane). Per-lane-indexed shfl feeds (s,e) to each half.

__global__ __launch_bounds__(256) void agg1_kernel(
        const int* __restrict__ rs, const int* __restrict__ csr,
        const float* __restrict__ as, const float* __restrict__ ad,
        const unsigned short* __restrict__ h1b, const float* __restrict__ bias,
        const unsigned short* __restrict__ hbufb, unsigned short* __restrict__ hb,
        const float* __restrict__ wts, const float* __restrict__ wtd,
        float* __restrict__ as2, float* __restrict__ ad2) {
    int lane = threadIdx.x & 63, wv = threadIdx.x >> 6;
    int n = blockIdx.x * 4 + wv;
    if (n >= Nn) return;
    int row = rs[n], end = rs[n + 1];
    int h = lane & 7;        // head for parallel-logit phase
    int j8 = lane >> 3;      // edge-slot for parallel-logit phase
    int half = lane >> 5;    // which edge of the pair this half-wave handles
    int l5 = lane & 31;
    int c0 = l5 * 4;         // 4 cols per lane (half-wave covers 128)
    int hh = l5 >> 2;        // head of cols c0..c0+3
    float adh = ad[n * 8 + h];

    float den_l = 0.f;
    float a0 = 0.f, a1 = 0.f, a2 = 0.f, a3 = 0.f;

    int j = row;
    for (; j + 8 <= end; j += 8) {
        int s_l = csr[j + j8];
        float v = as[s_l * 8 + h] + adh;
        v = v > 0.f ? v : SLOPE * v;
        float e_l = __expf(v);
        den_l += e_l;
        #pragma unroll
        for (int t = 0; t < 8; t += 2) {
            int idx = (t + half) * 8;
            int sP = __shfl(s_l, idx, 64);
            float eP = __shfl(e_l, idx + hh, 64);
            ushort4 u = *(const ushort4*)(h1b + (size_t)sP * 128 + c0);
            a0 += eP * bf2f(u.x); a1 += eP * bf2f(u.y);
            a2 += eP * bf2f(u.z); a3 += eP * bf2f(u.w);
        }
    }
    int cnt = end - j;
    if (cnt > 0) {
        int s_l = 0; float e_l = 0.f;
        if (j8 < cnt) {
            s_l = csr[j + j8];
            float v = as[s_l * 8 + h] + adh;
            v = v > 0.f ? v : SLOPE * v;
            e_l = __expf(v);
        }
        den_l += e_l;
        int t = 0;
        for (; t + 2 <= cnt; t += 2) {
            int idx = (t + half) * 8;
            int sP = __shfl(s_l, idx, 64);
            float eP = __shfl(e_l, idx + hh, 64);
            ushort4 u = *(const ushort4*)(h1b + (size_t)sP * 128 + c0);
            a0 += eP * bf2f(u.x); a1 += eP * bf2f(u.y);
            a2 += eP * bf2f(u.z); a3 += eP * bf2f(u.w);
        }
        if (t < cnt) {   // final odd edge: half 0 only
            int sP = __shfl(s_l, t * 8, 64);
            float eP = __shfl(e_l, t * 8 + hh, 64);
            if (half == 0) {
                ushort4 u = *(const ushort4*)(h1b + (size_t)sP * 128 + c0);
                a0 += eP * bf2f(u.x); a1 += eP * bf2f(u.y);
                a2 += eP * bf2f(u.z); a3 += eP * bf2f(u.w);
            }
        }
    }
    // combine edge-halves
    a0 += __shfl_xor(a0, 32, 64);
    a1 += __shfl_xor(a1, 32, 64);
    a2 += __shfl_xor(a2, 32, 64);
    a3 += __shfl_xor(a3, 32, 64);
    // den: reduce over the 8 edge-slots
    den_l += __shfl_xor(den_l, 8, 64);
    den_l += __shfl_xor(den_l, 16, 64);
    den_l += __shfl_xor(den_l, 32, 64);
    float inv = 1.f / __shfl(den_l, hh, 64);

    float ps = 0.f, pd = 0.f;
    if (half == 0) {
        float g0 = a0 * inv + bias[c0];
        float g1 = a1 * inv + bias[c0 + 1];
        float g2 = a2 * inv + bias[c0 + 2];
        float g3 = a3 * inv + bias[c0 + 3];
        ushort4 rr = *(const ushort4*)(hbufb + (size_t)n * 128 + c0);
        g0 = (g0 > 0.f ? g0 : expm1f(g0)) + bf2f(rr.x);
        g1 = (g1 > 0.f ? g1 : expm1f(g1)) + bf2f(rr.y);
        g2 = (g2 > 0.f ? g2 : expm1f(g2)) + bf2f(rr.z);
        g3 = (g3 > 0.f ? g3 : expm1f(g3)) + bf2f(rr.w);
        ushort4 o;
        o.x = f2bf(g0); o.y = f2bf(g1); o.z = f2bf(g2); o.w = f2bf(g3);
        *(ushort4*)(hb + (size_t)n * 128 + c0) = o;
        float4 wsv = *(const float4*)(wts + c0);
        float4 wdv = *(const float4*)(wtd + c0);
        ps = g0 * wsv.x + g1 * wsv.y + g2 * wsv.z + g3 * wsv.w;
        pd = g0 * wdv.x + g1 * wdv.y + g2 * wdv.z + g3 * wdv.w;
    }
    #pragma unroll
    for (int st = 32; st >= 1; st >>= 1) {
        ps += __shfl_xor(ps, st, 64);
        pd += __shfl_xor(pd, st, 64);
    }
    if (lane == 0) { as2[n] = ps; ad2[n] = pd; }
}

// ---------------- layer 2 GEMM (MFMA, pure): h2b + residual-out ----------------

__global__ __launch_bounds__(320) void gemm2_kernel(
        const unsigned short* __restrict__ hb, const unsigned short* __restrict__ Wb2t,
        const float* __restrict__ r2b,
        unsigned short* __restrict__ h2b, float* __restrict__ outp) {
    int lane = threadIdx.x & 63, wv = threadIdx.x >> 6;   // wv 0..4
    int m = lane & 15, q = lane >> 4;
    int row0 = blockIdx.x * 16;

    const unsigned short* hr = hb + (size_t)(row0 + m) * 128 + q * 8;
    const unsigned short* bp = Wb2t + (size_t)(wv * 16 + m) * 128 + q * 8;
    f32x4 acc = (f32x4){0.f, 0.f, 0.f, 0.f};
    #pragma unroll
    for (int kk = 0; kk < 4; kk++) {
        bf16x8 av = *(const bf16x8*)(hr + kk * 32);
        bf16x8 bv = *(const bf16x8*)(bp + kk * 32);
        acc = __builtin_amdgcn_mfma_f32_16x16x32_bf16(av, bv, acc, 0, 0, 0);
    }

    int col = wv * 16 + m;
    if (col < NC) {
        #pragma unroll
        for (int r = 0; r < 4; r++)
            h2b[(size_t)(row0 + q * 4 + r) * NC + col] = f2bf(acc[r]);
    } else {
        int cc = col - NC;
        float bias = r2b[cc];
        #pragma unroll
        for (int r = 0; r < 4; r++)
            outp[(size_t)(row0 + q * 4 + r) * NC + cc] = acc[r] + bias;
    }
}

// ---------------- layer 2 gather-aggregate: half-wave edge pairing + log_softmax ----------------
// lanes 0-19 edge A, lanes 32-51 edge B; 2 cols/lane (ushort2).

__global__ __launch_bounds__(256) void agg2_kernel(
        const int* __restrict__ rs, const int* __restrict__ csr,
        const float* __restrict__ as, const float* __restrict__ ad,
        const unsigned short* __restrict__ h2b, const float* __restrict__ b2,
        float* __restrict__ outp) {
    int lane = threadIdx.x & 63, wv = threadIdx.x >> 6;
    int n = blockIdx.x * 4 + wv;
    if (n >= Nn) return;
    int row = rs[n], end = rs[n + 1];
    float adn = ad[n];
    int half = lane >> 5;
    int l5 = lane & 31;
    bool act2 = l5 < 20;
    int c0 = l5 * 2;

    float den_l = 0.f, a0 = 0.f, a1 = 0.f;
    for (int base = row; base < end; base += 64) {
        int cnt = min(64, end - base);
        int s_l = 0; float e_l = 0.f;
        if (lane < cnt) {
            s_l = csr[base + lane];
            float v = as[s_l] + adn;
            v = v > 0.f ? v : SLOPE * v;
            e_l = __expf(v);
        }
        den_l += e_l;
        int t = 0;
        for (; t + 2 <= cnt; t += 2) {
            int idx = t + half;
            int sP = __shfl(s_l, idx, 64);
            float eP = __shfl(e_l, idx, 64);
            if (act2) {
                ushort2 u = *(const ushort2*)(h2b + (size_t)sP * NC + c0);
                a0 += eP * bf2f(u.x);
                a1 += eP * bf2f(u.y);
            }
        }
        if (t < cnt) {   // final odd edge: half 0 only
            int sP = __shfl(s_l, t, 64);
            float eP = __shfl(e_l, t, 64);
            if (act2 && half == 0) {
                ushort2 u = *(const ushort2*)(h2b + (size_t)sP * NC + c0);
                a0 += eP * bf2f(u.x);
                a1 += eP * bf2f(u.y);
            }
        }
    }
    a0 += __shfl_xor(a0, 32, 64);
    a1 += __shfl_xor(a1, 32, 64);
    #pragma unroll
    for (int st = 32; st >= 1; st >>= 1) den_l += __shfl_xor(den_l, st, 64);
    float invd = 1.f / den_l;

    bool actw = (half == 0) && act2;
    float v0 = -3.4e38f, v1 = -3.4e38f;
    if (actw) {
        float2 op = *(const float2*)(outp + (size_t)n * NC + c0);
        v0 = a0 * invd + b2[c0] + op.x;
        v1 = a1 * invd + b2[c0 + 1] + op.y;
    }
    float mm = fmaxf(v0, v1);
    #pragma unroll
    for (int st = 32; st >= 1; st >>= 1) mm = fmaxf(mm, __shfl_xor(mm, st, 64));
    float ex = actw ? (__expf(v0 - mm) + __expf(v1 - mm)) : 0.f;
    float ss = ex;
    #pragma unroll
    for (int st = 32; st >= 1; st >>= 1) ss += __shfl_xor(ss, st, 64);
    if (actw) {
        float lg = mm + logf(ss);
        float2 o; o.x = v0 - lg; o.y = v1 - lg;
        *(float2*)(outp + (size_t)n * NC + c0) = o;
    }
}

// ---------------- host ----------------

extern "C" void kernel_launch(void* const* d_in, const int* in_sizes, int n_in,
                              void* d_out, int out_size, void* d_ws, size_t ws_size,
                              hipStream_t stream) {
    const float* x      = (const float*)d_in[0];
    const int*   ei     = (const int*)d_in[1];
    const float* W1     = (const float*)d_in[2];
    const float* att_s1 = (const float*)d_in[3];
    const float* att_d1 = (const float*)d_in[4];
    const float* bias1  = (const float*)d_in[5];
    const float* W2     = (const float*)d_in[6];
    const float* att_s2 = (const float*)d_in[7];
    const float* att_d2 = (const float*)d_in[8];
    const float* bias2  = (const float*)d_in[9];
    const float* r1W    = (const float*)d_in[10];
    const float* r1b    = (const float*)d_in[11];
    const float* r2W    = (const float*)d_in[12];
    const float* r2b    = (const float*)d_in[13];
    float* out = (float*)d_out;

    float* ws   = (float*)d_ws;
    float* as1  = ws;                            // N*8
    float* ad1  = as1 + (size_t)Nn * 8;          // N*8
    float* as2  = ad1 + (size_t)Nn * 8;          // N
    float* ad2  = as2 + Nn;                      // N
    float* wts  = ad2 + Nn;                      // 128
    float* wtd  = wts + 128;                     // 128
    unsigned short* hbufb = (unsigned short*)(wtd + 128);  // N*128 bf16 (res1)
    unsigned short* h1b = hbufb + (size_t)Nn * 128;        // N*128 bf16
    unsigned short* hb  = h1b + (size_t)Nn * 128;          // N*128 bf16 (post-agg1 h)
    unsigned short* h2b = hb + (size_t)Nn * 128;           // N*40 bf16
    unsigned short* Wb1t = h2b + (size_t)Nn * 40;          // 256*128 bf16
    unsigned short* Wb2t = Wb1t + 256 * 128;               // 80*128 bf16
    uintptr_t pal = ((uintptr_t)(Wb2t + 80 * 128) + 7) & ~(uintptr_t)7;
    long long* pairs = (long long*)pal;          // NBUK*CAPB pairs (padded buckets)
    int* rs      = (int*)(pairs + (size_t)NBUK * CAPB);  // N+1
    int* bukcnt  = rs + Nn + 1;                  // NBUK
    int* bukbase = bukcnt + NBUK;                // NBUK+1
    int* csr     = bukbase + NBUK + 1;           // EP

    // ---- CSR build + weight prep ----
    hipMemsetAsync(bukcnt, 0, NBUK * sizeof(int), stream);
    partA_kernel<<<NBA, 256, 0, stream>>>(ei, bukcnt, pairs);
    bukscan_kernel<<<1, 512, 0, stream>>>(bukcnt, bukbase, rs);
    partB_kernel<<<NBUK, 256, 0, stream>>>(pairs, bukcnt, bukbase, rs, csr);
    castW_kernel<<<(256 * 128 + 80 * 128 + 256 + 255) / 256, 256, 0, stream>>>(
        W1, r1W, W2, r2W, att_s2, att_d2, Wb1t, Wb2t, wts, wtd);

    // ---- layer 1 ----
    gemm1_kernel<<<Nn / 16, 256, 0, stream>>>(x, Wb1t, r1b, att_s1, att_d1,
                                              h1b, hbufb, as1, ad1);
    agg1_kernel<<<(Nn + 3) / 4, 256, 0, stream>>>(rs, csr, as1, ad1, h1b, bias1,
                                                  hbufb, hb, wts, wtd, as2, ad2);

    // ---- layer 2 ----
    gemm2_kernel<<<Nn / 16, 320, 0, stream>>>(hb, Wb2t, r2b, h2b, out);
    agg2_kernel<<<(Nn + 3) / 4, 256, 0, stream>>>(rs, csr, as2, ad2, h2b, bias2, out);
}